// Round 3
// baseline (17356.279 us; speedup 1.0000x reference)
//
#include <hip/hip_runtime.h>
#include <hip/hip_cooperative_groups.h>
#include <math.h>

namespace cg = cooperative_groups;

#define B 32
#define T 50
#define H 1024
#define E 128
#define V 32000
#define G4 4096   // 4*H
#define HE 1152   // H+E
#define MPAD 1664 // 13*128 padded M for GEMM

__device__ __forceinline__ float sigm(float x){ return 1.0f/(1.0f+expf(-x)); }

// device-scope (agent) relaxed atomics: bypass L1, never register-cached.
__device__ __forceinline__ float ldA(const float* p){
  return __hip_atomic_load(p, __ATOMIC_RELAXED, __HIP_MEMORY_SCOPE_AGENT);
}
__device__ __forceinline__ void stA(float* p, float v){
  __hip_atomic_store(p, v, __ATOMIC_RELAXED, __HIP_MEMORY_SCOPE_AGENT);
}

// encp[b][e] = proj_b[e] + sum_j enc[b][j] * proj_w[e][E+j]
__global__ void k_encp(const float* __restrict__ enc, const float* __restrict__ pw,
                       const float* __restrict__ pb, float* __restrict__ encp){
  int b = blockIdx.x, e = threadIdx.x;
  const float* er = enc + b*H;
  const float* wr = pw + e*HE + E;
  float acc = pb[e];
  for (int j=0;j<H;j+=4){
    float4 w4 = *(const float4*)(wr+j);
    float4 e4 = *(const float4*)(er+j);
    acc += w4.x*e4.x + w4.y*e4.y + w4.z*e4.z + w4.w*e4.w;
  }
  encp[b*E+e] = acc;
}

// P[t][e][b] = encp[b][e] + sum_j target[b][t][j] * proj_w[e][j]
__global__ void k_proj(const float* __restrict__ target, const float* __restrict__ pw,
                       const float* __restrict__ encp, float* __restrict__ P){
  int t = blockIdx.x / B, b = blockIdx.x % B, e = threadIdx.x;
  const float* xr = target + (b*T + t)*E;
  const float* wr = pw + e*HE;
  float acc = encp[b*E+e];
  for (int j=0;j<E;j+=4){
    float4 w4 = *(const float4*)(wr+j);
    float4 x4 = *(const float4*)(xr+j);
    acc += w4.x*x4.x + w4.y*x4.y + w4.z*x4.z + w4.w*x4.w;
  }
  P[(t*E + e)*B + b] = acc;
}

// xg0[t][r][b] = b_ih0[r]+b_hh0[r] + sum_e w_ih0[r][e] * P[t][e][b]
__global__ void k_xg0(const float* __restrict__ wih0, const float* __restrict__ bih0,
                      const float* __restrict__ bhh0, const float* __restrict__ P,
                      float* __restrict__ xg){
  int idx = blockIdx.x*256 + threadIdx.x;
  int b = idx & 31; int r = (idx >> 5) & 4095; int t = idx >> 17;
  const float* wr = wih0 + r*E;
  const float* pr = P + t*E*B + b;
  float acc = bih0[r] + bhh0[r];
  #pragma unroll 8
  for (int e=0;e<E;e++) acc += wr[e] * pr[e*B];
  xg[idx] = acc;
}

__global__ void k_fill(float* __restrict__ p){
  p[blockIdx.x*256 + threadIdx.x] = 0.f;
}

// ---------------- cooperative persistent cells ----------------
__global__ __launch_bounds__(256, 4) void k_cells(
    const float* __restrict__ whh0, const float* __restrict__ wih1, const float* __restrict__ whh1,
    const float* __restrict__ bih1, const float* __restrict__ bhh1,
    const float* __restrict__ enc, const float* __restrict__ xg0,
    float* __restrict__ h0A, float* __restrict__ h0B,
    float* __restrict__ h1A, float* __restrict__ h1B,
    float* __restrict__ H1T){
  cg::grid_group grid = cg::this_grid();
  const int h = blockIdx.x;
  const int tid = threadIdx.x;
  const int w = tid >> 6, lane = tid & 63, b = lane & 31;

  __shared__ float red[4][4][32];   // [wave][gate][b]
  __shared__ float gates[4][32];
  __shared__ float cst[2][32];
  __shared__ float bs1[4];

  if (tid < 32){
    float v = enc[tid*H + h];
    cst[0][tid] = v; cst[1][tid] = v;
    stA(&h0A[h*32 + tid], v);
    stA(&h1A[h*32 + tid], v);
  }
  if (tid >= 32 && tid < 36){
    int q = tid - 32;
    bs1[q] = bih1[q*H + h] + bhh1[q*H + h];
  }
  __syncthreads();
  grid.sync();

  float* h0p = h0A; float* h0n = h0B;
  float* h1p = h1A; float* h1n = h1B;

  for (int t = 0; t < T; t++){
    // ---- layer 0: gates += h0p @ whh0.T (K=1024 split over 8 lane-groups) ----
    {
      const int kb = w*256 + (lane >> 5)*128;
      const float* wp0 = whh0 + (0*H + h)*H + kb;
      const float* wp1 = whh0 + (1*H + h)*H + kb;
      const float* wp2 = whh0 + (2*H + h)*H + kb;
      const float* wp3 = whh0 + (3*H + h)*H + kb;
      const float* hv = h0p + kb*32 + b;
      float a0=0,a1=0,a2=0,a3=0;
      #pragma unroll 4
      for (int kk=0; kk<128; kk+=4){
        float4 q0 = *(const float4*)(wp0+kk);
        float4 q1 = *(const float4*)(wp1+kk);
        float4 q2 = *(const float4*)(wp2+kk);
        float4 q3 = *(const float4*)(wp3+kk);
        float x0 = ldA(hv+(kk+0)*32), x1 = ldA(hv+(kk+1)*32);
        float x2 = ldA(hv+(kk+2)*32), x3 = ldA(hv+(kk+3)*32);
        a0 += q0.x*x0 + q0.y*x1 + q0.z*x2 + q0.w*x3;
        a1 += q1.x*x0 + q1.y*x1 + q1.z*x2 + q1.w*x3;
        a2 += q2.x*x0 + q2.y*x1 + q2.z*x2 + q2.w*x3;
        a3 += q3.x*x0 + q3.y*x1 + q3.z*x2 + q3.w*x3;
      }
      a0 += __shfl_xor(a0,32); a1 += __shfl_xor(a1,32);
      a2 += __shfl_xor(a2,32); a3 += __shfl_xor(a3,32);
      if (lane < 32){
        red[w][0][b]=a0; red[w][1][b]=a1; red[w][2][b]=a2; red[w][3][b]=a3;
      }
    }
    __syncthreads();
    if (tid < 128){
      int q = tid>>5, bb = tid&31;
      float g = red[0][q][bb]+red[1][q][bb]+red[2][q][bb]+red[3][q][bb]
              + xg0[((long)t*G4 + q*H + h)*B + bb];
      gates[q][bb] = (q==2) ? tanhf(g) : sigm(g);
    }
    __syncthreads();
    if (tid < 32){
      float cn = gates[1][tid]*cst[0][tid] + gates[0][tid]*gates[2][tid];
      cst[0][tid] = cn;
      stA(&h0n[h*32 + tid], gates[3][tid]*tanhf(cn));
    }
    grid.sync();
    // ---- layer 1: gates = h0n @ wih1.T + h1p @ whh1.T + biases (K=2048) ----
    {
      const float* wmat = (w < 2) ? wih1 : whh1;
      const float* vec  = (w < 2) ? h0n : h1p;
      const int kb = (w & 1)*512 + (lane >> 5)*256;
      const float* wp0 = wmat + (0*H + h)*H + kb;
      const float* wp1 = wmat + (1*H + h)*H + kb;
      const float* wp2 = wmat + (2*H + h)*H + kb;
      const float* wp3 = wmat + (3*H + h)*H + kb;
      const float* hv = vec + kb*32 + b;
      float a0=0,a1=0,a2=0,a3=0;
      #pragma unroll 4
      for (int kk=0; kk<256; kk+=4){
        float4 q0 = *(const float4*)(wp0+kk);
        float4 q1 = *(const float4*)(wp1+kk);
        float4 q2 = *(const float4*)(wp2+kk);
        float4 q3 = *(const float4*)(wp3+kk);
        float x0 = ldA(hv+(kk+0)*32), x1 = ldA(hv+(kk+1)*32);
        float x2 = ldA(hv+(kk+2)*32), x3 = ldA(hv+(kk+3)*32);
        a0 += q0.x*x0 + q0.y*x1 + q0.z*x2 + q0.w*x3;
        a1 += q1.x*x0 + q1.y*x1 + q1.z*x2 + q1.w*x3;
        a2 += q2.x*x0 + q2.y*x1 + q2.z*x2 + q2.w*x3;
        a3 += q3.x*x0 + q3.y*x1 + q3.z*x2 + q3.w*x3;
      }
      a0 += __shfl_xor(a0,32); a1 += __shfl_xor(a1,32);
      a2 += __shfl_xor(a2,32); a3 += __shfl_xor(a3,32);
      if (lane < 32){
        red[w][0][b]=a0; red[w][1][b]=a1; red[w][2][b]=a2; red[w][3][b]=a3;
      }
    }
    __syncthreads();
    if (tid < 128){
      int q = tid>>5, bb = tid&31;
      float g = red[0][q][bb]+red[1][q][bb]+red[2][q][bb]+red[3][q][bb] + bs1[q];
      gates[q][bb] = (q==2) ? tanhf(g) : sigm(g);
    }
    __syncthreads();
    if (tid < 32){
      float cn = gates[1][tid]*cst[1][tid] + gates[0][tid]*gates[2][tid];
      cst[1][tid] = cn;
      float hn = gates[3][tid]*tanhf(cn);
      stA(&h1n[h*32 + tid], hn);
      H1T[(long)h*MPAD + tid*T + t] = hn;
    }
    grid.sync();
    float* tp;
    tp = h0p; h0p = h0n; h0n = tp;
    tp = h1p; h1p = h1n; h1n = tp;
  }
}

// ---------------- fallback per-step cells (round-1 verified) ----------------
__global__ void k_init(const float* __restrict__ enc, float* __restrict__ h0, float* __restrict__ c0,
                       float* __restrict__ h1, float* __restrict__ c1){
  int idx = blockIdx.x*256 + threadIdx.x;   // 32768
  int b = idx & 31, h = idx >> 5;
  float v = enc[b*H + h];
  h0[idx]=v; c0[idx]=v; h1[idx]=v; c1[idx]=v;
}

__global__ __launch_bounds__(256) void k_cell0(const float* __restrict__ whh, const float* __restrict__ xg_t,
                       const float* __restrict__ h_in, float* __restrict__ h_out,
                       float* __restrict__ c){
  int h = (blockIdx.x*256 + threadIdx.x) >> 6;
  int lane = threadIdx.x & 63;
  int b = lane & 31, kh = lane >> 5;
  const float* w0 = whh + (0*H + h)*H + kh*512;
  const float* w1 = whh + (1*H + h)*H + kh*512;
  const float* w2 = whh + (2*H + h)*H + kh*512;
  const float* w3 = whh + (3*H + h)*H + kh*512;
  const float* hk = h_in + (kh*512)*B + b;
  float a0=0,a1=0,a2=0,a3=0, p0=0,p1=0,p2=0,p3=0;
  #pragma unroll 4
  for (int k=0;k<512;k+=4){
    float4 w40 = *(const float4*)(w0+k);
    float4 w41 = *(const float4*)(w1+k);
    float4 w42 = *(const float4*)(w2+k);
    float4 w43 = *(const float4*)(w3+k);
    float hv0 = hk[(k+0)*B], hv1 = hk[(k+1)*B], hv2 = hk[(k+2)*B], hv3 = hk[(k+3)*B];
    a0 += w40.x*hv0 + w40.y*hv1;  p0 += w40.z*hv2 + w40.w*hv3;
    a1 += w41.x*hv0 + w41.y*hv1;  p1 += w41.z*hv2 + w41.w*hv3;
    a2 += w42.x*hv0 + w42.y*hv1;  p2 += w42.z*hv2 + w42.w*hv3;
    a3 += w43.x*hv0 + w43.y*hv1;  p3 += w43.z*hv2 + w43.w*hv3;
  }
  float g0=a0+p0, g1=a1+p1, g2=a2+p2, g3=a3+p3;
  g0 += __shfl_xor(g0, 32);
  g1 += __shfl_xor(g1, 32);
  g2 += __shfl_xor(g2, 32);
  g3 += __shfl_xor(g3, 32);
  g0 += xg_t[(0*H+h)*B + b];
  g1 += xg_t[(1*H+h)*B + b];
  g2 += xg_t[(2*H+h)*B + b];
  g3 += xg_t[(3*H+h)*B + b];
  float ig = sigm(g0), fg = sigm(g1), gg = tanhf(g2), og = sigm(g3);
  int sidx = h*B + b;
  float cn = fg*c[sidx] + ig*gg;
  float hn = og*tanhf(cn);
  if (kh==0){ c[sidx]=cn; h_out[sidx]=hn; }
}

__global__ __launch_bounds__(256) void k_cell1(const float* __restrict__ wih, const float* __restrict__ whh,
                       const float* __restrict__ bih, const float* __restrict__ bhh,
                       const float* __restrict__ h0n, const float* __restrict__ h_in,
                       float* __restrict__ h_out, float* __restrict__ c,
                       float* __restrict__ H1T, int t){
  int h = (blockIdx.x*256 + threadIdx.x) >> 6;
  int lane = threadIdx.x & 63;
  int b = lane & 31, kh = lane >> 5;
  float a0=0,a1=0,a2=0,a3=0, p0=0,p1=0,p2=0,p3=0;
  {
    const float* w0 = wih + (0*H + h)*H + kh*512;
    const float* w1 = wih + (1*H + h)*H + kh*512;
    const float* w2 = wih + (2*H + h)*H + kh*512;
    const float* w3 = wih + (3*H + h)*H + kh*512;
    const float* hk = h0n + (kh*512)*B + b;
    #pragma unroll 4
    for (int k=0;k<512;k+=4){
      float4 w40 = *(const float4*)(w0+k);
      float4 w41 = *(const float4*)(w1+k);
      float4 w42 = *(const float4*)(w2+k);
      float4 w43 = *(const float4*)(w3+k);
      float hv0 = hk[(k+0)*B], hv1 = hk[(k+1)*B], hv2 = hk[(k+2)*B], hv3 = hk[(k+3)*B];
      a0 += w40.x*hv0 + w40.y*hv1;  p0 += w40.z*hv2 + w40.w*hv3;
      a1 += w41.x*hv0 + w41.y*hv1;  p1 += w41.z*hv2 + w41.w*hv3;
      a2 += w42.x*hv0 + w42.y*hv1;  p2 += w42.z*hv2 + w42.w*hv3;
      a3 += w43.x*hv0 + w43.y*hv1;  p3 += w43.z*hv2 + w43.w*hv3;
    }
  }
  {
    const float* w0 = whh + (0*H + h)*H + kh*512;
    const float* w1 = whh + (1*H + h)*H + kh*512;
    const float* w2 = whh + (2*H + h)*H + kh*512;
    const float* w3 = whh + (3*H + h)*H + kh*512;
    const float* hk = h_in + (kh*512)*B + b;
    #pragma unroll 4
    for (int k=0;k<512;k+=4){
      float4 w40 = *(const float4*)(w0+k);
      float4 w41 = *(const float4*)(w1+k);
      float4 w42 = *(const float4*)(w2+k);
      float4 w43 = *(const float4*)(w3+k);
      float hv0 = hk[(k+0)*B], hv1 = hk[(k+1)*B], hv2 = hk[(k+2)*B], hv3 = hk[(k+3)*B];
      a0 += w40.x*hv0 + w40.y*hv1;  p0 += w40.z*hv2 + w40.w*hv3;
      a1 += w41.x*hv0 + w41.y*hv1;  p1 += w41.z*hv2 + w41.w*hv3;
      a2 += w42.x*hv0 + w42.y*hv1;  p2 += w42.z*hv2 + w42.w*hv3;
      a3 += w43.x*hv0 + w43.y*hv1;  p3 += w43.z*hv2 + w43.w*hv3;
    }
  }
  float g0=a0+p0, g1=a1+p1, g2=a2+p2, g3=a3+p3;
  g0 += __shfl_xor(g0, 32);
  g1 += __shfl_xor(g1, 32);
  g2 += __shfl_xor(g2, 32);
  g3 += __shfl_xor(g3, 32);
  g0 += bih[0*H+h] + bhh[0*H+h];
  g1 += bih[1*H+h] + bhh[1*H+h];
  g2 += bih[2*H+h] + bhh[2*H+h];
  g3 += bih[3*H+h] + bhh[3*H+h];
  float ig = sigm(g0), fg = sigm(g1), gg = tanhf(g2), og = sigm(g3);
  int sidx = h*B + b;
  float cn = fg*c[sidx] + ig*gg;
  float hn = og*tanhf(cn);
  if (kh==0){ c[sidx]=cn; h_out[sidx]=hn; H1T[(long)h*MPAD + b*T + t] = hn; }
}

// ---------------- output GEMM + log-softmax ----------------
#define GBM 128
#define GBN 128
#define GBK 32
__global__ __launch_bounds__(256, 4) void k_gemm(const float* __restrict__ A,
                      const float* __restrict__ lw, const float* __restrict__ lb,
                      float* __restrict__ out){
  __shared__ float As[GBK][GBM];
  __shared__ float Ws[GBK][GBN];   // n-index XOR-swizzled by (k>>2)<<2
  const int tid = threadIdx.x;
  int orig = blockIdx.x;
  int xcd = orig & 7, ii = orig >> 3;
  int wgid = (xcd < 2 ? xcd*407 : 814 + (xcd-2)*406) + ii;
  int bm = wgid % 13, bn = wgid / 13;
  int m0 = bm*GBM, n0 = bn*GBN;
  int tx = tid & 15, ty = tid >> 4;
  float acc[8][8] = {};
  for (int k0 = 0; k0 < H; k0 += GBK){
    #pragma unroll
    for (int it=0; it<4; it++){
      int idx = tid + it*256;
      int k_l = idx >> 5, m4 = (idx & 31)*4;
      float4 v = *(const float4*)(A + (k0+k_l)*MPAD + m0 + m4);
      *(float4*)&As[k_l][m4] = v;
    }
    #pragma unroll
    for (int it=0; it<4; it++){
      int idx = tid + it*256;
      int n_l = idx >> 3, kq = idx & 7;
      float4 v = *(const float4*)(lw + (long)(n0+n_l)*H + k0 + kq*4);
      int sw = kq << 2;
      Ws[kq*4+0][n_l ^ sw] = v.x;
      Ws[kq*4+1][n_l ^ sw] = v.y;
      Ws[kq*4+2][n_l ^ sw] = v.z;
      Ws[kq*4+3][n_l ^ sw] = v.w;
    }
    __syncthreads();
    #pragma unroll
    for (int k=0;k<GBK;k++){
      int sw = (k >> 2) << 2;
      float4 a0 = *(const float4*)&As[k][ty*4];
      float4 a1 = *(const float4*)&As[k][ty*4+64];
      float4 w0 = *(const float4*)&Ws[k][(tx*4) ^ sw];
      float4 w1 = *(const float4*)&Ws[k][((tx*4) ^ sw) + 64];
      float am[8] = {a0.x,a0.y,a0.z,a0.w,a1.x,a1.y,a1.z,a1.w};
      float wn[8] = {w0.x,w0.y,w0.z,w0.w,w1.x,w1.y,w1.z,w1.w};
      #pragma unroll
      for (int im=0;im<8;im++)
        #pragma unroll
        for (int in=0;in<8;in++)
          acc[im][in] += am[im]*wn[in];
    }
    __syncthreads();
  }
  float4 b0 = *(const float4*)(lb + n0 + tx*4);
  float4 b1 = *(const float4*)(lb + n0 + tx*4 + 64);
  #pragma unroll
  for (int im=0;im<8;im++){
    int m = m0 + (im>>2)*64 + ty*4 + (im&3);
    if (m < B*T){
      float* orow = out + (long)m*V + n0;
      float4 o0, o1;
      o0.x = acc[im][0]+b0.x; o0.y = acc[im][1]+b0.y; o0.z = acc[im][2]+b0.z; o0.w = acc[im][3]+b0.w;
      o1.x = acc[im][4]+b1.x; o1.y = acc[im][5]+b1.y; o1.z = acc[im][6]+b1.z; o1.w = acc[im][7]+b1.w;
      *(float4*)(orow + tx*4) = o0;
      *(float4*)(orow + tx*4 + 64) = o1;
    }
  }
}

__global__ __launch_bounds__(256) void k_lsm(float* __restrict__ out){
  __shared__ float red[256];
  float4* row = (float4*)(out + (long)blockIdx.x * V);
  const int tid = threadIdx.x;
  float m = -INFINITY;
  for (int n=tid;n<V/4;n+=256){
    float4 v = row[n];
    m = fmaxf(m, fmaxf(fmaxf(v.x,v.y), fmaxf(v.z,v.w)));
  }
  red[tid]=m; __syncthreads();
  for (int s=128;s>0;s>>=1){ if(tid<s) red[tid]=fmaxf(red[tid],red[tid+s]); __syncthreads(); }
  m = red[0]; __syncthreads();
  float s = 0.f;
  for (int n=tid;n<V/4;n+=256){
    float4 v = row[n];
    s += expf(v.x-m)+expf(v.y-m)+expf(v.z-m)+expf(v.w-m);
  }
  red[tid]=s; __syncthreads();
  for (int st=128;st>0;st>>=1){ if(tid<st) red[tid]+=red[tid+st]; __syncthreads(); }
  float lse = m + logf(red[0]);
  for (int n=tid;n<V/4;n+=256){
    float4 v = row[n];
    v.x-=lse; v.y-=lse; v.z-=lse; v.w-=lse;
    row[n] = v;
  }
}

extern "C" void kernel_launch(void* const* d_in, const int* in_sizes, int n_in,
                              void* d_out, int out_size, void* d_ws, size_t ws_size,
                              hipStream_t stream){
  const float* enc    = (const float*)d_in[0];
  const float* target = (const float*)d_in[1];
  const float* pw     = (const float*)d_in[2];
  const float* pb     = (const float*)d_in[3];
  const float* wih0   = (const float*)d_in[4];
  const float* whh0   = (const float*)d_in[5];
  const float* bih0   = (const float*)d_in[6];
  const float* bhh0   = (const float*)d_in[7];
  const float* wih1   = (const float*)d_in[8];
  const float* whh1   = (const float*)d_in[9];
  const float* bih1   = (const float*)d_in[10];
  const float* bhh1   = (const float*)d_in[11];
  const float* lw     = (const float*)d_in[12];
  const float* lb     = (const float*)d_in[13];
  float* out = (float*)d_out;

  float* ws   = (float*)d_ws;
  float* xg0  = ws;                       // T*G4*B = 6,553,600 f
  float* P    = xg0 + (long)T*G4*B;       // 204,800 f
  float* encp = P + T*E*B;                // 4,096 f
  float* h0A  = encp + B*E;
  float* h0B  = h0A + H*B;
  float* h1A  = h0B + H*B;
  float* h1B  = h1A + H*B;
  float* H1T  = h1B + H*B;                // H*MPAD = 1,703,936 f
  float* c0f  = H1T + (long)H*MPAD;       // fallback c-state
  float* c1f  = c0f + H*B;

  k_encp<<<B, E, 0, stream>>>(enc, pw, pb, encp);
  k_proj<<<T*B, E, 0, stream>>>(target, pw, encp, P);
  k_xg0<<<(T*G4*B)/256, 256, 0, stream>>>(wih0, bih0, bhh0, P, xg0);
  k_fill<<<(H*MPAD)/256, 256, 0, stream>>>(H1T);

  void* cargs[] = {(void*)&whh0, (void*)&wih1, (void*)&whh1, (void*)&bih1, (void*)&bhh1,
                   (void*)&enc, (void*)&xg0,
                   (void*)&h0A, (void*)&h0B, (void*)&h1A, (void*)&h1B, (void*)&H1T};
  hipError_t cerr = hipLaunchCooperativeKernel((void*)k_cells, dim3(1024), dim3(256),
                                               cargs, 0, stream);
  if (cerr != hipSuccess){
    // fallback: per-step kernels (verified path)
    k_init<<<(H*B)/256, 256, 0, stream>>>(enc, h0A, c0f, h1A, c1f);
    float* h0in=h0A; float* h0out=h0B;
    float* h1in=h1A; float* h1out=h1B;
    for (int t=0;t<T;t++){
      k_cell0<<<256, 256, 0, stream>>>(whh0, xg0 + (long)t*G4*B, h0in, h0out, c0f);
      k_cell1<<<256, 256, 0, stream>>>(wih1, whh1, bih1, bhh1, h0out, h1in, h1out, c1f,
                                       H1T, t);
      float* tmp;
      tmp=h0in; h0in=h0out; h0out=tmp;
      tmp=h1in; h1in=h1out; h1out=tmp;
    }
  }

  k_gemm<<<3250, 256, 0, stream>>>(H1T, lw, lb, out);
  k_lsm<<<B*T, 256, 0, stream>>>(out);
}

// Round 4
// 15139.192 us; speedup vs baseline: 1.1464x; 1.1464x over previous
//
#include <hip/hip_runtime.h>
#include <hip/hip_bf16.h>
#include <math.h>

#define B 32
#define T 50
#define H 1024
#define E 128
#define V 32000
#define G4 4096   // 4*H
#define HE 1152   // H+E
#define MPAD 1664 // 13*128 padded M for GEMM

__device__ __forceinline__ float sigm(float x){ return 1.0f/(1.0f+expf(-x)); }

// ---- fast grid barrier: release fence, one atomicAdd per block, sleep-spin, acquire fence ----
__device__ __forceinline__ void gbar(unsigned* bar, unsigned tgt){
  __syncthreads();
  if (threadIdx.x == 0){
    __builtin_amdgcn_fence(__ATOMIC_RELEASE, "agent");
    __hip_atomic_fetch_add(bar, 1u, __ATOMIC_RELAXED, __HIP_MEMORY_SCOPE_AGENT);
    while (__hip_atomic_load(bar, __ATOMIC_RELAXED, __HIP_MEMORY_SCOPE_AGENT) < tgt)
      __builtin_amdgcn_s_sleep(2);
    __builtin_amdgcn_fence(__ATOMIC_ACQUIRE, "agent");
  }
  __syncthreads();
}

// encp[b][e] = proj_b[e] + sum_j enc[b][j] * proj_w[e][E+j]
__global__ void k_encp(const float* __restrict__ enc, const float* __restrict__ pw,
                       const float* __restrict__ pb, float* __restrict__ encp){
  int b = blockIdx.x, e = threadIdx.x;
  const float* er = enc + b*H;
  const float* wr = pw + e*HE + E;
  float acc = pb[e];
  for (int j=0;j<H;j+=4){
    float4 w4 = *(const float4*)(wr+j);
    float4 e4 = *(const float4*)(er+j);
    acc += w4.x*e4.x + w4.y*e4.y + w4.z*e4.z + w4.w*e4.w;
  }
  encp[b*E+e] = acc;
}

// P[t][e][b] = encp[b][e] + sum_j target[b][t][j] * proj_w[e][j]
__global__ void k_proj(const float* __restrict__ target, const float* __restrict__ pw,
                       const float* __restrict__ encp, float* __restrict__ P){
  int t = blockIdx.x / B, b = blockIdx.x % B, e = threadIdx.x;
  const float* xr = target + (b*T + t)*E;
  const float* wr = pw + e*HE;
  float acc = encp[b*E+e];
  for (int j=0;j<E;j+=4){
    float4 w4 = *(const float4*)(wr+j);
    float4 x4 = *(const float4*)(xr+j);
    acc += w4.x*x4.x + w4.y*x4.y + w4.z*x4.z + w4.w*x4.w;
  }
  P[(t*E + e)*B + b] = acc;
}

// xg0[t][r][b] = b_ih0[r]+b_hh0[r] + sum_e w_ih0[r][e] * P[t][e][b]
__global__ void k_xg0(const float* __restrict__ wih0, const float* __restrict__ bih0,
                      const float* __restrict__ bhh0, const float* __restrict__ P,
                      float* __restrict__ xg){
  int idx = blockIdx.x*256 + threadIdx.x;
  int b = idx & 31; int r = (idx >> 5) & 4095; int t = idx >> 17;
  const float* wr = wih0 + r*E;
  const float* pr = P + t*E*B + b;
  float acc = bih0[r] + bhh0[r];
  #pragma unroll 8
  for (int e=0;e<E;e++) acc += wr[e] * pr[e*B];
  xg[idx] = acc;
}

__global__ void k_fill(float* __restrict__ p){
  p[blockIdx.x*256 + threadIdx.x] = 0.f;
}

__global__ void k_zero(unsigned* __restrict__ bar){ *bar = 0u; }

// ---------------- cooperative persistent cells (v2) ----------------
// Block = one h unit. Weights bf16 in LDS (staged once). Wave q computes gate q.
// Lane l: k-slice kl=l>>2 (stride 16), b-range bg=(l&3)*8 (8 consecutive b).
// State layout: s[k*32 + b] f32 global, double-buffered; plain vectorized loads,
// coherence via gbar's agent-scope fences.
__global__ __launch_bounds__(256, 4) void k_cells(
    const float* __restrict__ whh0, const float* __restrict__ wih1, const float* __restrict__ whh1,
    const float* __restrict__ bih1, const float* __restrict__ bhh1,
    const float* __restrict__ enc, const float* __restrict__ xg0,
    float* __restrict__ h0A, float* __restrict__ h0B,
    float* __restrict__ h1A, float* __restrict__ h1B,
    float* __restrict__ H1T, unsigned* __restrict__ bar){
  const int h = blockIdx.x;
  const int tid = threadIdx.x;
  const int q = tid >> 6;          // wave index = gate index
  const int l = tid & 63;
  const int bg = (l & 3) << 3;     // b-range start (0,8,16,24)
  const int kl = l >> 2;           // k-lane 0..15

  __shared__ __hip_bfloat16 w0s[4][1024];   // whh0 rows for this h (8KB)
  __shared__ __hip_bfloat16 w1s[8][1024];   // wih1 (0..3) + whh1 (4..7) rows (16KB)
  __shared__ float h1loc[B*T];              // [b][t] stash of h1 outputs (6.4KB)
  __shared__ float gates[4][32];
  __shared__ float cst[2][32];
  __shared__ float bs1[4];

  // ---- stage weights (f32 -> bf16), init state ----
  for (int i = tid; i < 1024; i += 256){       // 4 rows x 256 float4
    int qq = i >> 8, k4 = (i & 255) << 2;
    float4 v = *(const float4*)(whh0 + ((long)(qq*H + h))*H + k4);
    w0s[qq][k4+0] = __float2bfloat16(v.x);
    w0s[qq][k4+1] = __float2bfloat16(v.y);
    w0s[qq][k4+2] = __float2bfloat16(v.z);
    w0s[qq][k4+3] = __float2bfloat16(v.w);
  }
  for (int i = tid; i < 2048; i += 256){       // 8 rows x 256 float4
    int qq = i >> 8, k4 = (i & 255) << 2;
    const float* src = (qq < 4) ? (wih1 + ((long)(qq*H + h))*H)
                                : (whh1 + ((long)((qq-4)*H + h))*H);
    float4 v = *(const float4*)(src + k4);
    w1s[qq][k4+0] = __float2bfloat16(v.x);
    w1s[qq][k4+1] = __float2bfloat16(v.y);
    w1s[qq][k4+2] = __float2bfloat16(v.z);
    w1s[qq][k4+3] = __float2bfloat16(v.w);
  }
  if (tid < 32){
    float v = enc[tid*H + h];
    cst[0][tid] = v; cst[1][tid] = v;
    h0A[h*32 + tid] = v;
    h1A[h*32 + tid] = v;
  }
  if (tid >= 32 && tid < 36){
    int g = tid - 32;
    bs1[g] = bih1[g*H + h] + bhh1[g*H + h];
  }
  unsigned ep = 1024;
  gbar(bar, ep); ep += 1024;

  float* h0p = h0A; float* h0n = h0B;
  float* h1p = h1A; float* h1n = h1B;
  float acc[8];

  for (int t = 0; t < T; t++){
    // ---- layer 0: gate q = sum_k whh0[q*H+h][k] * h0p[k][b], b in bg..bg+7 ----
    #pragma unroll
    for (int j=0;j<8;j++) acc[j]=0.f;
    {
      const __hip_bfloat16* wrow = w0s[q];
      #pragma unroll 4
      for (int i=0;i<64;i++){
        int k = kl + (i<<4);
        float wt = __bfloat162float(wrow[k]);
        const float* hp = h0p + (k<<5) + bg;
        float4 x0 = *(const float4*)(hp);
        float4 x1 = *(const float4*)(hp+4);
        acc[0]+=wt*x0.x; acc[1]+=wt*x0.y; acc[2]+=wt*x0.z; acc[3]+=wt*x0.w;
        acc[4]+=wt*x1.x; acc[5]+=wt*x1.y; acc[6]+=wt*x1.z; acc[7]+=wt*x1.w;
      }
    }
    #pragma unroll
    for (int m=4;m<64;m<<=1){
      #pragma unroll
      for (int j=0;j<8;j++) acc[j] += __shfl_xor(acc[j], m);
    }
    if (l < 4){
      *(float4*)&gates[q][l*8]   = make_float4(acc[0],acc[1],acc[2],acc[3]);
      *(float4*)&gates[q][l*8+4] = make_float4(acc[4],acc[5],acc[6],acc[7]);
    }
    __syncthreads();
    if (tid < 128){
      int g = tid>>5, bb = tid&31;
      float v = gates[g][bb] + xg0[((long)t*G4 + g*H + h)*32 + bb];
      gates[g][bb] = (g==2) ? tanhf(v) : sigm(v);
    }
    __syncthreads();
    if (tid < 32){
      float cn = gates[1][tid]*cst[0][tid] + gates[0][tid]*gates[2][tid];
      cst[0][tid] = cn;
      h0n[h*32 + tid] = gates[3][tid]*tanhf(cn);
    }
    gbar(bar, ep); ep += 1024;

    // ---- layer 1: gate q = wih1 row . h0n  +  whh1 row . h1p ----
    #pragma unroll
    for (int j=0;j<8;j++) acc[j]=0.f;
    {
      const __hip_bfloat16* wr0 = w1s[q];
      const __hip_bfloat16* wr1 = w1s[4+q];
      #pragma unroll 4
      for (int i=0;i<64;i++){
        int k = kl + (i<<4);
        float wa = __bfloat162float(wr0[k]);
        float wb = __bfloat162float(wr1[k]);
        const float* pa = h0n + (k<<5) + bg;
        const float* pb = h1p + (k<<5) + bg;
        float4 a0 = *(const float4*)(pa);
        float4 a1 = *(const float4*)(pa+4);
        float4 c0 = *(const float4*)(pb);
        float4 c1 = *(const float4*)(pb+4);
        acc[0]+=wa*a0.x+wb*c0.x; acc[1]+=wa*a0.y+wb*c0.y;
        acc[2]+=wa*a0.z+wb*c0.z; acc[3]+=wa*a0.w+wb*c0.w;
        acc[4]+=wa*a1.x+wb*c1.x; acc[5]+=wa*a1.y+wb*c1.y;
        acc[6]+=wa*a1.z+wb*c1.z; acc[7]+=wa*a1.w+wb*c1.w;
      }
    }
    #pragma unroll
    for (int m=4;m<64;m<<=1){
      #pragma unroll
      for (int j=0;j<8;j++) acc[j] += __shfl_xor(acc[j], m);
    }
    if (l < 4){
      *(float4*)&gates[q][l*8]   = make_float4(acc[0],acc[1],acc[2],acc[3]);
      *(float4*)&gates[q][l*8+4] = make_float4(acc[4],acc[5],acc[6],acc[7]);
    }
    __syncthreads();
    if (tid < 128){
      int g = tid>>5, bb = tid&31;
      float v = gates[g][bb] + bs1[g];
      gates[g][bb] = (g==2) ? tanhf(v) : sigm(v);
    }
    __syncthreads();
    if (tid < 32){
      float cn = gates[1][tid]*cst[1][tid] + gates[0][tid]*gates[2][tid];
      cst[1][tid] = cn;
      float hn = gates[3][tid]*tanhf(cn);
      h1n[h*32 + tid] = hn;
      h1loc[tid*T + t] = hn;
    }
    gbar(bar, ep); ep += 1024;

    float* tp;
    tp = h0p; h0p = h0n; h0n = tp;
    tp = h1p; h1p = h1n; h1n = tp;
  }

  // coalesced H1T flush: row m = b*T+t == linear index of h1loc
  for (int i = tid; i < B*T; i += 256)
    H1T[(long)h*MPAD + i] = h1loc[i];
}

// ---------------- fallback per-step cells ----------------
__global__ void k_init(const float* __restrict__ enc, float* __restrict__ h0, float* __restrict__ c0,
                       float* __restrict__ h1, float* __restrict__ c1){
  int idx = blockIdx.x*256 + threadIdx.x;
  int b = idx & 31, h = idx >> 5;
  float v = enc[b*H + h];
  h0[idx]=v; c0[idx]=v; h1[idx]=v; c1[idx]=v;
}

__global__ __launch_bounds__(256) void k_cell0(const float* __restrict__ whh, const float* __restrict__ xg_t,
                       const float* __restrict__ h_in, float* __restrict__ h_out,
                       float* __restrict__ c){
  int h = (blockIdx.x*256 + threadIdx.x) >> 6;
  int lane = threadIdx.x & 63;
  int b = lane & 31, kh = lane >> 5;
  const float* w0 = whh + (0*H + h)*H + kh*512;
  const float* w1 = whh + (1*H + h)*H + kh*512;
  const float* w2 = whh + (2*H + h)*H + kh*512;
  const float* w3 = whh + (3*H + h)*H + kh*512;
  const float* hk = h_in + (kh*512)*B + b;
  float a0=0,a1=0,a2=0,a3=0, p0=0,p1=0,p2=0,p3=0;
  #pragma unroll 4
  for (int k=0;k<512;k+=4){
    float4 w40 = *(const float4*)(w0+k);
    float4 w41 = *(const float4*)(w1+k);
    float4 w42 = *(const float4*)(w2+k);
    float4 w43 = *(const float4*)(w3+k);
    float hv0 = hk[(k+0)*B], hv1 = hk[(k+1)*B], hv2 = hk[(k+2)*B], hv3 = hk[(k+3)*B];
    a0 += w40.x*hv0 + w40.y*hv1;  p0 += w40.z*hv2 + w40.w*hv3;
    a1 += w41.x*hv0 + w41.y*hv1;  p1 += w41.z*hv2 + w41.w*hv3;
    a2 += w42.x*hv0 + w42.y*hv1;  p2 += w42.z*hv2 + w42.w*hv3;
    a3 += w43.x*hv0 + w43.y*hv1;  p3 += w43.z*hv2 + w43.w*hv3;
  }
  float g0=a0+p0, g1=a1+p1, g2=a2+p2, g3=a3+p3;
  g0 += __shfl_xor(g0, 32);
  g1 += __shfl_xor(g1, 32);
  g2 += __shfl_xor(g2, 32);
  g3 += __shfl_xor(g3, 32);
  g0 += xg_t[(0*H+h)*B + b];
  g1 += xg_t[(1*H+h)*B + b];
  g2 += xg_t[(2*H+h)*B + b];
  g3 += xg_t[(3*H+h)*B + b];
  float ig = sigm(g0), fg = sigm(g1), gg = tanhf(g2), og = sigm(g3);
  int sidx = h*B + b;
  float cn = fg*c[sidx] + ig*gg;
  float hn = og*tanhf(cn);
  if (kh==0){ c[sidx]=cn; h_out[sidx]=hn; }
}

__global__ __launch_bounds__(256) void k_cell1(const float* __restrict__ wih, const float* __restrict__ whh,
                       const float* __restrict__ bih, const float* __restrict__ bhh,
                       const float* __restrict__ h0n, const float* __restrict__ h_in,
                       float* __restrict__ h_out, float* __restrict__ c,
                       float* __restrict__ H1T, int t){
  int h = (blockIdx.x*256 + threadIdx.x) >> 6;
  int lane = threadIdx.x & 63;
  int b = lane & 31, kh = lane >> 5;
  float a0=0,a1=0,a2=0,a3=0, p0=0,p1=0,p2=0,p3=0;
  {
    const float* w0 = wih + (0*H + h)*H + kh*512;
    const float* w1 = wih + (1*H + h)*H + kh*512;
    const float* w2 = wih + (2*H + h)*H + kh*512;
    const float* w3 = wih + (3*H + h)*H + kh*512;
    const float* hk = h0n + (kh*512)*B + b;
    #pragma unroll 4
    for (int k=0;k<512;k+=4){
      float4 w40 = *(const float4*)(w0+k);
      float4 w41 = *(const float4*)(w1+k);
      float4 w42 = *(const float4*)(w2+k);
      float4 w43 = *(const float4*)(w3+k);
      float hv0 = hk[(k+0)*B], hv1 = hk[(k+1)*B], hv2 = hk[(k+2)*B], hv3 = hk[(k+3)*B];
      a0 += w40.x*hv0 + w40.y*hv1;  p0 += w40.z*hv2 + w40.w*hv3;
      a1 += w41.x*hv0 + w41.y*hv1;  p1 += w41.z*hv2 + w41.w*hv3;
      a2 += w42.x*hv0 + w42.y*hv1;  p2 += w42.z*hv2 + w42.w*hv3;
      a3 += w43.x*hv0 + w43.y*hv1;  p3 += w43.z*hv2 + w43.w*hv3;
    }
  }
  {
    const float* w0 = whh + (0*H + h)*H + kh*512;
    const float* w1 = whh + (1*H + h)*H + kh*512;
    const float* w2 = whh + (2*H + h)*H + kh*512;
    const float* w3 = whh + (3*H + h)*H + kh*512;
    const float* hk = h_in + (kh*512)*B + b;
    #pragma unroll 4
    for (int k=0;k<512;k+=4){
      float4 w40 = *(const float4*)(w0+k);
      float4 w41 = *(const float4*)(w1+k);
      float4 w42 = *(const float4*)(w2+k);
      float4 w43 = *(const float4*)(w3+k);
      float hv0 = hk[(k+0)*B], hv1 = hk[(k+1)*B], hv2 = hk[(k+2)*B], hv3 = hk[(k+3)*B];
      a0 += w40.x*hv0 + w40.y*hv1;  p0 += w40.z*hv2 + w40.w*hv3;
      a1 += w41.x*hv0 + w41.y*hv1;  p1 += w41.z*hv2 + w41.w*hv3;
      a2 += w42.x*hv0 + w42.y*hv1;  p2 += w42.z*hv2 + w42.w*hv3;
      a3 += w43.x*hv0 + w43.y*hv1;  p3 += w43.z*hv2 + w43.w*hv3;
    }
  }
  float g0=a0+p0, g1=a1+p1, g2=a2+p2, g3=a3+p3;
  g0 += __shfl_xor(g0, 32);
  g1 += __shfl_xor(g1, 32);
  g2 += __shfl_xor(g2, 32);
  g3 += __shfl_xor(g3, 32);
  g0 += bih[0*H+h] + bhh[0*H+h];
  g1 += bih[1*H+h] + bhh[1*H+h];
  g2 += bih[2*H+h] + bhh[2*H+h];
  g3 += bih[3*H+h] + bhh[3*H+h];
  float ig = sigm(g0), fg = sigm(g1), gg = tanhf(g2), og = sigm(g3);
  int sidx = h*B + b;
  float cn = fg*c[sidx] + ig*gg;
  float hn = og*tanhf(cn);
  if (kh==0){ c[sidx]=cn; h_out[sidx]=hn; H1T[(long)h*MPAD + b*T + t] = hn; }
}

// ---------------- output GEMM + log-softmax ----------------
#define GBM 128
#define GBN 128
#define GBK 32
__global__ __launch_bounds__(256, 4) void k_gemm(const float* __restrict__ A,
                      const float* __restrict__ lw, const float* __restrict__ lb,
                      float* __restrict__ out){
  __shared__ float As[GBK][GBM];
  __shared__ float Ws[GBK][GBN];   // n-index XOR-swizzled by (k>>2)<<2
  const int tid = threadIdx.x;
  int orig = blockIdx.x;
  int xcd = orig & 7, ii = orig >> 3;
  int wgid = (xcd < 2 ? xcd*407 : 814 + (xcd-2)*406) + ii;
  int bm = wgid % 13, bn = wgid / 13;
  int m0 = bm*GBM, n0 = bn*GBN;
  int tx = tid & 15, ty = tid >> 4;
  float acc[8][8] = {};
  for (int k0 = 0; k0 < H; k0 += GBK){
    #pragma unroll
    for (int it=0; it<4; it++){
      int idx = tid + it*256;
      int k_l = idx >> 5, m4 = (idx & 31)*4;
      float4 v = *(const float4*)(A + (k0+k_l)*MPAD + m0 + m4);
      *(float4*)&As[k_l][m4] = v;
    }
    #pragma unroll
    for (int it=0; it<4; it++){
      int idx = tid + it*256;
      int n_l = idx >> 3, kq = idx & 7;
      float4 v = *(const float4*)(lw + (long)(n0+n_l)*H + k0 + kq*4);
      int sw = kq << 2;
      Ws[kq*4+0][n_l ^ sw] = v.x;
      Ws[kq*4+1][n_l ^ sw] = v.y;
      Ws[kq*4+2][n_l ^ sw] = v.z;
      Ws[kq*4+3][n_l ^ sw] = v.w;
    }
    __syncthreads();
    #pragma unroll
    for (int k=0;k<GBK;k++){
      int sw = (k >> 2) << 2;
      float4 a0 = *(const float4*)&As[k][ty*4];
      float4 a1 = *(const float4*)&As[k][ty*4+64];
      float4 w0 = *(const float4*)&Ws[k][(tx*4) ^ sw];
      float4 w1 = *(const float4*)&Ws[k][((tx*4) ^ sw) + 64];
      float am[8] = {a0.x,a0.y,a0.z,a0.w,a1.x,a1.y,a1.z,a1.w};
      float wn[8] = {w0.x,w0.y,w0.z,w0.w,w1.x,w1.y,w1.z,w1.w};
      #pragma unroll
      for (int im=0;im<8;im++)
        #pragma unroll
        for (int in=0;in<8;in++)
          acc[im][in] += am[im]*wn[in];
    }
    __syncthreads();
  }
  float4 b0 = *(const float4*)(lb + n0 + tx*4);
  float4 b1 = *(const float4*)(lb + n0 + tx*4 + 64);
  #pragma unroll
  for (int im=0;im<8;im++){
    int m = m0 + (im>>2)*64 + ty*4 + (im&3);
    if (m < B*T){
      float* orow = out + (long)m*V + n0;
      float4 o0, o1;
      o0.x = acc[im][0]+b0.x; o0.y = acc[im][1]+b0.y; o0.z = acc[im][2]+b0.z; o0.w = acc[im][3]+b0.w;
      o1.x = acc[im][4]+b1.x; o1.y = acc[im][5]+b1.y; o1.z = acc[im][6]+b1.z; o1.w = acc[im][7]+b1.w;
      *(float4*)(orow + tx*4) = o0;
      *(float4*)(orow + tx*4 + 64) = o1;
    }
  }
}

__global__ __launch_bounds__(256) void k_lsm(float* __restrict__ out){
  __shared__ float red[256];
  float4* row = (float4*)(out + (long)blockIdx.x * V);
  const int tid = threadIdx.x;
  float m = -INFINITY;
  for (int n=tid;n<V/4;n+=256){
    float4 v = row[n];
    m = fmaxf(m, fmaxf(fmaxf(v.x,v.y), fmaxf(v.z,v.w)));
  }
  red[tid]=m; __syncthreads();
  for (int s=128;s>0;s>>=1){ if(tid<s) red[tid]=fmaxf(red[tid],red[tid+s]); __syncthreads(); }
  m = red[0]; __syncthreads();
  float s = 0.f;
  for (int n=tid;n<V/4;n+=256){
    float4 v = row[n];
    s += expf(v.x-m)+expf(v.y-m)+expf(v.z-m)+expf(v.w-m);
  }
  red[tid]=s; __syncthreads();
  for (int st=128;st>0;st>>=1){ if(tid<st) red[tid]+=red[tid+st]; __syncthreads(); }
  float lse = m + logf(red[0]);
  for (int n=tid;n<V/4;n+=256){
    float4 v = row[n];
    v.x-=lse; v.y-=lse; v.z-=lse; v.w-=lse;
    row[n] = v;
  }
}

extern "C" void kernel_launch(void* const* d_in, const int* in_sizes, int n_in,
                              void* d_out, int out_size, void* d_ws, size_t ws_size,
                              hipStream_t stream){
  const float* enc    = (const float*)d_in[0];
  const float* target = (const float*)d_in[1];
  const float* pw     = (const float*)d_in[2];
  const float* pb     = (const float*)d_in[3];
  const float* wih0   = (const float*)d_in[4];
  const float* whh0   = (const float*)d_in[5];
  const float* bih0   = (const float*)d_in[6];
  const float* bhh0   = (const float*)d_in[7];
  const float* wih1   = (const float*)d_in[8];
  const float* whh1   = (const float*)d_in[9];
  const float* bih1   = (const float*)d_in[10];
  const float* bhh1   = (const float*)d_in[11];
  const float* lw     = (const float*)d_in[12];
  const float* lb     = (const float*)d_in[13];
  float* out = (float*)d_out;

  float* ws   = (float*)d_ws;
  float* xg0  = ws;                       // T*G4*B = 6,553,600 f
  float* P    = xg0 + (long)T*G4*B;       // 204,800 f
  float* encp = P + T*E*B;                // 4,096 f
  float* h0A  = encp + B*E;
  float* h0B  = h0A + H*B;
  float* h1A  = h0B + H*B;
  float* h1B  = h1A + H*B;
  float* H1T  = h1B + H*B;                // H*MPAD = 1,703,936 f
  float* c0f  = H1T + (long)H*MPAD;       // fallback c-state
  float* c1f  = c0f + H*B;
  unsigned* bar = (unsigned*)(c1f + H*B);

  k_encp<<<B, E, 0, stream>>>(enc, pw, pb, encp);
  k_proj<<<T*B, E, 0, stream>>>(target, pw, encp, P);
  k_xg0<<<(T*G4*B)/256, 256, 0, stream>>>(wih0, bih0, bhh0, P, xg0);
  k_fill<<<(H*MPAD)/256, 256, 0, stream>>>(H1T);
  k_zero<<<1, 1, 0, stream>>>(bar);

  void* cargs[] = {(void*)&whh0, (void*)&wih1, (void*)&whh1, (void*)&bih1, (void*)&bhh1,
                   (void*)&enc, (void*)&xg0,
                   (void*)&h0A, (void*)&h0B, (void*)&h1A, (void*)&h1B, (void*)&H1T,
                   (void*)&bar};
  hipError_t cerr = hipLaunchCooperativeKernel((void*)k_cells, dim3(1024), dim3(256),
                                               cargs, 0, stream);
  if (cerr != hipSuccess){
    // fallback: per-step kernels
    k_init<<<(H*B)/256, 256, 0, stream>>>(enc, h0A, c0f, h1A, c1f);
    float* h0in=h0A; float* h0out=h0B;
    float* h1in=h1A; float* h1out=h1B;
    for (int t=0;t<T;t++){
      k_cell0<<<256, 256, 0, stream>>>(whh0, xg0 + (long)t*G4*B, h0in, h0out, c0f);
      k_cell1<<<256, 256, 0, stream>>>(wih1, whh1, bih1, bhh1, h0out, h1in, h1out, c1f,
                                       H1T, t);
      float* tmp;
      tmp=h0in; h0in=h0out; h0out=tmp;
      tmp=h1in; h1in=h1out; h1out=tmp;
    }
  }

  k_gemm<<<3250, 256, 0, stream>>>(H1T, lw, lb, out);
  k_lsm<<<B*T, 256, 0, stream>>>(out);
}

// Round 6
// 2996.331 us; speedup vs baseline: 5.7925x; 5.0526x over previous
//
#include <hip/hip_runtime.h>
#include <hip/hip_bf16.h>
#include <math.h>

#define B 32
#define T 50
#define H 1024
#define E 128
#define V 32000
#define G4 4096   // 4*H
#define HE 1152   // H+E
#define MPAD 1664 // 13*128 padded M for GEMM
#define NB 256    // coop grid blocks

typedef __fp16 half2v __attribute__((ext_vector_type(2)));
union U32H2 { unsigned u; half2v h; };

__device__ __forceinline__ float sigm(float x){ return 1.0f/(1.0f+expf(-x)); }

__device__ __forceinline__ half2v pk2(float a, float b){
#if __has_builtin(__builtin_amdgcn_cvt_pkrtz)
  return __builtin_amdgcn_cvt_pkrtz(a, b);
#else
  half2v r; r.x = (__fp16)a; r.y = (__fp16)b; return r;
#endif
}

__device__ __forceinline__ float dot2(half2v a, half2v b, float c){
#if __has_builtin(__builtin_amdgcn_fdot2)
  return __builtin_amdgcn_fdot2(a, b, c, false);
#else
  return c + (float)a.x*(float)b.x + (float)a.y*(float)b.y;
#endif
}

// ---- fast grid barrier ----
__device__ __forceinline__ void gbar(unsigned* bar, unsigned tgt){
  __syncthreads();
  if (threadIdx.x == 0){
    __builtin_amdgcn_fence(__ATOMIC_RELEASE, "agent");
    __hip_atomic_fetch_add(bar, 1u, __ATOMIC_RELAXED, __HIP_MEMORY_SCOPE_AGENT);
    while (__hip_atomic_load(bar, __ATOMIC_RELAXED, __HIP_MEMORY_SCOPE_AGENT) < tgt)
      __builtin_amdgcn_s_sleep(2);
    __builtin_amdgcn_fence(__ATOMIC_ACQUIRE, "agent");
  }
  __syncthreads();
}

// encp[b][e] = proj_b[e] + sum_j enc[b][j] * proj_w[e][E+j]
__global__ void k_encp(const float* __restrict__ enc, const float* __restrict__ pw,
                       const float* __restrict__ pb, float* __restrict__ encp){
  int b = blockIdx.x, e = threadIdx.x;
  const float* er = enc + b*H;
  const float* wr = pw + e*HE + E;
  float acc = pb[e];
  for (int j=0;j<H;j+=4){
    float4 w4 = *(const float4*)(wr+j);
    float4 e4 = *(const float4*)(er+j);
    acc += w4.x*e4.x + w4.y*e4.y + w4.z*e4.z + w4.w*e4.w;
  }
  encp[b*E+e] = acc;
}

// P[t][e][b] = encp[b][e] + sum_j target[b][t][j] * proj_w[e][j]
__global__ void k_proj(const float* __restrict__ target, const float* __restrict__ pw,
                       const float* __restrict__ encp, float* __restrict__ P){
  int t = blockIdx.x / B, b = blockIdx.x % B, e = threadIdx.x;
  const float* xr = target + (b*T + t)*E;
  const float* wr = pw + e*HE;
  float acc = encp[b*E+e];
  for (int j=0;j<E;j+=4){
    float4 w4 = *(const float4*)(wr+j);
    float4 x4 = *(const float4*)(xr+j);
    acc += w4.x*x4.x + w4.y*x4.y + w4.z*x4.z + w4.w*x4.w;
  }
  P[(t*E + e)*B + b] = acc;
}

// xg0[t][r][b] = b_ih0[r]+b_hh0[r] + sum_e w_ih0[r][e] * P[t][e][b]
__global__ void k_xg0(const float* __restrict__ wih0, const float* __restrict__ bih0,
                      const float* __restrict__ bhh0, const float* __restrict__ P,
                      float* __restrict__ xg){
  int idx = blockIdx.x*256 + threadIdx.x;
  int b = idx & 31; int r = (idx >> 5) & 4095; int t = idx >> 17;
  const float* wr = wih0 + r*E;
  const float* pr = P + t*E*B + b;
  float acc = bih0[r] + bhh0[r];
  #pragma unroll 8
  for (int e=0;e<E;e++) acc += wr[e] * pr[e*B];
  xg[idx] = acc;
}

__global__ void k_fill(float* __restrict__ p){
  p[blockIdx.x*256 + threadIdx.x] = 0.f;
}

__global__ void k_zero(unsigned* __restrict__ bar){ *bar = 0u; }

// ---------------- cooperative persistent cells (v3) ----------------
// 256 blocks x 1024 thr (1/CU). Block owns 4 h-units; ALL weights f16 in LDS.
// 16 waves partition K (64 k each, rotated chunk (w+gB+t)&15). State f16-pair
// packed [k2][b] in global; v_dot2_f32_f16 inner product; LDS cross-wave reduce.
__global__ __launch_bounds__(1024, 4) void k_cells(
    const float* __restrict__ whh0, const float* __restrict__ wih1, const float* __restrict__ whh1,
    const float* __restrict__ bih1, const float* __restrict__ bhh1,
    const float* __restrict__ enc, const float* __restrict__ xg0,
    unsigned* __restrict__ h0A2, unsigned* __restrict__ h0B2,
    unsigned* __restrict__ h1A2, unsigned* __restrict__ h1B2,
    float* __restrict__ H1T, unsigned* __restrict__ bar){
  const int gB = blockIdx.x;
  const int tid = threadIdx.x;
  const int w = tid >> 6;       // wave 0..15 = k-chunk owner
  const int l = tid & 63;
  const int b = l & 31;
  const int rh = l >> 5;        // row-half: rows rh*8..rh*8+7

  __shared__ half2v w0s[16][512];        // layer0 whh0 rows (32 KB)
  __shared__ half2v w1s[32][512];        // wih1(0-15) + whh1(16-31) (64 KB)
  __shared__ float partial[16][16][32];  // [wave][row][b] (32 KB)
  __shared__ float gates[16][32];        // [q*4+hl][b]
  __shared__ float cst[2][4][32];
  __shared__ float bs1v[16];
  __shared__ __fp16 h1loc[4][1600];      // [hl][b*T+t] (12.8 KB)

  // ---- stage weights f32 -> f16 pairs ----
  for (int i = tid; i < 16*512; i += 1024){
    int r = i >> 9, k2 = i & 511;
    int q = r >> 2, hl = r & 3;
    float2 v = *(const float2*)(whh0 + ((long)q*H + 4*gB + hl)*H + 2*k2);
    w0s[r][k2] = pk2(v.x, v.y);
  }
  for (int i = tid; i < 32*512; i += 1024){
    int r = i >> 9, k2 = i & 511;
    int rr = r & 15;
    int q = rr >> 2, hl = rr & 3;
    const float* srcm = (r < 16) ? wih1 : whh1;
    float2 v = *(const float2*)(srcm + ((long)q*H + 4*gB + hl)*H + 2*k2);
    w1s[r][k2] = pk2(v.x, v.y);
  }
  if (tid < 16){
    int q = tid >> 2, hl = tid & 3;
    bs1v[tid] = bih1[q*H + 4*gB + hl] + bhh1[q*H + 4*gB + hl];
  }
  if (tid < 128){
    int hl = tid >> 5, bb = tid & 31;
    float v = enc[bb*H + 4*gB + hl];
    cst[0][hl][bb] = v; cst[1][hl][bb] = v;
  }
  if (tid < 64){
    int hp = tid >> 5, bb = tid & 31;
    U32H2 uu;
    uu.h = pk2(enc[bb*H + 4*gB + 2*hp], enc[bb*H + 4*gB + 2*hp + 1]);
    h0A2[(2*gB + hp)*32 + bb] = uu.u;
    h1A2[(2*gB + hp)*32 + bb] = uu.u;
  }
  unsigned ep = NB;
  gbar(bar, ep); ep += NB;

  unsigned* h0p2 = h0A2; unsigned* h0n2 = h0B2;
  unsigned* h1p2 = h1A2; unsigned* h1n2 = h1B2;

  for (int t = 0; t < T; t++){
    // ======== layer 0 ========
    {
      int c = (w + gB + t) & 15;
      const unsigned* sp = h0p2 + c*1024 + b;
      float acc[8] = {0,0,0,0,0,0,0,0};
      #pragma unroll 8
      for (int j = 0; j < 32; j++){
        U32H2 sv; sv.u = sp[j*32];
        int k2 = c*32 + j;
        #pragma unroll
        for (int r = 0; r < 8; r++)
          acc[r] = dot2(w0s[rh*8 + r][k2], sv.h, acc[r]);
      }
      #pragma unroll
      for (int r = 0; r < 8; r++) partial[w][rh*8 + r][b] = acc[r];
    }
    __syncthreads();
    if (tid < 512){
      int r = tid >> 5, bb = tid & 31;
      float s = 0.f;
      #pragma unroll
      for (int w2 = 0; w2 < 16; w2++) s += partial[w2][r][bb];
      int q = r >> 2, hl = r & 3;
      float v = s + xg0[((long)t*G4 + (long)q*H + 4*gB + hl)*32 + bb];
      gates[r][bb] = (q == 2) ? tanhf(v) : sigm(v);
    }
    __syncthreads();
    if (tid < 64){
      int hp = tid >> 5, bb = tid & 31;
      float hn0, hn1;
      {
        int hl = 2*hp;
        float cn = gates[4+hl][bb]*cst[0][hl][bb] + gates[0+hl][bb]*gates[8+hl][bb];
        cst[0][hl][bb] = cn;
        hn0 = gates[12+hl][bb]*tanhf(cn);
      }
      {
        int hl = 2*hp + 1;
        float cn = gates[4+hl][bb]*cst[0][hl][bb] + gates[0+hl][bb]*gates[8+hl][bb];
        cst[0][hl][bb] = cn;
        hn1 = gates[12+hl][bb]*tanhf(cn);
      }
      U32H2 uu; uu.h = pk2(hn0, hn1);
      h0n2[(2*gB + hp)*32 + bb] = uu.u;
    }
    gbar(bar, ep); ep += NB;

    // ======== layer 1 ========
    {
      int c = (w + gB + t) & 15;
      const unsigned* sa = h0n2 + c*1024 + b;
      const unsigned* sb = h1p2 + c*1024 + b;
      float acc[8] = {0,0,0,0,0,0,0,0};
      #pragma unroll 4
      for (int j = 0; j < 32; j++){
        U32H2 ua; ua.u = sa[j*32];
        U32H2 ub; ub.u = sb[j*32];
        int k2 = c*32 + j;
        #pragma unroll
        for (int r = 0; r < 8; r++){
          float x = dot2(w1s[rh*8 + r][k2], ua.h, acc[r]);
          acc[r] = dot2(w1s[16 + rh*8 + r][k2], ub.h, x);
        }
      }
      #pragma unroll
      for (int r = 0; r < 8; r++) partial[w][rh*8 + r][b] = acc[r];
    }
    __syncthreads();
    if (tid < 512){
      int r = tid >> 5, bb = tid & 31;
      float s = 0.f;
      #pragma unroll
      for (int w2 = 0; w2 < 16; w2++) s += partial[w2][r][bb];
      int q = r >> 2;
      float v = s + bs1v[r];
      gates[r][bb] = (q == 2) ? tanhf(v) : sigm(v);
    }
    __syncthreads();
    if (tid < 64){
      int hp = tid >> 5, bb = tid & 31;
      float hn0, hn1;
      {
        int hl = 2*hp;
        float cn = gates[4+hl][bb]*cst[1][hl][bb] + gates[0+hl][bb]*gates[8+hl][bb];
        cst[1][hl][bb] = cn;
        hn0 = gates[12+hl][bb]*tanhf(cn);
        h1loc[hl][bb*T + t] = (__fp16)hn0;
      }
      {
        int hl = 2*hp + 1;
        float cn = gates[4+hl][bb]*cst[1][hl][bb] + gates[0+hl][bb]*gates[8+hl][bb];
        cst[1][hl][bb] = cn;
        hn1 = gates[12+hl][bb]*tanhf(cn);
        h1loc[hl][bb*T + t] = (__fp16)hn1;
      }
      U32H2 uu; uu.h = pk2(hn0, hn1);
      h1n2[(2*gB + hp)*32 + bb] = uu.u;
    }
    gbar(bar, ep); ep += NB;

    unsigned* tp;
    tp = h0p2; h0p2 = h0n2; h0n2 = tp;
    tp = h1p2; h1p2 = h1n2; h1n2 = tp;
  }

  // coalesced H1T flush
  for (int hl = 0; hl < 4; hl++)
    for (int m = tid; m < B*T; m += 1024)
      H1T[(long)(4*gB + hl)*MPAD + m] = (float)h1loc[hl][m];
}

// ---------------- fallback per-step cells (verified) ----------------
__global__ void k_init(const float* __restrict__ enc, float* __restrict__ h0, float* __restrict__ c0,
                       float* __restrict__ h1, float* __restrict__ c1){
  int idx = blockIdx.x*256 + threadIdx.x;
  int b = idx & 31, h = idx >> 5;
  float v = enc[b*H + h];
  h0[idx]=v; c0[idx]=v; h1[idx]=v; c1[idx]=v;
}

__global__ __launch_bounds__(256) void k_cell0(const float* __restrict__ whh, const float* __restrict__ xg_t,
                       const float* __restrict__ h_in, float* __restrict__ h_out,
                       float* __restrict__ c){
  int h = (blockIdx.x*256 + threadIdx.x) >> 6;
  int lane = threadIdx.x & 63;
  int b = lane & 31, kh = lane >> 5;
  const float* w0 = whh + (0*H + h)*H + kh*512;
  const float* w1 = whh + (1*H + h)*H + kh*512;
  const float* w2 = whh + (2*H + h)*H + kh*512;
  const float* w3 = whh + (3*H + h)*H + kh*512;
  const float* hk = h_in + (kh*512)*B + b;
  float a0=0,a1=0,a2=0,a3=0, p0=0,p1=0,p2=0,p3=0;
  #pragma unroll 4
  for (int k=0;k<512;k+=4){
    float4 w40 = *(const float4*)(w0+k);
    float4 w41 = *(const float4*)(w1+k);
    float4 w42 = *(const float4*)(w2+k);
    float4 w43 = *(const float4*)(w3+k);
    float hv0 = hk[(k+0)*B], hv1 = hk[(k+1)*B], hv2 = hk[(k+2)*B], hv3 = hk[(k+3)*B];
    a0 += w40.x*hv0 + w40.y*hv1;  p0 += w40.z*hv2 + w40.w*hv3;
    a1 += w41.x*hv0 + w41.y*hv1;  p1 += w41.z*hv2 + w41.w*hv3;
    a2 += w42.x*hv0 + w42.y*hv1;  p2 += w42.z*hv2 + w42.w*hv3;
    a3 += w43.x*hv0 + w43.y*hv1;  p3 += w43.z*hv2 + w43.w*hv3;
  }
  float g0=a0+p0, g1=a1+p1, g2=a2+p2, g3=a3+p3;
  g0 += __shfl_xor(g0, 32);
  g1 += __shfl_xor(g1, 32);
  g2 += __shfl_xor(g2, 32);
  g3 += __shfl_xor(g3, 32);
  g0 += xg_t[(0*H+h)*B + b];
  g1 += xg_t[(1*H+h)*B + b];
  g2 += xg_t[(2*H+h)*B + b];
  g3 += xg_t[(3*H+h)*B + b];
  float ig = sigm(g0), fg = sigm(g1), gg = tanhf(g2), og = sigm(g3);
  int sidx = h*B + b;
  float cn = fg*c[sidx] + ig*gg;
  float hn = og*tanhf(cn);
  if (kh==0){ c[sidx]=cn; h_out[sidx]=hn; }
}

__global__ __launch_bounds__(256) void k_cell1(const float* __restrict__ wih, const float* __restrict__ whh,
                       const float* __restrict__ bih, const float* __restrict__ bhh,
                       const float* __restrict__ h0n, const float* __restrict__ h_in,
                       float* __restrict__ h_out, float* __restrict__ c,
                       float* __restrict__ H1T, int t){
  int h = (blockIdx.x*256 + threadIdx.x) >> 6;
  int lane = threadIdx.x & 63;
  int b = lane & 31, kh = lane >> 5;
  float a0=0,a1=0,a2=0,a3=0, p0=0,p1=0,p2=0,p3=0;
  {
    const float* w0 = wih + (0*H + h)*H + kh*512;
    const float* w1 = wih + (1*H + h)*H + kh*512;
    const float* w2 = wih + (2*H + h)*H + kh*512;
    const float* w3 = wih + (3*H + h)*H + kh*512;
    const float* hk = h0n + (kh*512)*B + b;
    #pragma unroll 4
    for (int k=0;k<512;k+=4){
      float4 w40 = *(const float4*)(w0+k);
      float4 w41 = *(const float4*)(w1+k);
      float4 w42 = *(const float4*)(w2+k);
      float4 w43 = *(const float4*)(w3+k);
      float hv0 = hk[(k+0)*B], hv1 = hk[(k+1)*B], hv2 = hk[(k+2)*B], hv3 = hk[(k+3)*B];
      a0 += w40.x*hv0 + w40.y*hv1;  p0 += w40.z*hv2 + w40.w*hv3;
      a1 += w41.x*hv0 + w41.y*hv1;  p1 += w41.z*hv2 + w41.w*hv3;
      a2 += w42.x*hv0 + w42.y*hv1;  p2 += w42.z*hv2 + w42.w*hv3;
      a3 += w43.x*hv0 + w43.y*hv1;  p3 += w43.z*hv2 + w43.w*hv3;
    }
  }
  {
    const float* w0 = whh + (0*H + h)*H + kh*512;
    const float* w1 = whh + (1*H + h)*H + kh*512;
    const float* w2 = whh + (2*H + h)*H + kh*512;
    const float* w3 = whh + (3*H + h)*H + kh*512;
    const float* hk = h_in + (kh*512)*B + b;
    #pragma unroll 4
    for (int k=0;k<512;k+=4){
      float4 w40 = *(const float4*)(w0+k);
      float4 w41 = *(const float4*)(w1+k);
      float4 w42 = *(const float4*)(w2+k);
      float4 w43 = *(const float4*)(w3+k);
      float hv0 = hk[(k+0)*B], hv1 = hk[(k+1)*B], hv2 = hk[(k+2)*B], hv3 = hk[(k+3)*B];
      a0 += w40.x*hv0 + w40.y*hv1;  p0 += w40.z*hv2 + w40.w*hv3;
      a1 += w41.x*hv0 + w41.y*hv1;  p1 += w41.z*hv2 + w41.w*hv3;
      a2 += w42.x*hv0 + w42.y*hv1;  p2 += w42.z*hv2 + w42.w*hv3;
      a3 += w43.x*hv0 + w43.y*hv1;  p3 += w43.z*hv2 + w43.w*hv3;
    }
  }
  float g0=a0+p0, g1=a1+p1, g2=a2+p2, g3=a3+p3;
  g0 += __shfl_xor(g0, 32);
  g1 += __shfl_xor(g1, 32);
  g2 += __shfl_xor(g2, 32);
  g3 += __shfl_xor(g3, 32);
  g0 += bih[0*H+h] + bhh[0*H+h];
  g1 += bih[1*H+h] + bhh[1*H+h];
  g2 += bih[2*H+h] + bhh[2*H+h];
  g3 += bih[3*H+h] + bhh[3*H+h];
  float ig = sigm(g0), fg = sigm(g1), gg = tanhf(g2), og = sigm(g3);
  int sidx = h*B + b;
  float cn = fg*c[sidx] + ig*gg;
  float hn = og*tanhf(cn);
  if (kh==0){ c[sidx]=cn; h_out[sidx]=hn; H1T[(long)h*MPAD + b*T + t] = hn; }
}

// ---------------- output GEMM + log-softmax ----------------
#define GBM 128
#define GBN 128
#define GBK 32
__global__ __launch_bounds__(256, 4) void k_gemm(const float* __restrict__ A,
                      const float* __restrict__ lw, const float* __restrict__ lb,
                      float* __restrict__ out){
  __shared__ float As[GBK][GBM];
  __shared__ float Ws[GBK][GBN];
  const int tid = threadIdx.x;
  int orig = blockIdx.x;
  int xcd = orig & 7, ii = orig >> 3;
  int wgid = (xcd < 2 ? xcd*407 : 814 + (xcd-2)*406) + ii;
  int bm = wgid % 13, bn = wgid / 13;
  int m0 = bm*GBM, n0 = bn*GBN;
  int tx = tid & 15, ty = tid >> 4;
  float acc[8][8] = {};
  for (int k0 = 0; k0 < H; k0 += GBK){
    #pragma unroll
    for (int it=0; it<4; it++){
      int idx = tid + it*256;
      int k_l = idx >> 5, m4 = (idx & 31)*4;
      float4 v = *(const float4*)(A + (k0+k_l)*MPAD + m0 + m4);
      *(float4*)&As[k_l][m4] = v;
    }
    #pragma unroll
    for (int it=0; it<4; it++){
      int idx = tid + it*256;
      int n_l = idx >> 3, kq = idx & 7;
      float4 v = *(const float4*)(lw + (long)(n0+n_l)*H + k0 + kq*4);
      int sw = kq << 2;
      Ws[kq*4+0][n_l ^ sw] = v.x;
      Ws[kq*4+1][n_l ^ sw] = v.y;
      Ws[kq*4+2][n_l ^ sw] = v.z;
      Ws[kq*4+3][n_l ^ sw] = v.w;
    }
    __syncthreads();
    #pragma unroll
    for (int k=0;k<GBK;k++){
      int sw = (k >> 2) << 2;
      float4 a0 = *(const float4*)&As[k][ty*4];
      float4 a1 = *(const float4*)&As[k][ty*4+64];
      float4 w0 = *(const float4*)&Ws[k][(tx*4) ^ sw];
      float4 w1 = *(const float4*)&Ws[k][((tx*4) ^ sw) + 64];
      float am[8] = {a0.x,a0.y,a0.z,a0.w,a1.x,a1.y,a1.z,a1.w};
      float wn[8] = {w0.x,w0.y,w0.z,w0.w,w1.x,w1.y,w1.z,w1.w};
      #pragma unroll
      for (int im=0;im<8;im++)
        #pragma unroll
        for (int in=0;in<8;in++)
          acc[im][in] += am[im]*wn[in];
    }
    __syncthreads();
  }
  float4 b0 = *(const float4*)(lb + n0 + tx*4);
  float4 b1 = *(const float4*)(lb + n0 + tx*4 + 64);
  #pragma unroll
  for (int im=0;im<8;im++){
    int m = m0 + (im>>2)*64 + ty*4 + (im&3);
    if (m < B*T){
      float* orow = out + (long)m*V + n0;
      float4 o0, o1;
      o0.x = acc[im][0]+b0.x; o0.y = acc[im][1]+b0.y; o0.z = acc[im][2]+b0.z; o0.w = acc[im][3]+b0.w;
      o1.x = acc[im][4]+b1.x; o1.y = acc[im][5]+b1.y; o1.z = acc[im][6]+b1.z; o1.w = acc[im][7]+b1.w;
      *(float4*)(orow + tx*4) = o0;
      *(float4*)(orow + tx*4 + 64) = o1;
    }
  }
}

__global__ __launch_bounds__(256) void k_lsm(float* __restrict__ out){
  __shared__ float red[256];
  float4* row = (float4*)(out + (long)blockIdx.x * V);
  const int tid = threadIdx.x;
  float m = -INFINITY;
  for (int n=tid;n<V/4;n+=256){
    float4 v = row[n];
    m = fmaxf(m, fmaxf(fmaxf(v.x,v.y), fmaxf(v.z,v.w)));
  }
  red[tid]=m; __syncthreads();
  for (int s=128;s>0;s>>=1){ if(tid<s) red[tid]=fmaxf(red[tid],red[tid+s]); __syncthreads(); }
  m = red[0]; __syncthreads();
  float s = 0.f;
  for (int n=tid;n<V/4;n+=256){
    float4 v = row[n];
    s += expf(v.x-m)+expf(v.y-m)+expf(v.z-m)+expf(v.w-m);
  }
  red[tid]=s; __syncthreads();
  for (int st=128;st>0;st>>=1){ if(tid<st) red[tid]+=red[tid+st]; __syncthreads(); }
  float lse = m + logf(red[0]);
  for (int n=tid;n<V/4;n+=256){
    float4 v = row[n];
    v.x-=lse; v.y-=lse; v.z-=lse; v.w-=lse;
    row[n] = v;
  }
}

extern "C" void kernel_launch(void* const* d_in, const int* in_sizes, int n_in,
                              void* d_out, int out_size, void* d_ws, size_t ws_size,
                              hipStream_t stream){
  const float* enc    = (const float*)d_in[0];
  const float* target = (const float*)d_in[1];
  const float* pw     = (const float*)d_in[2];
  const float* pb     = (const float*)d_in[3];
  const float* wih0   = (const float*)d_in[4];
  const float* whh0   = (const float*)d_in[5];
  const float* bih0   = (const float*)d_in[6];
  const float* bhh0   = (const float*)d_in[7];
  const float* wih1   = (const float*)d_in[8];
  const float* whh1   = (const float*)d_in[9];
  const float* bih1   = (const float*)d_in[10];
  const float* bhh1   = (const float*)d_in[11];
  const float* lw     = (const float*)d_in[12];
  const float* lb     = (const float*)d_in[13];
  float* out = (float*)d_out;

  float* ws   = (float*)d_ws;
  float* xg0  = ws;                        // 6,553,600 f
  float* P    = xg0 + (long)T*G4*B;        // 204,800 f
  float* encp = P + T*E*B;                 // 4,096 f
  float* H1T  = encp + B*E;                // 1,703,936 f
  unsigned* h0A2 = (unsigned*)(H1T + (long)H*MPAD);  // 16,384 u each
  unsigned* h0B2 = h0A2 + 16384;
  unsigned* h1A2 = h0B2 + 16384;
  unsigned* h1B2 = h1A2 + 16384;
  float* fh0a = (float*)(h1B2 + 16384);    // fallback f32 state
  float* fh0b = fh0a + H*B;
  float* fh1a = fh0b + H*B;
  float* fh1b = fh1a + H*B;
  float* fc0  = fh1b + H*B;
  float* fc1  = fc0 + H*B;
  unsigned* bar = (unsigned*)(fc1 + H*B);

  k_encp<<<B, E, 0, stream>>>(enc, pw, pb, encp);
  k_proj<<<T*B, E, 0, stream>>>(target, pw, encp, P);
  k_xg0<<<(T*G4*B)/256, 256, 0, stream>>>(wih0, bih0, bhh0, P, xg0);
  k_fill<<<(H*MPAD)/256, 256, 0, stream>>>(H1T);
  k_zero<<<1, 1, 0, stream>>>(bar);

  void* cargs[] = {(void*)&whh0, (void*)&wih1, (void*)&whh1, (void*)&bih1, (void*)&bhh1,
                   (void*)&enc, (void*)&xg0,
                   (void*)&h0A2, (void*)&h0B2, (void*)&h1A2, (void*)&h1B2,
                   (void*)&H1T, (void*)&bar};
  hipError_t cerr = hipLaunchCooperativeKernel((void*)k_cells, dim3(NB), dim3(1024),
                                               cargs, 0, stream);
  if (cerr != hipSuccess){
    k_init<<<(H*B)/256, 256, 0, stream>>>(enc, fh0a, fc0, fh1a, fc1);
    float* h0in=fh0a; float* h0out=fh0b;
    float* h1in=fh1a; float* h1out=fh1b;
    for (int t=0;t<T;t++){
      k_cell0<<<256, 256, 0, stream>>>(whh0, xg0 + (long)t*G4*B, h0in, h0out, fc0);
      k_cell1<<<256, 256, 0, stream>>>(wih1, whh1, bih1, bhh1, h0out, h1in, h1out, fc1,
                                       H1T, t);
      float* tmp;
      tmp=h0in; h0in=h0out; h0out=tmp;
      tmp=h1in; h1in=h1out; h1out=tmp;
    }
  }

  k_gemm<<<3250, 256, 0, stream>>>(H1T, lw, lb, out);
  k_lsm<<<B*T, 256, 0, stream>>>(out);
}

// Round 7
// 1951.202 us; speedup vs baseline: 8.8952x; 1.5356x over previous
//
#include <hip/hip_runtime.h>
#include <hip/hip_bf16.h>
#include <math.h>

#define B 32
#define T 50
#define H 1024
#define E 128
#define V 32000
#define G4 4096   // 4*H
#define HE 1152   // H+E
#define MROWS 1664 // 13*128 padded M for GEMM
#define NB 256    // coop grid blocks

typedef __fp16 half2v __attribute__((ext_vector_type(2)));
union U32H2 { unsigned u; half2v h; };
typedef short short8 __attribute__((ext_vector_type(8)));
typedef float floatx4 __attribute__((ext_vector_type(4)));
union U16S8 { uint4 u4; short8 s8; };

__device__ __forceinline__ float sigm(float x){ return 1.0f/(1.0f+expf(-x)); }

__device__ __forceinline__ half2v pk2(float a, float b){
#if __has_builtin(__builtin_amdgcn_cvt_pkrtz)
  return __builtin_amdgcn_cvt_pkrtz(a, b);
#else
  half2v r; r.x = (__fp16)a; r.y = (__fp16)b; return r;
#endif
}

__device__ __forceinline__ float dot2(half2v a, half2v b, float c){
#if __has_builtin(__builtin_amdgcn_fdot2)
  return __builtin_amdgcn_fdot2(a, b, c, false);
#else
  return c + (float)a.x*(float)b.x + (float)a.y*(float)b.y;
#endif
}

// pack two f32 -> one u32 of two bf16 (RNE)
__device__ __forceinline__ unsigned pkbf(float a, float b){
  unsigned ua = __float_as_uint(a), ub = __float_as_uint(b);
  unsigned ra = (ua + 0x7FFFu + ((ua>>16)&1u)) >> 16;
  unsigned rb = (ub + 0x7FFFu + ((ub>>16)&1u)) >> 16;
  return ra | (rb << 16);
}

// ---- two-level tree grid barrier: 8 leaves x 32 blocks + root ----
// bar[0]=root, bar[64+g*64]=leaf g. ep is the 1-based epoch number.
__device__ __forceinline__ void gbar(unsigned* bar, unsigned ep){
  __syncthreads();
  if (threadIdx.x == 0){
    __builtin_amdgcn_fence(__ATOMIC_RELEASE, "agent");
    unsigned g = blockIdx.x & 7u;
    unsigned old = __hip_atomic_fetch_add(&bar[64 + g*64], 1u,
                     __ATOMIC_RELAXED, __HIP_MEMORY_SCOPE_AGENT);
    if (old == ep*32u - 1u)
      __hip_atomic_fetch_add(&bar[0], 1u, __ATOMIC_RELAXED, __HIP_MEMORY_SCOPE_AGENT);
    while (__hip_atomic_load(&bar[0], __ATOMIC_RELAXED, __HIP_MEMORY_SCOPE_AGENT) < ep*8u)
      __builtin_amdgcn_s_sleep(1);
    __builtin_amdgcn_fence(__ATOMIC_ACQUIRE, "agent");
  }
  __syncthreads();
}

// encp[b][e] = proj_b[e] + sum_j enc[b][j] * proj_w[e][E+j]
__global__ void k_encp(const float* __restrict__ enc, const float* __restrict__ pw,
                       const float* __restrict__ pb, float* __restrict__ encp){
  int b = blockIdx.x, e = threadIdx.x;
  const float* er = enc + b*H;
  const float* wr = pw + e*HE + E;
  float acc = pb[e];
  for (int j=0;j<H;j+=4){
    float4 w4 = *(const float4*)(wr+j);
    float4 e4 = *(const float4*)(er+j);
    acc += w4.x*e4.x + w4.y*e4.y + w4.z*e4.z + w4.w*e4.w;
  }
  encp[b*E+e] = acc;
}

// P[t][e][b] = encp[b][e] + sum_j target[b][t][j] * proj_w[e][j]
__global__ void k_proj(const float* __restrict__ target, const float* __restrict__ pw,
                       const float* __restrict__ encp, float* __restrict__ P){
  int t = blockIdx.x / B, b = blockIdx.x % B, e = threadIdx.x;
  const float* xr = target + (b*T + t)*E;
  const float* wr = pw + e*HE;
  float acc = encp[b*E+e];
  for (int j=0;j<E;j+=4){
    float4 w4 = *(const float4*)(wr+j);
    float4 x4 = *(const float4*)(xr+j);
    acc += w4.x*x4.x + w4.y*x4.y + w4.z*x4.z + w4.w*x4.w;
  }
  P[(t*E + e)*B + b] = acc;
}

// xg0[t][r][b] = b_ih0[r]+b_hh0[r] + sum_e w_ih0[r][e] * P[t][e][b]
__global__ void k_xg0(const float* __restrict__ wih0, const float* __restrict__ bih0,
                      const float* __restrict__ bhh0, const float* __restrict__ P,
                      float* __restrict__ xg){
  int idx = blockIdx.x*256 + threadIdx.x;
  int b = idx & 31; int r = (idx >> 5) & 4095; int t = idx >> 17;
  const float* wr = wih0 + r*E;
  const float* pr = P + t*E*B + b;
  float acc = bih0[r] + bhh0[r];
  #pragma unroll 8
  for (int e=0;e<E;e++) acc += wr[e] * pr[e*B];
  xg[idx] = acc;
}

__global__ void k_fill(float* __restrict__ p){
  p[blockIdx.x*256 + threadIdx.x] = 0.f;
}

__global__ void k_zero(unsigned* __restrict__ bar){
  bar[blockIdx.x*256 + threadIdx.x] = 0u;
}

// ---------------- cooperative persistent cells (v4) ----------------
// 256 blocks x 1024 thr. Block owns 4 h-units; weights f16 in LDS.
// 16 waves partition K; state f16-pair packed [k2][b] global; tree barrier;
// xg0 prefetched at phase start. Flush writes H1Tmk f32 [m=b*T+t][k=h].
__global__ __launch_bounds__(1024, 4) void k_cells(
    const float* __restrict__ whh0, const float* __restrict__ wih1, const float* __restrict__ whh1,
    const float* __restrict__ bih1, const float* __restrict__ bhh1,
    const float* __restrict__ enc, const float* __restrict__ xg0,
    unsigned* __restrict__ h0A2, unsigned* __restrict__ h0B2,
    unsigned* __restrict__ h1A2, unsigned* __restrict__ h1B2,
    float* __restrict__ H1Tmk, unsigned* __restrict__ bar){
  const int gB = blockIdx.x;
  const int tid = threadIdx.x;
  const int w = tid >> 6;       // wave 0..15 = k-chunk owner
  const int l = tid & 63;
  const int b = l & 31;
  const int rh = l >> 5;        // row-half: rows rh*8..rh*8+7

  __shared__ half2v w0s[16][512];        // layer0 whh0 rows (32 KB)
  __shared__ half2v w1s[32][512];        // wih1(0-15) + whh1(16-31) (64 KB)
  __shared__ float partial[16][16][32];  // [wave][row][b] (32 KB)
  __shared__ float gates[16][32];        // [q*4+hl][b]
  __shared__ float cst[2][4][32];
  __shared__ float bs1v[16];
  __shared__ __fp16 h1loc[4][1600];      // [hl][b*T+t] (12.8 KB)

  // ---- stage weights f32 -> f16 pairs ----
  for (int i = tid; i < 16*512; i += 1024){
    int r = i >> 9, k2 = i & 511;
    int q = r >> 2, hl = r & 3;
    float2 v = *(const float2*)(whh0 + ((long)q*H + 4*gB + hl)*H + 2*k2);
    w0s[r][k2] = pk2(v.x, v.y);
  }
  for (int i = tid; i < 32*512; i += 1024){
    int r = i >> 9, k2 = i & 511;
    int rr = r & 15;
    int q = rr >> 2, hl = rr & 3;
    const float* srcm = (r < 16) ? wih1 : whh1;
    float2 v = *(const float2*)(srcm + ((long)q*H + 4*gB + hl)*H + 2*k2);
    w1s[r][k2] = pk2(v.x, v.y);
  }
  if (tid < 16){
    int q = tid >> 2, hl = tid & 3;
    bs1v[tid] = bih1[q*H + 4*gB + hl] + bhh1[q*H + 4*gB + hl];
  }
  if (tid < 128){
    int hl = tid >> 5, bb = tid & 31;
    float v = enc[bb*H + 4*gB + hl];
    cst[0][hl][bb] = v; cst[1][hl][bb] = v;
  }
  if (tid < 64){
    int hp = tid >> 5, bb = tid & 31;
    U32H2 uu;
    uu.h = pk2(enc[bb*H + 4*gB + 2*hp], enc[bb*H + 4*gB + 2*hp + 1]);
    h0A2[(2*gB + hp)*32 + bb] = uu.u;
    h1A2[(2*gB + hp)*32 + bb] = uu.u;
  }
  unsigned ep = 1;
  gbar(bar, ep); ep++;

  unsigned* h0p2 = h0A2; unsigned* h0n2 = h0B2;
  unsigned* h1p2 = h1A2; unsigned* h1n2 = h1B2;

  for (int t = 0; t < T; t++){
    // ======== layer 0 ========
    // prefetch xg0 for this step (constant data -> race-free)
    float xgv = 0.f;
    if (tid < 512){
      int r = tid >> 5, bb = tid & 31;
      int q = r >> 2, hl = r & 3;
      xgv = xg0[((long)t*G4 + (long)q*H + 4*gB + hl)*32 + bb];
    }
    {
      int c = (w + gB + t) & 15;
      const unsigned* sp = h0p2 + c*1024 + b;
      float acc[8] = {0,0,0,0,0,0,0,0};
      #pragma unroll 8
      for (int j = 0; j < 32; j++){
        U32H2 sv; sv.u = sp[j*32];
        int k2 = c*32 + j;
        #pragma unroll
        for (int r = 0; r < 8; r++)
          acc[r] = dot2(w0s[rh*8 + r][k2], sv.h, acc[r]);
      }
      #pragma unroll
      for (int r = 0; r < 8; r++) partial[w][rh*8 + r][b] = acc[r];
    }
    __syncthreads();
    if (tid < 512){
      int r = tid >> 5, bb = tid & 31;
      float s = 0.f;
      #pragma unroll
      for (int w2 = 0; w2 < 16; w2++) s += partial[w2][r][bb];
      int q = r >> 2;
      float v = s + xgv;
      gates[r][bb] = (q == 2) ? tanhf(v) : sigm(v);
    }
    __syncthreads();
    if (tid < 64){
      int hp = tid >> 5, bb = tid & 31;
      float hn0, hn1;
      {
        int hl = 2*hp;
        float cn = gates[4+hl][bb]*cst[0][hl][bb] + gates[0+hl][bb]*gates[8+hl][bb];
        cst[0][hl][bb] = cn;
        hn0 = gates[12+hl][bb]*tanhf(cn);
      }
      {
        int hl = 2*hp + 1;
        float cn = gates[4+hl][bb]*cst[0][hl][bb] + gates[0+hl][bb]*gates[8+hl][bb];
        cst[0][hl][bb] = cn;
        hn1 = gates[12+hl][bb]*tanhf(cn);
      }
      U32H2 uu; uu.h = pk2(hn0, hn1);
      h0n2[(2*gB + hp)*32 + bb] = uu.u;
    }
    gbar(bar, ep); ep++;

    // ======== layer 1 ========
    {
      int c = (w + gB + t) & 15;
      const unsigned* sa = h0n2 + c*1024 + b;
      const unsigned* sb = h1p2 + c*1024 + b;
      float acc[8] = {0,0,0,0,0,0,0,0};
      #pragma unroll 4
      for (int j = 0; j < 32; j++){
        U32H2 ua; ua.u = sa[j*32];
        U32H2 ub; ub.u = sb[j*32];
        int k2 = c*32 + j;
        #pragma unroll
        for (int r = 0; r < 8; r++){
          float x = dot2(w1s[rh*8 + r][k2], ua.h, acc[r]);
          acc[r] = dot2(w1s[16 + rh*8 + r][k2], ub.h, x);
        }
      }
      #pragma unroll
      for (int r = 0; r < 8; r++) partial[w][rh*8 + r][b] = acc[r];
    }
    __syncthreads();
    if (tid < 512){
      int r = tid >> 5, bb = tid & 31;
      float s = 0.f;
      #pragma unroll
      for (int w2 = 0; w2 < 16; w2++) s += partial[w2][r][bb];
      int q = r >> 2;
      float v = s + bs1v[r];
      gates[r][bb] = (q == 2) ? tanhf(v) : sigm(v);
    }
    __syncthreads();
    if (tid < 64){
      int hp = tid >> 5, bb = tid & 31;
      float hn0, hn1;
      {
        int hl = 2*hp;
        float cn = gates[4+hl][bb]*cst[1][hl][bb] + gates[0+hl][bb]*gates[8+hl][bb];
        cst[1][hl][bb] = cn;
        hn0 = gates[12+hl][bb]*tanhf(cn);
        h1loc[hl][bb*T + t] = (__fp16)hn0;
      }
      {
        int hl = 2*hp + 1;
        float cn = gates[4+hl][bb]*cst[1][hl][bb] + gates[0+hl][bb]*gates[8+hl][bb];
        cst[1][hl][bb] = cn;
        hn1 = gates[12+hl][bb]*tanhf(cn);
        h1loc[hl][bb*T + t] = (__fp16)hn1;
      }
      U32H2 uu; uu.h = pk2(hn0, hn1);
      h1n2[(2*gB + hp)*32 + bb] = uu.u;
    }
    gbar(bar, ep); ep++;

    unsigned* tp;
    tp = h0p2; h0p2 = h0n2; h0n2 = tp;
    tp = h1p2; h1p2 = h1n2; h1n2 = tp;
  }

  // H1Tmk flush: row m = b*T+t, 4 contiguous k = 4gB..4gB+3 (16B store)
  for (int m = tid; m < B*T; m += 1024){
    float4 v;
    v.x = (float)h1loc[0][m]; v.y = (float)h1loc[1][m];
    v.z = (float)h1loc[2][m]; v.w = (float)h1loc[3][m];
    *(float4*)&H1Tmk[(long)m*1024 + 4*gB] = v;
  }
}

// ---------------- fallback per-step cells (verified) ----------------
__global__ void k_init(const float* __restrict__ enc, float* __restrict__ h0, float* __restrict__ c0,
                       float* __restrict__ h1, float* __restrict__ c1){
  int idx = blockIdx.x*256 + threadIdx.x;
  int b = idx & 31, h = idx >> 5;
  float v = enc[b*H + h];
  h0[idx]=v; c0[idx]=v; h1[idx]=v; c1[idx]=v;
}

__global__ __launch_bounds__(256) void k_cell0(const float* __restrict__ whh, const float* __restrict__ xg_t,
                       const float* __restrict__ h_in, float* __restrict__ h_out,
                       float* __restrict__ c){
  int h = (blockIdx.x*256 + threadIdx.x) >> 6;
  int lane = threadIdx.x & 63;
  int b = lane & 31, kh = lane >> 5;
  const float* w0 = whh + (0*H + h)*H + kh*512;
  const float* w1 = whh + (1*H + h)*H + kh*512;
  const float* w2 = whh + (2*H + h)*H + kh*512;
  const float* w3 = whh + (3*H + h)*H + kh*512;
  const float* hk = h_in + (kh*512)*B + b;
  float a0=0,a1=0,a2=0,a3=0, p0=0,p1=0,p2=0,p3=0;
  #pragma unroll 4
  for (int k=0;k<512;k+=4){
    float4 w40 = *(const float4*)(w0+k);
    float4 w41 = *(const float4*)(w1+k);
    float4 w42 = *(const float4*)(w2+k);
    float4 w43 = *(const float4*)(w3+k);
    float hv0 = hk[(k+0)*B], hv1 = hk[(k+1)*B], hv2 = hk[(k+2)*B], hv3 = hk[(k+3)*B];
    a0 += w40.x*hv0 + w40.y*hv1;  p0 += w40.z*hv2 + w40.w*hv3;
    a1 += w41.x*hv0 + w41.y*hv1;  p1 += w41.z*hv2 + w41.w*hv3;
    a2 += w42.x*hv0 + w42.y*hv1;  p2 += w42.z*hv2 + w42.w*hv3;
    a3 += w43.x*hv0 + w43.y*hv1;  p3 += w43.z*hv2 + w43.w*hv3;
  }
  float g0=a0+p0, g1=a1+p1, g2=a2+p2, g3=a3+p3;
  g0 += __shfl_xor(g0, 32);
  g1 += __shfl_xor(g1, 32);
  g2 += __shfl_xor(g2, 32);
  g3 += __shfl_xor(g3, 32);
  g0 += xg_t[(0*H+h)*B + b];
  g1 += xg_t[(1*H+h)*B + b];
  g2 += xg_t[(2*H+h)*B + b];
  g3 += xg_t[(3*H+h)*B + b];
  float ig = sigm(g0), fg = sigm(g1), gg = tanhf(g2), og = sigm(g3);
  int sidx = h*B + b;
  float cn = fg*c[sidx] + ig*gg;
  float hn = og*tanhf(cn);
  if (kh==0){ c[sidx]=cn; h_out[sidx]=hn; }
}

__global__ __launch_bounds__(256) void k_cell1(const float* __restrict__ wih, const float* __restrict__ whh,
                       const float* __restrict__ bih, const float* __restrict__ bhh,
                       const float* __restrict__ h0n, const float* __restrict__ h_in,
                       float* __restrict__ h_out, float* __restrict__ c,
                       float* __restrict__ H1Tmk, int t){
  int h = (blockIdx.x*256 + threadIdx.x) >> 6;
  int lane = threadIdx.x & 63;
  int b = lane & 31, kh = lane >> 5;
  float a0=0,a1=0,a2=0,a3=0, p0=0,p1=0,p2=0,p3=0;
  {
    const float* w0 = wih + (0*H + h)*H + kh*512;
    const float* w1 = wih + (1*H + h)*H + kh*512;
    const float* w2 = wih + (2*H + h)*H + kh*512;
    const float* w3 = wih + (3*H + h)*H + kh*512;
    const float* hk = h0n + (kh*512)*B + b;
    #pragma unroll 4
    for (int k=0;k<512;k+=4){
      float4 w40 = *(const float4*)(w0+k);
      float4 w41 = *(const float4*)(w1+k);
      float4 w42 = *(const float4*)(w2+k);
      float4 w43 = *(const float4*)(w3+k);
      float hv0 = hk[(k+0)*B], hv1 = hk[(k+1)*B], hv2 = hk[(k+2)*B], hv3 = hk[(k+3)*B];
      a0 += w40.x*hv0 + w40.y*hv1;  p0 += w40.z*hv2 + w40.w*hv3;
      a1 += w41.x*hv0 + w41.y*hv1;  p1 += w41.z*hv2 + w41.w*hv3;
      a2 += w42.x*hv0 + w42.y*hv1;  p2 += w42.z*hv2 + w42.w*hv3;
      a3 += w43.x*hv0 + w43.y*hv1;  p3 += w43.z*hv2 + w43.w*hv3;
    }
  }
  {
    const float* w0 = whh + (0*H + h)*H + kh*512;
    const float* w1 = whh + (1*H + h)*H + kh*512;
    const float* w2 = whh + (2*H + h)*H + kh*512;
    const float* w3 = whh + (3*H + h)*H + kh*512;
    const float* hk = h_in + (kh*512)*B + b;
    #pragma unroll 4
    for (int k=0;k<512;k+=4){
      float4 w40 = *(const float4*)(w0+k);
      float4 w41 = *(const float4*)(w1+k);
      float4 w42 = *(const float4*)(w2+k);
      float4 w43 = *(const float4*)(w3+k);
      float hv0 = hk[(k+0)*B], hv1 = hk[(k+1)*B], hv2 = hk[(k+2)*B], hv3 = hk[(k+3)*B];
      a0 += w40.x*hv0 + w40.y*hv1;  p0 += w40.z*hv2 + w40.w*hv3;
      a1 += w41.x*hv0 + w41.y*hv1;  p1 += w41.z*hv2 + w41.w*hv3;
      a2 += w42.x*hv0 + w42.y*hv1;  p2 += w42.z*hv2 + w42.w*hv3;
      a3 += w43.x*hv0 + w43.y*hv1;  p3 += w43.z*hv2 + w43.w*hv3;
    }
  }
  float g0=a0+p0, g1=a1+p1, g2=a2+p2, g3=a3+p3;
  g0 += __shfl_xor(g0, 32);
  g1 += __shfl_xor(g1, 32);
  g2 += __shfl_xor(g2, 32);
  g3 += __shfl_xor(g3, 32);
  g0 += bih[0*H+h] + bhh[0*H+h];
  g1 += bih[1*H+h] + bhh[1*H+h];
  g2 += bih[2*H+h] + bhh[2*H+h];
  g3 += bih[3*H+h] + bhh[3*H+h];
  float ig = sigm(g0), fg = sigm(g1), gg = tanhf(g2), og = sigm(g3);
  int sidx = h*B + b;
  float cn = fg*c[sidx] + ig*gg;
  float hn = og*tanhf(cn);
  if (kh==0){ c[sidx]=cn; h_out[sidx]=hn; H1Tmk[((long)(b*T + t))*1024 + h] = hn; }
}

// ---------------- MFMA bf16 output GEMM ----------------
// out[m][n] = sum_k A[m][k] * lw[n][k] + lb[n], A = H1Tmk f32 (cvt to bf16 in staging)
__global__ __launch_bounds__(256, 2) void k_gemm(const float* __restrict__ A,
                      const float* __restrict__ lw, const float* __restrict__ lb,
                      float* __restrict__ out){
  __shared__ uint4 As4[128*8];   // [row][seg^(row&7)] 8 bf16 per uint4 (16 KB)
  __shared__ uint4 Ws4[128*8];   // same for lw rows (16 KB)
  const int tid = threadIdx.x;
  // bijective XCD swizzle over 3250 = 2*407 + 6*406
  int orig = blockIdx.x;
  int xcd = orig & 7, ii = orig >> 3;
  int wgid = (xcd < 2 ? xcd*407 : 814 + (xcd-2)*406) + ii;
  int bm = wgid % 13, bn = wgid / 13;
  int m0 = bm*128, n0 = bn*128;
  const int wv = tid >> 6, l = tid & 63;
  const int wm = (wv >> 1)*64, wn = (wv & 1)*64;
  const int lrow = l & 15, lk = l >> 4;   // frag row 0..15, k-block 0..3

  floatx4 acc[4][4] = {};
  for (int k0 = 0; k0 < H; k0 += 64){
    // stage A tile: 128 rows x 64 k (f32 -> bf16)
    #pragma unroll
    for (int it = 0; it < 4; it++){
      int slot = tid + it*256;
      int row = slot >> 3, seg = slot & 7;
      const float4* src = (const float4*)(A + (long)(m0+row)*1024 + k0 + seg*8);
      float4 v0 = src[0], v1 = src[1];
      uint4 pk;
      pk.x = pkbf(v0.x, v0.y); pk.y = pkbf(v0.z, v0.w);
      pk.z = pkbf(v1.x, v1.y); pk.w = pkbf(v1.z, v1.w);
      As4[row*8 + (seg ^ (row & 7))] = pk;
    }
    // stage W tile: 128 rows (n) x 64 k
    #pragma unroll
    for (int it = 0; it < 4; it++){
      int slot = tid + it*256;
      int row = slot >> 3, seg = slot & 7;
      const float4* src = (const float4*)(lw + (long)(n0+row)*1024 + k0 + seg*8);
      float4 v0 = src[0], v1 = src[1];
      uint4 pk;
      pk.x = pkbf(v0.x, v0.y); pk.y = pkbf(v0.z, v0.w);
      pk.z = pkbf(v1.x, v1.y); pk.w = pkbf(v1.z, v1.w);
      Ws4[row*8 + (seg ^ (row & 7))] = pk;
    }
    __syncthreads();
    #pragma unroll
    for (int ks = 0; ks < 2; ks++){
      short8 af[4], bf_[4];
      #pragma unroll
      for (int fi = 0; fi < 4; fi++){
        int row = wm + fi*16 + lrow;
        U16S8 u; u.u4 = As4[row*8 + ((ks*4 + lk) ^ (lrow & 7))];
        af[fi] = u.s8;
      }
      #pragma unroll
      for (int fj = 0; fj < 4; fj++){
        int row = wn + fj*16 + lrow;
        U16S8 u; u.u4 = Ws4[row*8 + ((ks*4 + lk) ^ (lrow & 7))];
        bf_[fj] = u.s8;
      }
      #pragma unroll
      for (int fi = 0; fi < 4; fi++)
        #pragma unroll
        for (int fj = 0; fj < 4; fj++)
          acc[fi][fj] = __builtin_amdgcn_mfma_f32_16x16x32_bf16(af[fi], bf_[fj], acc[fi][fj], 0, 0, 0);
    }
    __syncthreads();
  }
  // epilogue: D[m= wm+fi*16+(l>>4)*4+r][n= wn+fj*16+(l&15)]
  #pragma unroll
  for (int fj = 0; fj < 4; fj++){
    int n = n0 + wn + fj*16 + lrow;
    float bias = lb[n];
    #pragma unroll
    for (int fi = 0; fi < 4; fi++){
      floatx4 av = acc[fi][fj];
      int mb = m0 + wm + fi*16 + lk*4;
      #pragma unroll
      for (int r = 0; r < 4; r++){
        int m = mb + r;
        if (m < B*T) out[(long)m*V + n] = av[r] + bias;
      }
    }
  }
}

__global__ __launch_bounds__(256) void k_lsm(float* __restrict__ out){
  __shared__ float red[256];
  float4* row = (float4*)(out + (long)blockIdx.x * V);
  const int tid = threadIdx.x;
  float m = -INFINITY;
  for (int n=tid;n<V/4;n+=256){
    float4 v = row[n];
    m = fmaxf(m, fmaxf(fmaxf(v.x,v.y), fmaxf(v.z,v.w)));
  }
  red[tid]=m; __syncthreads();
  for (int s=128;s>0;s>>=1){ if(tid<s) red[tid]=fmaxf(red[tid],red[tid+s]); __syncthreads(); }
  m = red[0]; __syncthreads();
  float s = 0.f;
  for (int n=tid;n<V/4;n+=256){
    float4 v = row[n];
    s += expf(v.x-m)+expf(v.y-m)+expf(v.z-m)+expf(v.w-m);
  }
  red[tid]=s; __syncthreads();
  for (int st=128;st>0;st>>=1){ if(tid<st) red[tid]+=red[tid+st]; __syncthreads(); }
  float lse = m + logf(red[0]);
  for (int n=tid;n<V/4;n+=256){
    float4 v = row[n];
    v.x-=lse; v.y-=lse; v.z-=lse; v.w-=lse;
    row[n] = v;
  }
}

extern "C" void kernel_launch(void* const* d_in, const int* in_sizes, int n_in,
                              void* d_out, int out_size, void* d_ws, size_t ws_size,
                              hipStream_t stream){
  const float* enc    = (const float*)d_in[0];
  const float* target = (const float*)d_in[1];
  const float* pw     = (const float*)d_in[2];
  const float* pb     = (const float*)d_in[3];
  const float* wih0   = (const float*)d_in[4];
  const float* whh0   = (const float*)d_in[5];
  const float* bih0   = (const float*)d_in[6];
  const float* bhh0   = (const float*)d_in[7];
  const float* wih1   = (const float*)d_in[8];
  const float* whh1   = (const float*)d_in[9];
  const float* bih1   = (const float*)d_in[10];
  const float* bhh1   = (const float*)d_in[11];
  const float* lw     = (const float*)d_in[12];
  const float* lb     = (const float*)d_in[13];
  float* out = (float*)d_out;

  float* ws   = (float*)d_ws;
  float* xg0  = ws;                        // 6,553,600 f
  float* P    = xg0 + (long)T*G4*B;        // 204,800 f
  float* encp = P + T*E*B;                 // 4,096 f
  float* H1Tmk = encp + B*E;               // MROWS*1024 = 1,703,936 f
  unsigned* h0A2 = (unsigned*)(H1Tmk + (long)MROWS*1024);  // 16,384 u each
  unsigned* h0B2 = h0A2 + 16384;
  unsigned* h1A2 = h0B2 + 16384;
  unsigned* h1B2 = h1A2 + 16384;
  float* fh0a = (float*)(h1B2 + 16384);    // fallback f32 state
  float* fh0b = fh0a + H*B;
  float* fh1a = fh0b + H*B;
  float* fh1b = fh1a + H*B;
  float* fc0  = fh1b + H*B;
  float* fc1  = fc0 + H*B;
  unsigned* bar = (unsigned*)(fc1 + H*B);  // 1024 u

  k_encp<<<B, E, 0, stream>>>(enc, pw, pb, encp);
  k_proj<<<T*B, E, 0, stream>>>(target, pw, encp, P);
  k_xg0<<<(T*G4*B)/256, 256, 0, stream>>>(wih0, bih0, bhh0, P, xg0);
  k_fill<<<(MROWS*1024)/256, 256, 0, stream>>>(H1Tmk);
  k_zero<<<4, 256, 0, stream>>>(bar);

  void* cargs[] = {(void*)&whh0, (void*)&wih1, (void*)&whh1, (void*)&bih1, (void*)&bhh1,
                   (void*)&enc, (void*)&xg0,
                   (void*)&h0A2, (void*)&h0B2, (void*)&h1A2, (void*)&h1B2,
                   (void*)&H1Tmk, (void*)&bar};
  hipError_t cerr = hipLaunchCooperativeKernel((void*)k_cells, dim3(NB), dim3(1024),
                                               cargs, 0, stream);
  if (cerr != hipSuccess){
    k_init<<<(H*B)/256, 256, 0, stream>>>(enc, fh0a, fc0, fh1a, fc1);
    float* h0in=fh0a; float* h0out=fh0b;
    float* h1in=fh1a; float* h1out=fh1b;
    for (int t=0;t<T;t++){
      k_cell0<<<256, 256, 0, stream>>>(whh0, xg0 + (long)t*G4*B, h0in, h0out, fc0);
      k_cell1<<<256, 256, 0, stream>>>(wih1, whh1, bih1, bhh1, h0out, h1in, h1out, fc1,
                                       H1Tmk, t);
      float* tmp;
      tmp=h0in; h0in=h0out; h0out=tmp;
      tmp=h1in; h1in=h1out; h1out=tmp;
    }
  }

  k_gemm<<<3250, 256, 0, stream>>>(H1Tmk, lw, lb, out);
  k_lsm<<<B*T, 256, 0, stream>>>(out);
}

// Round 9
// 1755.930 us; speedup vs baseline: 9.8844x; 1.1112x over previous
//
#include <hip/hip_runtime.h>
#include <hip/hip_bf16.h>
#include <math.h>

#define B 32
#define T 50
#define H 1024
#define E 128
#define V 32000
#define G4 4096   // 4*H
#define HE 1152   // H+E
#define MROWS 1664 // 13*128 padded M for GEMM
#define NB 256    // coop grid blocks

typedef __fp16 half2v __attribute__((ext_vector_type(2)));
union U32H2 { unsigned u; half2v h; };
typedef short short8 __attribute__((ext_vector_type(8)));
typedef float floatx4 __attribute__((ext_vector_type(4)));
union U16S8 { uint4 u4; short8 s8; };

__device__ __forceinline__ float sigm(float x){ return 1.0f/(1.0f+expf(-x)); }

__device__ __forceinline__ half2v pk2(float a, float b){
#if __has_builtin(__builtin_amdgcn_cvt_pkrtz)
  return __builtin_amdgcn_cvt_pkrtz(a, b);
#else
  half2v r; r.x = (__fp16)a; r.y = (__fp16)b; return r;
#endif
}

__device__ __forceinline__ float dot2(half2v a, half2v b, float c){
#if __has_builtin(__builtin_amdgcn_fdot2)
  return __builtin_amdgcn_fdot2(a, b, c, false);
#else
  return c + (float)a.x*(float)b.x + (float)a.y*(float)b.y;
#endif
}

// pack two f32 -> one u32 of two bf16 (RNE)
__device__ __forceinline__ unsigned pkbf(float a, float b){
  unsigned ua = __float_as_uint(a), ub = __float_as_uint(b);
  unsigned ra = (ua + 0x7FFFu + ((ua>>16)&1u)) >> 16;
  unsigned rb = (ub + 0x7FFFu + ((ub>>16)&1u)) >> 16;
  return ra | (rb << 16);
}

// ---- two-level tree grid barrier: 8 leaves x 32 blocks + root ----
__device__ __forceinline__ void gbar(unsigned* bar, unsigned ep){
  __syncthreads();
  if (threadIdx.x == 0){
    __builtin_amdgcn_fence(__ATOMIC_RELEASE, "agent");
    unsigned g = blockIdx.x & 7u;
    unsigned old = __hip_atomic_fetch_add(&bar[64 + g*64], 1u,
                     __ATOMIC_RELAXED, __HIP_MEMORY_SCOPE_AGENT);
    if (old == ep*32u - 1u)
      __hip_atomic_fetch_add(&bar[0], 1u, __ATOMIC_RELAXED, __HIP_MEMORY_SCOPE_AGENT);
    while (__hip_atomic_load(&bar[0], __ATOMIC_RELAXED, __HIP_MEMORY_SCOPE_AGENT) < ep*8u)
      __builtin_amdgcn_s_sleep(1);
    __builtin_amdgcn_fence(__ATOMIC_ACQUIRE, "agent");
  }
  __syncthreads();
}

// encp[b][e] = proj_b[e] + sum_j enc[b][j] * proj_w[e][E+j]
__global__ void k_encp(const float* __restrict__ enc, const float* __restrict__ pw,
                       const float* __restrict__ pb, float* __restrict__ encp){
  int b = blockIdx.x, e = threadIdx.x;
  const float* er = enc + b*H;
  const float* wr = pw + e*HE + E;
  float acc = pb[e];
  for (int j=0;j<H;j+=4){
    float4 w4 = *(const float4*)(wr+j);
    float4 e4 = *(const float4*)(er+j);
    acc += w4.x*e4.x + w4.y*e4.y + w4.z*e4.z + w4.w*e4.w;
  }
  encp[b*E+e] = acc;
}

// P[t][e][b] = encp[b][e] + sum_j target[b][t][j] * proj_w[e][j]
__global__ void k_proj(const float* __restrict__ target, const float* __restrict__ pw,
                       const float* __restrict__ encp, float* __restrict__ P){
  int t = blockIdx.x / B, b = blockIdx.x % B, e = threadIdx.x;
  const float* xr = target + (b*T + t)*E;
  const float* wr = pw + e*HE;
  float acc = encp[b*E+e];
  for (int j=0;j<E;j+=4){
    float4 w4 = *(const float4*)(wr+j);
    float4 x4 = *(const float4*)(xr+j);
    acc += w4.x*x4.x + w4.y*x4.y + w4.z*x4.z + w4.w*x4.w;
  }
  P[(t*E + e)*B + b] = acc;
}

// xg0[t][r][b] = b_ih0[r]+b_hh0[r] + sum_e w_ih0[r][e] * P[t][e][b]
__global__ void k_xg0(const float* __restrict__ wih0, const float* __restrict__ bih0,
                      const float* __restrict__ bhh0, const float* __restrict__ P,
                      float* __restrict__ xg){
  int idx = blockIdx.x*256 + threadIdx.x;
  int b = idx & 31; int r = (idx >> 5) & 4095; int t = idx >> 17;
  const float* wr = wih0 + r*E;
  const float* pr = P + t*E*B + b;
  float acc = bih0[r] + bhh0[r];
  #pragma unroll 8
  for (int e=0;e<E;e++) acc += wr[e] * pr[e*B];
  xg[idx] = acc;
}

__global__ void k_fill(float* __restrict__ p){
  p[blockIdx.x*256 + threadIdx.x] = 0.f;
}

__global__ void k_zero(unsigned* __restrict__ bar){
  bar[blockIdx.x*256 + threadIdx.x] = 0u;
}

// ---------------- cooperative persistent cells (v5: merged phase) ----------------
// 51 phases, ONE gbar each. Phase p: layer1(p-1) + layer0(p) merged matvec
// (shared h0 chunk load, 24 independent dot2 chains), layer0 partial kept in
// registers across the layer1 reduce. Weights f16 LDS; state f16-pair global.
__global__ __launch_bounds__(1024, 4) void k_cells(
    const float* __restrict__ whh0, const float* __restrict__ wih1, const float* __restrict__ whh1,
    const float* __restrict__ bih1, const float* __restrict__ bhh1,
    const float* __restrict__ enc, const float* __restrict__ xg0,
    unsigned* __restrict__ h0A2, unsigned* __restrict__ h0B2,
    unsigned* __restrict__ h1A2, unsigned* __restrict__ h1B2,
    float* __restrict__ H1Tmk, unsigned* __restrict__ bar){
  const int gB = blockIdx.x;
  const int tid = threadIdx.x;
  const int w = tid >> 6;       // wave 0..15 = k-chunk owner
  const int l = tid & 63;
  const int b = l & 31;
  const int rh = l >> 5;        // row-half: rows rh*8..rh*8+7

  __shared__ half2v w0s[16][512];        // layer0 whh0 rows (32 KB)
  __shared__ half2v w1s[32][512];        // wih1(0-15) + whh1(16-31) (64 KB)
  __shared__ float partial[16][16][32];  // [wave][row][b] (32 KB)
  __shared__ float gates[16][32];        // [q*4+hl][b]
  __shared__ float cst[2][4][32];
  __shared__ float bs1v[16];
  __shared__ __fp16 h1loc[4][1600];      // [hl][b*T+t] (12.8 KB)

  // ---- stage weights f32 -> f16 pairs ----
  for (int i = tid; i < 16*512; i += 1024){
    int r = i >> 9, k2 = i & 511;
    int q = r >> 2, hl = r & 3;
    float2 v = *(const float2*)(whh0 + ((long)q*H + 4*gB + hl)*H + 2*k2);
    w0s[r][k2] = pk2(v.x, v.y);
  }
  for (int i = tid; i < 32*512; i += 1024){
    int r = i >> 9, k2 = i & 511;
    int rr = r & 15;
    int q = rr >> 2, hl = rr & 3;
    const float* srcm = (r < 16) ? wih1 : whh1;
    float2 v = *(const float2*)(srcm + ((long)q*H + 4*gB + hl)*H + 2*k2);
    w1s[r][k2] = pk2(v.x, v.y);
  }
  if (tid < 16){
    int q = tid >> 2, hl = tid & 3;
    bs1v[tid] = bih1[q*H + 4*gB + hl] + bhh1[q*H + 4*gB + hl];
  }
  if (tid < 128){
    int hl = tid >> 5, bb = tid & 31;
    float v = enc[bb*H + 4*gB + hl];
    cst[0][hl][bb] = v; cst[1][hl][bb] = v;
  }
  if (tid < 64){
    int hp = tid >> 5, bb = tid & 31;
    U32H2 uu;
    uu.h = pk2(enc[bb*H + 4*gB + 2*hp], enc[bb*H + 4*gB + 2*hp + 1]);
    h0A2[(2*gB + hp)*32 + bb] = uu.u;
    h1A2[(2*gB + hp)*32 + bb] = uu.u;
  }
  unsigned ep = 1;
  gbar(bar, ep); ep++;

  for (int p = 0; p <= T; p++){
    // buffers: X0[par] read; X0[!par] layer0 write; X1[(p-1)&1] read; X1[p&1] write
    const unsigned* h0r = (p & 1) ? h0B2 : h0A2;
    unsigned*       h0w = (p & 1) ? h0A2 : h0B2;
    const unsigned* h1r = (p & 1) ? h1A2 : h1B2;
    unsigned*       h1w = (p & 1) ? h1B2 : h1A2;

    // xg prefetch for layer0(p)
    float xgv = 0.f;
    if (p < T && tid < 512){
      int r = tid >> 5, bb = tid & 31;
      int q = r >> 2, hl = r & 3;
      xgv = xg0[((long)p*G4 + (long)q*H + 4*gB + hl)*32 + bb];
    }

    // ---- merged matvec ----
    float a0[8] = {0,0,0,0,0,0,0,0};
    {
      int c = (w + gB + p) & 15;
      const unsigned* sa = h0r + c*1024 + b;
      const unsigned* sb = h1r + c*1024 + b;
      if (p == 0){
        #pragma unroll 4
        for (int j = 0; j < 32; j++){
          U32H2 ua; ua.u = sa[j*32];
          int k2 = c*32 + j;
          #pragma unroll
          for (int r = 0; r < 8; r++)
            a0[r] = dot2(w0s[rh*8 + r][k2], ua.h, a0[r]);
        }
      } else if (p == T){
        float aI[8] = {0,0,0,0,0,0,0,0}, aH[8] = {0,0,0,0,0,0,0,0};
        #pragma unroll 4
        for (int j = 0; j < 32; j++){
          U32H2 ua; ua.u = sa[j*32];
          U32H2 ub; ub.u = sb[j*32];
          int k2 = c*32 + j;
          #pragma unroll
          for (int r = 0; r < 8; r++){
            aI[r] = dot2(w1s[rh*8 + r][k2], ua.h, aI[r]);
            aH[r] = dot2(w1s[16 + rh*8 + r][k2], ub.h, aH[r]);
          }
        }
        #pragma unroll
        for (int r = 0; r < 8; r++) partial[w][rh*8 + r][b] = aI[r] + aH[r];
      } else {
        float aI[8] = {0,0,0,0,0,0,0,0}, aH[8] = {0,0,0,0,0,0,0,0};
        #pragma unroll 2
        for (int j = 0; j < 32; j++){
          U32H2 ua; ua.u = sa[j*32];
          U32H2 ub; ub.u = sb[j*32];
          int k2 = c*32 + j;
          #pragma unroll
          for (int r = 0; r < 8; r++){
            aI[r] = dot2(w1s[rh*8 + r][k2], ua.h, aI[r]);
            aH[r] = dot2(w1s[16 + rh*8 + r][k2], ub.h, aH[r]);
            a0[r] = dot2(w0s[rh*8 + r][k2], ua.h, a0[r]);
          }
        }
        #pragma unroll
        for (int r = 0; r < 8; r++) partial[w][rh*8 + r][b] = aI[r] + aH[r];
      }
    }
    __syncthreads();
    // ---- layer1(p-1) reduce + cell ----
    if (p >= 1 && tid < 512){
      int r = tid >> 5, bb = tid & 31;
      float s = 0.f;
      #pragma unroll
      for (int w2 = 0; w2 < 16; w2++) s += partial[w2][r][bb];
      float v = s + bs1v[r];
      gates[r][bb] = ((r >> 2) == 2) ? tanhf(v) : sigm(v);
    }
    __syncthreads();
    if (p >= 1 && tid < 64){
      int hp = tid >> 5, bb = tid & 31;
      int t1 = p - 1;
      float hn0, hn1;
      {
        int hl = 2*hp;
        float cn = gates[4+hl][bb]*cst[1][hl][bb] + gates[0+hl][bb]*gates[8+hl][bb];
        cst[1][hl][bb] = cn;
        hn0 = gates[12+hl][bb]*tanhf(cn);
        h1loc[hl][bb*T + t1] = (__fp16)hn0;
      }
      {
        int hl = 2*hp + 1;
        float cn = gates[4+hl][bb]*cst[1][hl][bb] + gates[0+hl][bb]*gates[8+hl][bb];
        cst[1][hl][bb] = cn;
        hn1 = gates[12+hl][bb]*tanhf(cn);
        h1loc[hl][bb*T + t1] = (__fp16)hn1;
      }
      U32H2 uu; uu.h = pk2(hn0, hn1);
      h1w[(2*gB + hp)*32 + bb] = uu.u;
    }
    // ---- layer0(p) partial stash (registers -> LDS) ----
    if (p < T){
      #pragma unroll
      for (int r = 0; r < 8; r++) partial[w][rh*8 + r][b] = a0[r];
    }
    __syncthreads();
    if (p < T && tid < 512){
      int r = tid >> 5, bb = tid & 31;
      float s = 0.f;
      #pragma unroll
      for (int w2 = 0; w2 < 16; w2++) s += partial[w2][r][bb];
      float v = s + xgv;
      gates[r][bb] = ((r >> 2) == 2) ? tanhf(v) : sigm(v);
    }
    __syncthreads();
    if (p < T && tid < 64){
      int hp = tid >> 5, bb = tid & 31;
      float hn0, hn1;
      {
        int hl = 2*hp;
        float cn = gates[4+hl][bb]*cst[0][hl][bb] + gates[0+hl][bb]*gates[8+hl][bb];
        cst[0][hl][bb] = cn;
        hn0 = gates[12+hl][bb]*tanhf(cn);
      }
      {
        int hl = 2*hp + 1;
        float cn = gates[4+hl][bb]*cst[0][hl][bb] + gates[0+hl][bb]*gates[8+hl][bb];
        cst[0][hl][bb] = cn;
        hn1 = gates[12+hl][bb]*tanhf(cn);
      }
      U32H2 uu; uu.h = pk2(hn0, hn1);
      h0w[(2*gB + hp)*32 + bb] = uu.u;
    }
    gbar(bar, ep); ep++;
  }

  // H1Tmk flush: row m = b*T+t, 4 contiguous k = 4gB..4gB+3 (16B store)
  for (int m = tid; m < B*T; m += 1024){
    float4 v;
    v.x = (float)h1loc[0][m]; v.y = (float)h1loc[1][m];
    v.z = (float)h1loc[2][m]; v.w = (float)h1loc[3][m];
    *(float4*)&H1Tmk[(long)m*1024 + 4*gB] = v;
  }
}

// ---------------- fallback per-step cells (verified) ----------------
__global__ void k_init(const float* __restrict__ enc, float* __restrict__ h0, float* __restrict__ c0,
                       float* __restrict__ h1, float* __restrict__ c1){
  int idx = blockIdx.x*256 + threadIdx.x;
  int b = idx & 31, h = idx >> 5;
  float v = enc[b*H + h];
  h0[idx]=v; c0[idx]=v; h1[idx]=v; c1[idx]=v;
}

__global__ __launch_bounds__(256) void k_cell0(const float* __restrict__ whh, const float* __restrict__ xg_t,
                       const float* __restrict__ h_in, float* __restrict__ h_out,
                       float* __restrict__ c){
  int h = (blockIdx.x*256 + threadIdx.x) >> 6;
  int lane = threadIdx.x & 63;
  int b = lane & 31, kh = lane >> 5;
  const float* w0 = whh + (0*H + h)*H + kh*512;
  const float* w1 = whh + (1*H + h)*H + kh*512;
  const float* w2 = whh + (2*H + h)*H + kh*512;
  const float* w3 = whh + (3*H + h)*H + kh*512;
  const float* hk = h_in + (kh*512)*B + b;
  float a0=0,a1=0,a2=0,a3=0, p0=0,p1=0,p2=0,p3=0;
  #pragma unroll 4
  for (int k=0;k<512;k+=4){
    float4 w40 = *(const float4*)(w0+k);
    float4 w41 = *(const float4*)(w1+k);
    float4 w42 = *(const float4*)(w2+k);
    float4 w43 = *(const float4*)(w3+k);
    float hv0 = hk[(k+0)*B], hv1 = hk[(k+1)*B], hv2 = hk[(k+2)*B], hv3 = hk[(k+3)*B];
    a0 += w40.x*hv0 + w40.y*hv1;  p0 += w40.z*hv2 + w40.w*hv3;
    a1 += w41.x*hv0 + w41.y*hv1;  p1 += w41.z*hv2 + w41.w*hv3;
    a2 += w42.x*hv0 + w42.y*hv1;  p2 += w42.z*hv2 + w42.w*hv3;
    a3 += w43.x*hv0 + w43.y*hv1;  p3 += w43.z*hv2 + w43.w*hv3;
  }
  float g0=a0+p0, g1=a1+p1, g2=a2+p2, g3=a3+p3;
  g0 += __shfl_xor(g0, 32);
  g1 += __shfl_xor(g1, 32);
  g2 += __shfl_xor(g2, 32);
  g3 += __shfl_xor(g3, 32);
  g0 += xg_t[(0*H+h)*B + b];
  g1 += xg_t[(1*H+h)*B + b];
  g2 += xg_t[(2*H+h)*B + b];
  g3 += xg_t[(3*H+h)*B + b];
  float ig = sigm(g0), fg = sigm(g1), gg = tanhf(g2), og = sigm(g3);
  int sidx = h*B + b;
  float cn = fg*c[sidx] + ig*gg;
  float hn = og*tanhf(cn);
  if (kh==0){ c[sidx]=cn; h_out[sidx]=hn; }
}

__global__ __launch_bounds__(256) void k_cell1(const float* __restrict__ wih, const float* __restrict__ whh,
                       const float* __restrict__ bih, const float* __restrict__ bhh,
                       const float* __restrict__ h0n, const float* __restrict__ h_in,
                       float* __restrict__ h_out, float* __restrict__ c,
                       float* __restrict__ H1Tmk, int t){
  int h = (blockIdx.x*256 + threadIdx.x) >> 6;
  int lane = threadIdx.x & 63;
  int b = lane & 31, kh = lane >> 5;
  float a0=0,a1=0,a2=0,a3=0, p0=0,p1=0,p2=0,p3=0;
  {
    const float* w0 = wih + (0*H + h)*H + kh*512;
    const float* w1 = wih + (1*H + h)*H + kh*512;
    const float* w2 = wih + (2*H + h)*H + kh*512;
    const float* w3 = wih + (3*H + h)*H + kh*512;
    const float* hk = h0n + (kh*512)*B + b;
    #pragma unroll 4
    for (int k=0;k<512;k+=4){
      float4 w40 = *(const float4*)(w0+k);
      float4 w41 = *(const float4*)(w1+k);
      float4 w42 = *(const float4*)(w2+k);
      float4 w43 = *(const float4*)(w3+k);
      float hv0 = hk[(k+0)*B], hv1 = hk[(k+1)*B], hv2 = hk[(k+2)*B], hv3 = hk[(k+3)*B];
      a0 += w40.x*hv0 + w40.y*hv1;  p0 += w40.z*hv2 + w40.w*hv3;
      a1 += w41.x*hv0 + w41.y*hv1;  p1 += w41.z*hv2 + w41.w*hv3;
      a2 += w42.x*hv0 + w42.y*hv1;  p2 += w42.z*hv2 + w42.w*hv3;
      a3 += w43.x*hv0 + w43.y*hv1;  p3 += w43.z*hv2 + w43.w*hv3;
    }
  }
  {
    const float* w0 = whh + (0*H + h)*H + kh*512;
    const float* w1 = whh + (1*H + h)*H + kh*512;
    const float* w2 = whh + (2*H + h)*H + kh*512;
    const float* w3 = whh + (3*H + h)*H + kh*512;
    const float* hk = h_in + (kh*512)*B + b;
    #pragma unroll 4
    for (int k=0;k<512;k+=4){
      float4 w40 = *(const float4*)(w0+k);
      float4 w41 = *(const float4*)(w1+k);
      float4 w42 = *(const float4*)(w2+k);
      float4 w43 = *(const float4*)(w3+k);
      float hv0 = hk[(k+0)*B], hv1 = hk[(k+1)*B], hv2 = hk[(k+2)*B], hv3 = hk[(k+3)*B];
      a0 += w40.x*hv0 + w40.y*hv1;  p0 += w40.z*hv2 + w40.w*hv3;
      a1 += w41.x*hv0 + w41.y*hv1;  p1 += w41.z*hv2 + w41.w*hv3;
      a2 += w42.x*hv0 + w42.y*hv1;  p2 += w42.z*hv2 + w42.w*hv3;
      a3 += w43.x*hv0 + w43.y*hv1;  p3 += w43.z*hv2 + w43.w*hv3;
    }
  }
  float g0=a0+p0, g1=a1+p1, g2=a2+p2, g3=a3+p3;
  g0 += __shfl_xor(g0, 32);
  g1 += __shfl_xor(g1, 32);
  g2 += __shfl_xor(g2, 32);
  g3 += __shfl_xor(g3, 32);
  g0 += bih[0*H+h] + bhh[0*H+h];
  g1 += bih[1*H+h] + bhh[1*H+h];
  g2 += bih[2*H+h] + bhh[2*H+h];
  g3 += bih[3*H+h] + bhh[3*H+h];
  float ig = sigm(g0), fg = sigm(g1), gg = tanhf(g2), og = sigm(g3);
  int sidx = h*B + b;
  float cn = fg*c[sidx] + ig*gg;
  float hn = og*tanhf(cn);
  if (kh==0){ c[sidx]=cn; h_out[sidx]=hn; H1Tmk[((long)(b*T + t))*1024 + h] = hn; }
}

// ---------------- MFMA bf16 output GEMM ----------------
__global__ __launch_bounds__(256, 2) void k_gemm(const float* __restrict__ A,
                      const float* __restrict__ lw, const float* __restrict__ lb,
                      float* __restrict__ out){
  __shared__ uint4 As4[128*8];
  __shared__ uint4 Ws4[128*8];
  const int tid = threadIdx.x;
  int orig = blockIdx.x;
  int xcd = orig & 7, ii = orig >> 3;
  int wgid = (xcd < 2 ? xcd*407 : 814 + (xcd-2)*406) + ii;
  int bm = wgid % 13, bn = wgid / 13;
  int m0 = bm*128, n0 = bn*128;
  const int wv = tid >> 6, l = tid & 63;
  const int wm = (wv >> 1)*64, wn = (wv & 1)*64;
  const int lrow = l & 15, lk = l >> 4;

  floatx4 acc[4][4] = {};
  for (int k0 = 0; k0 < H; k0 += 64){
    #pragma unroll
    for (int it = 0; it < 4; it++){
      int slot = tid + it*256;
      int row = slot >> 3, seg = slot & 7;
      const float4* src = (const float4*)(A + (long)(m0+row)*1024 + k0 + seg*8);
      float4 v0 = src[0], v1 = src[1];
      uint4 pk;
      pk.x = pkbf(v0.x, v0.y); pk.y = pkbf(v0.z, v0.w);
      pk.z = pkbf(v1.x, v1.y); pk.w = pkbf(v1.z, v1.w);
      As4[row*8 + (seg ^ (row & 7))] = pk;
    }
    #pragma unroll
    for (int it = 0; it < 4; it++){
      int slot = tid + it*256;
      int row = slot >> 3, seg = slot & 7;
      const float4* src = (const float4*)(lw + (long)(n0+row)*1024 + k0 + seg*8);
      float4 v0 = src[0], v1 = src[1];
      uint4 pk;
      pk.x = pkbf(v0.x, v0.y); pk.y = pkbf(v0.z, v0.w);
      pk.z = pkbf(v1.x, v1.y); pk.w = pkbf(v1.z, v1.w);
      Ws4[row*8 + (seg ^ (row & 7))] = pk;
    }
    __syncthreads();
    #pragma unroll
    for (int ks = 0; ks < 2; ks++){
      short8 af[4], bf_[4];
      #pragma unroll
      for (int fi = 0; fi < 4; fi++){
        int row = wm + fi*16 + lrow;
        U16S8 u; u.u4 = As4[row*8 + ((ks*4 + lk) ^ (lrow & 7))];
        af[fi] = u.s8;
      }
      #pragma unroll
      for (int fj = 0; fj < 4; fj++){
        int row = wn + fj*16 + lrow;
        U16S8 u; u.u4 = Ws4[row*8 + ((ks*4 + lk) ^ (lrow & 7))];
        bf_[fj] = u.s8;
      }
      #pragma unroll
      for (int fi = 0; fi < 4; fi++)
        #pragma unroll
        for (int fj = 0; fj < 4; fj++)
          acc[fi][fj] = __builtin_amdgcn_mfma_f32_16x16x32_bf16(af[fi], bf_[fj], acc[fi][fj], 0, 0, 0);
    }
    __syncthreads();
  }
  #pragma unroll
  for (int fj = 0; fj < 4; fj++){
    int n = n0 + wn + fj*16 + lrow;
    float bias = lb[n];
    #pragma unroll
    for (int fi = 0; fi < 4; fi++){
      floatx4 av = acc[fi][fj];
      int mb = m0 + wm + fi*16 + lk*4;
      #pragma unroll
      for (int r = 0; r < 4; r++){
        int m = mb + r;
        if (m < B*T) out[(long)m*V + n] = av[r] + bias;
      }
    }
  }
}

__global__ __launch_bounds__(256) void k_lsm(float* __restrict__ out){
  __shared__ float red[256];
  float4* row = (float4*)(out + (long)blockIdx.x * V);
  const int tid = threadIdx.x;
  float m = -INFINITY;
  for (int n=tid;n<V/4;n+=256){
    float4 v = row[n];
    m = fmaxf(m, fmaxf(fmaxf(v.x,v.y), fmaxf(v.z,v.w)));
  }
  red[tid]=m; __syncthreads();
  for (int s=128;s>0;s>>=1){ if(tid<s) red[tid]=fmaxf(red[tid],red[tid+s]); __syncthreads(); }
  m = red[0]; __syncthreads();
  float s = 0.f;
  for (int n=tid;n<V/4;n+=256){
    float4 v = row[n];
    s += __expf(v.x-m)+__expf(v.y-m)+__expf(v.z-m)+__expf(v.w-m);
  }
  red[tid]=s; __syncthreads();
  for (int st=128;st>0;st>>=1){ if(tid<st) red[tid]+=red[tid+st]; __syncthreads(); }
  float lse = m + __logf(red[0]);
  for (int n=tid;n<V/4;n+=256){
    float4 v = row[n];
    v.x-=lse; v.y-=lse; v.z-=lse; v.w-=lse;
    row[n] = v;
  }
}

extern "C" void kernel_launch(void* const* d_in, const int* in_sizes, int n_in,
                              void* d_out, int out_size, void* d_ws, size_t ws_size,
                              hipStream_t stream){
  const float* enc    = (const float*)d_in[0];
  const float* target = (const float*)d_in[1];
  const float* pw     = (const float*)d_in[2];
  const float* pb     = (const float*)d_in[3];
  const float* wih0   = (const float*)d_in[4];
  const float* whh0   = (const float*)d_in[5];
  const float* bih0   = (const float*)d_in[6];
  const float* bhh0   = (const float*)d_in[7];
  const float* wih1   = (const float*)d_in[8];
  const float* whh1   = (const float*)d_in[9];
  const float* bih1   = (const float*)d_in[10];
  const float* bhh1   = (const float*)d_in[11];
  const float* lw     = (const float*)d_in[12];
  const float* lb     = (const float*)d_in[13];
  float* out = (float*)d_out;

  float* ws   = (float*)d_ws;
  float* xg0  = ws;
  float* P    = xg0 + (long)T*G4*B;
  float* encp = P + T*E*B;
  float* H1Tmk = encp + B*E;
  unsigned* h0A2 = (unsigned*)(H1Tmk + (long)MROWS*1024);
  unsigned* h0B2 = h0A2 + 16384;
  unsigned* h1A2 = h0B2 + 16384;
  unsigned* h1B2 = h1A2 + 16384;
  float* fh0a = (float*)(h1B2 + 16384);
  float* fh0b = fh0a + H*B;
  float* fh1a = fh0b + H*B;
  float* fh1b = fh1a + H*B;
  float* fc0  = fh1b + H*B;
  float* fc1  = fc0 + H*B;
  unsigned* bar = (unsigned*)(fc1 + H*B);

  k_encp<<<B, E, 0, stream>>>(enc, pw, pb, encp);
  k_proj<<<T*B, E, 0, stream>>>(target, pw, encp, P);
  k_xg0<<<(T*G4*B)/256, 256, 0, stream>>>(wih0, bih0, bhh0, P, xg0);
  k_fill<<<(MROWS*1024)/256, 256, 0, stream>>>(H1Tmk);
  k_zero<<<4, 256, 0, stream>>>(bar);

  void* cargs[] = {(void*)&whh0, (void*)&wih1, (void*)&whh1, (void*)&bih1, (void*)&bhh1,
                   (void*)&enc, (void*)&xg0,
                   (void*)&h0A2, (void*)&h0B2, (void*)&h1A2, (void*)&h1B2,
                   (void*)&H1Tmk, (void*)&bar};
  hipError_t cerr = hipLaunchCooperativeKernel((void*)k_cells, dim3(NB), dim3(1024),
                                               cargs, 0, stream);
  if (cerr != hipSuccess){
    k_init<<<(H*B)/256, 256, 0, stream>>>(enc, fh0a, fc0, fh1a, fc1);
    float* h0in=fh0a; float* h0out=fh0b;
    float* h1in=fh1a; float* h1out=fh1b;
    for (int t=0;t<T;t++){
      k_cell0<<<256, 256, 0, stream>>>(whh0, xg0 + (long)t*G4*B, h0in, h0out, fc0);
      k_cell1<<<256, 256, 0, stream>>>(wih1, whh1, bih1, bhh1, h0out, h1in, h1out, fc1,
                                       H1Tmk, t);
      float* tmp;
      tmp=h0in; h0in=h0out; h0out=tmp;
      tmp=h1in; h1in=h1out; h1out=tmp;
    }
  }

  k_gemm<<<3250, 256, 0, stream>>>(H1Tmk, lw, lb, out);
  k_lsm<<<B*T, 256, 0, stream>>>(out);
}

// Round 10
// 1672.955 us; speedup vs baseline: 10.3746x; 1.0496x over previous
//
#include <hip/hip_runtime.h>
#include <hip/hip_bf16.h>
#include <math.h>

#define B 32
#define T 50
#define H 1024
#define E 128
#define V 32000
#define G4 4096   // 4*H
#define HE 1152   // H+E
#define MROWS 1664 // 13*128 padded M for GEMM
#define NB 256    // coop grid blocks

typedef __fp16 half2v __attribute__((ext_vector_type(2)));
union U32H2 { unsigned u; half2v h; };
typedef short short8 __attribute__((ext_vector_type(8)));
typedef float floatx4 __attribute__((ext_vector_type(4)));
union U16S8 { uint4 u4; short8 s8; };

__device__ __forceinline__ float sigm(float x){ return 1.0f/(1.0f+expf(-x)); }

__device__ __forceinline__ half2v pk2(float a, float b){
#if __has_builtin(__builtin_amdgcn_cvt_pkrtz)
  return __builtin_amdgcn_cvt_pkrtz(a, b);
#else
  half2v r; r.x = (__fp16)a; r.y = (__fp16)b; return r;
#endif
}

__device__ __forceinline__ float dot2(half2v a, half2v b, float c){
#if __has_builtin(__builtin_amdgcn_fdot2)
  return __builtin_amdgcn_fdot2(a, b, c, false);
#else
  return c + (float)a.x*(float)b.x + (float)a.y*(float)b.y;
#endif
}

// pack two f32 -> one u32 of two bf16 (RNE)
__device__ __forceinline__ unsigned pkbf(float a, float b){
  unsigned ua = __float_as_uint(a), ub = __float_as_uint(b);
  unsigned ra = (ua + 0x7FFFu + ((ua>>16)&1u)) >> 16;
  unsigned rb = (ub + 0x7FFFu + ((ub>>16)&1u)) >> 16;
  return ra | (rb << 16);
}
__device__ __forceinline__ unsigned short bf1(float v){
  unsigned u = __float_as_uint(v);
  return (unsigned short)((u + 0x7FFFu + ((u>>16)&1u)) >> 16);
}

// ---- two-level tree grid barrier: 8 leaves x 32 blocks + root ----
__device__ __forceinline__ void gbar(unsigned* bar, unsigned ep){
  __syncthreads();
  if (threadIdx.x == 0){
    __builtin_amdgcn_fence(__ATOMIC_RELEASE, "agent");
    unsigned g = blockIdx.x & 7u;
    unsigned old = __hip_atomic_fetch_add(&bar[64 + g*64], 1u,
                     __ATOMIC_RELAXED, __HIP_MEMORY_SCOPE_AGENT);
    if (old == ep*32u - 1u)
      __hip_atomic_fetch_add(&bar[0], 1u, __ATOMIC_RELAXED, __HIP_MEMORY_SCOPE_AGENT);
    while (__hip_atomic_load(&bar[0], __ATOMIC_RELAXED, __HIP_MEMORY_SCOPE_AGENT) < ep*8u)
      __builtin_amdgcn_s_sleep(1);
    __builtin_amdgcn_fence(__ATOMIC_ACQUIRE, "agent");
  }
  __syncthreads();
}

// encp[b][e] = proj_b[e] + sum_j enc[b][j] * proj_w[e][E+j]
__global__ void k_encp(const float* __restrict__ enc, const float* __restrict__ pw,
                       const float* __restrict__ pb, float* __restrict__ encp){
  int b = blockIdx.x, e = threadIdx.x;
  const float* er = enc + b*H;
  const float* wr = pw + e*HE + E;
  float acc = pb[e];
  for (int j=0;j<H;j+=4){
    float4 w4 = *(const float4*)(wr+j);
    float4 e4 = *(const float4*)(er+j);
    acc += w4.x*e4.x + w4.y*e4.y + w4.z*e4.z + w4.w*e4.w;
  }
  encp[b*E+e] = acc;
}

// P[t][e][b] = encp[b][e] + sum_j target[b][t][j] * proj_w[e][j]
__global__ void k_proj(const float* __restrict__ target, const float* __restrict__ pw,
                       const float* __restrict__ encp, float* __restrict__ P){
  int t = blockIdx.x / B, b = blockIdx.x % B, e = threadIdx.x;
  const float* xr = target + (b*T + t)*E;
  const float* wr = pw + e*HE;
  float acc = encp[b*E+e];
  for (int j=0;j<E;j+=4){
    float4 w4 = *(const float4*)(wr+j);
    float4 x4 = *(const float4*)(xr+j);
    acc += w4.x*x4.x + w4.y*x4.y + w4.z*x4.z + w4.w*x4.w;
  }
  P[(t*E + e)*B + b] = acc;
}

// xg0[t][r][b] = b_ih0[r]+b_hh0[r] + sum_e w_ih0[r][e] * P[t][e][b]
__global__ void k_xg0(const float* __restrict__ wih0, const float* __restrict__ bih0,
                      const float* __restrict__ bhh0, const float* __restrict__ P,
                      float* __restrict__ xg){
  int idx = blockIdx.x*256 + threadIdx.x;
  int b = idx & 31; int r = (idx >> 5) & 4095; int t = idx >> 17;
  const float* wr = wih0 + r*E;
  const float* pr = P + t*E*B + b;
  float acc = bih0[r] + bhh0[r];
  #pragma unroll 8
  for (int e=0;e<E;e++) acc += wr[e] * pr[e*B];
  xg[idx] = acc;
}

__global__ void k_zero32(unsigned* __restrict__ p){
  p[blockIdx.x*256 + threadIdx.x] = 0u;
}

// convert lw f32 -> bf16 in the GEMM's swizzled tile layout
// slot(n,k): bn=n>>7,row=n&127,k0c=k>>6,seg=(k&63)>>3 -> ((bn*16+k0c)*128+row)*8+(seg^(row&7))
__global__ void k_cvtw(const float* __restrict__ lw, uint4* __restrict__ wsw){
  int gid = blockIdx.x*256 + threadIdx.x;   // 4,096,000
  int n = gid >> 7, rem = gid & 127;
  int k0c = rem >> 3, seg = rem & 7;
  const float4* src = (const float4*)(lw + (long)n*H + k0c*64 + seg*8);
  float4 v0 = src[0], v1 = src[1];
  uint4 pk;
  pk.x = pkbf(v0.x, v0.y); pk.y = pkbf(v0.z, v0.w);
  pk.z = pkbf(v1.x, v1.y); pk.w = pkbf(v1.z, v1.w);
  int bn = n >> 7, row = n & 127;
  wsw[((long)(bn*16 + k0c)*128 + row)*8 + (seg ^ (row & 7))] = pk;
}

// ---------------- cooperative persistent cells (v6: uint2 state) ----------------
__global__ __launch_bounds__(1024, 4) void k_cells(
    const float* __restrict__ whh0, const float* __restrict__ wih1, const float* __restrict__ whh1,
    const float* __restrict__ bih1, const float* __restrict__ bhh1,
    const float* __restrict__ enc, const float* __restrict__ xg0,
    unsigned* __restrict__ h0A2, unsigned* __restrict__ h0B2,
    unsigned* __restrict__ h1A2, unsigned* __restrict__ h1B2,
    unsigned* __restrict__ Abf, unsigned* __restrict__ bar){
  const int gB = blockIdx.x;
  const int tid = threadIdx.x;
  const int w = tid >> 6;       // wave 0..15 = k-chunk owner
  const int l = tid & 63;
  const int b = l & 31;
  const int rh = l >> 5;        // row-half: rows rh*8..rh*8+7

  __shared__ half2v w0s[16][512];        // layer0 whh0 rows (32 KB)
  __shared__ half2v w1s[32][512];        // wih1(0-15) + whh1(16-31) (64 KB)
  __shared__ float partial[16][16][32];  // [wave][row][b] (32 KB)
  __shared__ float gates[16][32];
  __shared__ float cst[2][4][32];
  __shared__ float bs1v[16];
  __shared__ __fp16 h1loc[4][1600];      // [hl][b*T+t] (12.8 KB)

  // ---- stage weights f32 -> f16 pairs ----
  for (int i = tid; i < 16*512; i += 1024){
    int r = i >> 9, k2 = i & 511;
    int q = r >> 2, hl = r & 3;
    float2 v = *(const float2*)(whh0 + ((long)q*H + 4*gB + hl)*H + 2*k2);
    w0s[r][k2] = pk2(v.x, v.y);
  }
  for (int i = tid; i < 32*512; i += 1024){
    int r = i >> 9, k2 = i & 511;
    int rr = r & 15;
    int q = rr >> 2, hl = rr & 3;
    const float* srcm = (r < 16) ? wih1 : whh1;
    float2 v = *(const float2*)(srcm + ((long)q*H + 4*gB + hl)*H + 2*k2);
    w1s[r][k2] = pk2(v.x, v.y);
  }
  if (tid < 16){
    int q = tid >> 2, hl = tid & 3;
    bs1v[tid] = bih1[q*H + 4*gB + hl] + bhh1[q*H + 4*gB + hl];
  }
  if (tid < 128){
    int hl = tid >> 5, bb = tid & 31;
    float v = enc[bb*H + 4*gB + hl];
    cst[0][hl][bb] = v; cst[1][hl][bb] = v;
  }
  if (tid < 32){
    int bb = tid;
    U32H2 z0, z1;
    z0.h = pk2(enc[bb*H + 4*gB + 0], enc[bb*H + 4*gB + 1]);
    z1.h = pk2(enc[bb*H + 4*gB + 2], enc[bb*H + 4*gB + 3]);
    uint2 val; val.x = z0.u; val.y = z1.u;
    ((uint2*)h0A2)[gB*32 + bb] = val;
    ((uint2*)h1A2)[gB*32 + bb] = val;
  }
  unsigned ep = 1;
  gbar(bar, ep); ep++;

  for (int p = 0; p <= T; p++){
    const unsigned* h0r = (p & 1) ? h0B2 : h0A2;
    unsigned*       h0w = (p & 1) ? h0A2 : h0B2;
    const unsigned* h1r = (p & 1) ? h1A2 : h1B2;
    unsigned*       h1w = (p & 1) ? h1B2 : h1A2;

    // xg prefetch for layer0(p)
    float xgv = 0.f;
    if (p < T && tid < 512){
      int r = tid >> 5, bb = tid & 31;
      int q = r >> 2, hl = r & 3;
      xgv = xg0[((long)p*G4 + (long)q*H + 4*gB + hl)*32 + bb];
    }

    // ---- merged matvec (uint2-paired state) ----
    float a0[8] = {0,0,0,0,0,0,0,0};
    {
      int c = (w + gB + p) & 15;
      const uint2* sa = (const uint2*)h0r + c*512 + b;
      const uint2* sb = (const uint2*)h1r + c*512 + b;
      if (p == 0){
        #pragma unroll 4
        for (int j2 = 0; j2 < 16; j2++){
          uint2 va = sa[j2*32];
          U32H2 u0, u1; u0.u = va.x; u1.u = va.y;
          int k2 = c*32 + j2*2;
          #pragma unroll
          for (int r = 0; r < 8; r++){
            a0[r] = dot2(w0s[rh*8 + r][k2],   u0.h, a0[r]);
            a0[r] = dot2(w0s[rh*8 + r][k2+1], u1.h, a0[r]);
          }
        }
      } else if (p == T){
        float aI[8] = {0,0,0,0,0,0,0,0}, aH[8] = {0,0,0,0,0,0,0,0};
        #pragma unroll 4
        for (int j2 = 0; j2 < 16; j2++){
          uint2 va = sa[j2*32];
          uint2 vb = sb[j2*32];
          U32H2 a0h,a1h,b0h,b1h; a0h.u=va.x; a1h.u=va.y; b0h.u=vb.x; b1h.u=vb.y;
          int k2 = c*32 + j2*2;
          #pragma unroll
          for (int r = 0; r < 8; r++){
            aI[r] = dot2(w1s[rh*8 + r][k2],      a0h.h, aI[r]);
            aI[r] = dot2(w1s[rh*8 + r][k2+1],    a1h.h, aI[r]);
            aH[r] = dot2(w1s[16 + rh*8 + r][k2],   b0h.h, aH[r]);
            aH[r] = dot2(w1s[16 + rh*8 + r][k2+1], b1h.h, aH[r]);
          }
        }
        #pragma unroll
        for (int r = 0; r < 8; r++) partial[w][rh*8 + r][b] = aI[r] + aH[r];
      } else {
        float aI[8] = {0,0,0,0,0,0,0,0}, aH[8] = {0,0,0,0,0,0,0,0};
        #pragma unroll 4
        for (int j2 = 0; j2 < 16; j2++){
          uint2 va = sa[j2*32];
          uint2 vb = sb[j2*32];
          U32H2 a0h,a1h,b0h,b1h; a0h.u=va.x; a1h.u=va.y; b0h.u=vb.x; b1h.u=vb.y;
          int k2 = c*32 + j2*2;
          #pragma unroll
          for (int r = 0; r < 8; r++){
            aI[r] = dot2(w1s[rh*8 + r][k2],      a0h.h, aI[r]);
            aI[r] = dot2(w1s[rh*8 + r][k2+1],    a1h.h, aI[r]);
            aH[r] = dot2(w1s[16 + rh*8 + r][k2],   b0h.h, aH[r]);
            aH[r] = dot2(w1s[16 + rh*8 + r][k2+1], b1h.h, aH[r]);
            a0[r] = dot2(w0s[rh*8 + r][k2],      a0h.h, a0[r]);
            a0[r] = dot2(w0s[rh*8 + r][k2+1],    a1h.h, a0[r]);
          }
        }
        #pragma unroll
        for (int r = 0; r < 8; r++) partial[w][rh*8 + r][b] = aI[r] + aH[r];
      }
    }
    __syncthreads();
    // ---- layer1(p-1) reduce + cell ----
    if (p >= 1 && tid < 512){
      int r = tid >> 5, bb = tid & 31;
      float s = 0.f;
      #pragma unroll
      for (int w2 = 0; w2 < 16; w2++) s += partial[w2][r][bb];
      float v = s + bs1v[r];
      gates[r][bb] = ((r >> 2) == 2) ? tanhf(v) : sigm(v);
    }
    __syncthreads();
    if (p >= 1 && tid < 32){
      int bb = tid, t1 = p - 1;
      float hn[4];
      #pragma unroll
      for (int hl = 0; hl < 4; hl++){
        float cn = gates[4+hl][bb]*cst[1][hl][bb] + gates[0+hl][bb]*gates[8+hl][bb];
        cst[1][hl][bb] = cn;
        hn[hl] = gates[12+hl][bb]*tanhf(cn);
        h1loc[hl][bb*T + t1] = (__fp16)hn[hl];
      }
      U32H2 z0, z1; z0.h = pk2(hn[0], hn[1]); z1.h = pk2(hn[2], hn[3]);
      uint2 val; val.x = z0.u; val.y = z1.u;
      ((uint2*)h1w)[gB*32 + bb] = val;
    }
    // ---- layer0(p) partial stash ----
    if (p < T){
      #pragma unroll
      for (int r = 0; r < 8; r++) partial[w][rh*8 + r][b] = a0[r];
    }
    __syncthreads();
    if (p < T && tid < 512){
      int r = tid >> 5, bb = tid & 31;
      float s = 0.f;
      #pragma unroll
      for (int w2 = 0; w2 < 16; w2++) s += partial[w2][r][bb];
      float v = s + xgv;
      gates[r][bb] = ((r >> 2) == 2) ? tanhf(v) : sigm(v);
    }
    __syncthreads();
    if (p < T && tid < 32){
      int bb = tid;
      float hn[4];
      #pragma unroll
      for (int hl = 0; hl < 4; hl++){
        float cn = gates[4+hl][bb]*cst[0][hl][bb] + gates[0+hl][bb]*gates[8+hl][bb];
        cst[0][hl][bb] = cn;
        hn[hl] = gates[12+hl][bb]*tanhf(cn);
      }
      U32H2 z0, z1; z0.h = pk2(hn[0], hn[1]); z1.h = pk2(hn[2], hn[3]);
      uint2 val; val.x = z0.u; val.y = z1.u;
      ((uint2*)h0w)[gB*32 + bb] = val;
    }
    gbar(bar, ep); ep++;
  }

  // A-tile flush: block gB covers k = 4gB..4gB+3, write swizzled bf16
  {
    int k0c = gB >> 4;
    int seg = (gB & 15) >> 1;
    int pos = (gB & 1) * 4;
    for (int m = tid; m < B*T; m += 1024){
      float v0 = (float)h1loc[0][m], v1 = (float)h1loc[1][m];
      float v2 = (float)h1loc[2][m], v3 = (float)h1loc[3][m];
      int bm = m >> 7, row = m & 127;
      long slot = ((long)(bm*16 + k0c)*128 + row)*8 + (seg ^ (row & 7));
      uint2 val; val.x = pkbf(v0, v1); val.y = pkbf(v2, v3);
      *(uint2*)((char*)Abf + slot*16 + pos*2) = val;
    }
  }
}

// ---------------- fallback per-step cells ----------------
__global__ void k_init(const float* __restrict__ enc, float* __restrict__ h0, float* __restrict__ c0,
                       float* __restrict__ h1, float* __restrict__ c1){
  int idx = blockIdx.x*256 + threadIdx.x;
  int b = idx & 31, h = idx >> 5;
  float v = enc[b*H + h];
  h0[idx]=v; c0[idx]=v; h1[idx]=v; c1[idx]=v;
}

__global__ __launch_bounds__(256) void k_cell0(const float* __restrict__ whh, const float* __restrict__ xg_t,
                       const float* __restrict__ h_in, float* __restrict__ h_out,
                       float* __restrict__ c){
  int h = (blockIdx.x*256 + threadIdx.x) >> 6;
  int lane = threadIdx.x & 63;
  int b = lane & 31, kh = lane >> 5;
  const float* w0 = whh + (0*H + h)*H + kh*512;
  const float* w1 = whh + (1*H + h)*H + kh*512;
  const float* w2 = whh + (2*H + h)*H + kh*512;
  const float* w3 = whh + (3*H + h)*H + kh*512;
  const float* hk = h_in + (kh*512)*B + b;
  float a0=0,a1=0,a2=0,a3=0, p0=0,p1=0,p2=0,p3=0;
  #pragma unroll 4
  for (int k=0;k<512;k+=4){
    float4 w40 = *(const float4*)(w0+k);
    float4 w41 = *(const float4*)(w1+k);
    float4 w42 = *(const float4*)(w2+k);
    float4 w43 = *(const float4*)(w3+k);
    float hv0 = hk[(k+0)*B], hv1 = hk[(k+1)*B], hv2 = hk[(k+2)*B], hv3 = hk[(k+3)*B];
    a0 += w40.x*hv0 + w40.y*hv1;  p0 += w40.z*hv2 + w40.w*hv3;
    a1 += w41.x*hv0 + w41.y*hv1;  p1 += w41.z*hv2 + w41.w*hv3;
    a2 += w42.x*hv0 + w42.y*hv1;  p2 += w42.z*hv2 + w42.w*hv3;
    a3 += w43.x*hv0 + w43.y*hv1;  p3 += w43.z*hv2 + w43.w*hv3;
  }
  float g0=a0+p0, g1=a1+p1, g2=a2+p2, g3=a3+p3;
  g0 += __shfl_xor(g0, 32);
  g1 += __shfl_xor(g1, 32);
  g2 += __shfl_xor(g2, 32);
  g3 += __shfl_xor(g3, 32);
  g0 += xg_t[(0*H+h)*B + b];
  g1 += xg_t[(1*H+h)*B + b];
  g2 += xg_t[(2*H+h)*B + b];
  g3 += xg_t[(3*H+h)*B + b];
  float ig = sigm(g0), fg = sigm(g1), gg = tanhf(g2), og = sigm(g3);
  int sidx = h*B + b;
  float cn = fg*c[sidx] + ig*gg;
  float hn = og*tanhf(cn);
  if (kh==0){ c[sidx]=cn; h_out[sidx]=hn; }
}

__global__ __launch_bounds__(256) void k_cell1(const float* __restrict__ wih, const float* __restrict__ whh,
                       const float* __restrict__ bih, const float* __restrict__ bhh,
                       const float* __restrict__ h0n, const float* __restrict__ h_in,
                       float* __restrict__ h_out, float* __restrict__ c,
                       unsigned* __restrict__ Abf, int t){
  int h = (blockIdx.x*256 + threadIdx.x) >> 6;
  int lane = threadIdx.x & 63;
  int b = lane & 31, kh = lane >> 5;
  float a0=0,a1=0,a2=0,a3=0, p0=0,p1=0,p2=0,p3=0;
  {
    const float* w0 = wih + (0*H + h)*H + kh*512;
    const float* w1 = wih + (1*H + h)*H + kh*512;
    const float* w2 = wih + (2*H + h)*H + kh*512;
    const float* w3 = wih + (3*H + h)*H + kh*512;
    const float* hk = h0n + (kh*512)*B + b;
    #pragma unroll 4
    for (int k=0;k<512;k+=4){
      float4 w40 = *(const float4*)(w0+k);
      float4 w41 = *(const float4*)(w1+k);
      float4 w42 = *(const float4*)(w2+k);
      float4 w43 = *(const float4*)(w3+k);
      float hv0 = hk[(k+0)*B], hv1 = hk[(k+1)*B], hv2 = hk[(k+2)*B], hv3 = hk[(k+3)*B];
      a0 += w40.x*hv0 + w40.y*hv1;  p0 += w40.z*hv2 + w40.w*hv3;
      a1 += w41.x*hv0 + w41.y*hv1;  p1 += w41.z*hv2 + w41.w*hv3;
      a2 += w42.x*hv0 + w42.y*hv1;  p2 += w42.z*hv2 + w42.w*hv3;
      a3 += w43.x*hv0 + w43.y*hv1;  p3 += w43.z*hv2 + w43.w*hv3;
    }
  }
  {
    const float* w0 = whh + (0*H + h)*H + kh*512;
    const float* w1 = whh + (1*H + h)*H + kh*512;
    const float* w2 = whh + (2*H + h)*H + kh*512;
    const float* w3 = whh + (3*H + h)*H + kh*512;
    const float* hk = h_in + (kh*512)*B + b;
    #pragma unroll 4
    for (int k=0;k<512;k+=4){
      float4 w40 = *(const float4*)(w0+k);
      float4 w41 = *(const float4*)(w1+k);
      float4 w42 = *(const float4*)(w2+k);
      float4 w43 = *(const float4*)(w3+k);
      float hv0 = hk[(k+0)*B], hv1 = hk[(k+1)*B], hv2 = hk[(k+2)*B], hv3 = hk[(k+3)*B];
      a0 += w40.x*hv0 + w40.y*hv1;  p0 += w40.z*hv2 + w40.w*hv3;
      a1 += w41.x*hv0 + w41.y*hv1;  p1 += w41.z*hv2 + w41.w*hv3;
      a2 += w42.x*hv0 + w42.y*hv1;  p2 += w42.z*hv2 + w42.w*hv3;
      a3 += w43.x*hv0 + w43.y*hv1;  p3 += w43.z*hv2 + w43.w*hv3;
    }
  }
  float g0=a0+p0, g1=a1+p1, g2=a2+p2, g3=a3+p3;
  g0 += __shfl_xor(g0, 32);
  g1 += __shfl_xor(g1, 32);
  g2 += __shfl_xor(g2, 32);
  g3 += __shfl_xor(g3, 32);
  g0 += bih[0*H+h] + bhh[0*H+h];
  g1 += bih[1*H+h] + bhh[1*H+h];
  g2 += bih[2*H+h] + bhh[2*H+h];
  g3 += bih[3*H+h] + bhh[3*H+h];
  float ig = sigm(g0), fg = sigm(g1), gg = tanhf(g2), og = sigm(g3);
  int sidx = h*B + b;
  float cn = fg*c[sidx] + ig*gg;
  float hn = og*tanhf(cn);
  if (kh==0){
    c[sidx]=cn; h_out[sidx]=hn;
    int m = b*T + t;
    int bm = m >> 7, row = m & 127;
    int k0c = h >> 6, kin = h & 63, seg = kin >> 3, pos = kin & 7;
    long slot = ((long)(bm*16 + k0c)*128 + row)*8 + (seg ^ (row & 7));
    *(unsigned short*)((char*)Abf + slot*16 + pos*2) = bf1(hn);
  }
}

// ---------------- MFMA bf16 output GEMM (pre-swizzled operands) ----------------
__global__ __launch_bounds__(256, 2) void k_gemm_pre(const uint4* __restrict__ Abf4,
                      const uint4* __restrict__ Wsw4, const float* __restrict__ lb,
                      float* __restrict__ out){
  __shared__ uint4 As4[1024];
  __shared__ uint4 Ws4[1024];
  const int tid = threadIdx.x;
  int orig = blockIdx.x;
  int xcd = orig & 7, ii = orig >> 3;
  int wgid = (xcd < 2 ? xcd*407 : 814 + (xcd-2)*406) + ii;
  int bm = wgid % 13, bn = wgid / 13;
  int m0 = bm*128, n0 = bn*128;
  const int wv = tid >> 6, l = tid & 63;
  const int wm = (wv >> 1)*64, wn = (wv & 1)*64;
  const int lrow = l & 15, lk = l >> 4;

  floatx4 acc[4][4] = {};
  for (int k0c = 0; k0c < 16; k0c++){
    const uint4* sA = Abf4 + (long)(bm*16 + k0c)*1024;
    const uint4* sW = Wsw4 + (long)(bn*16 + k0c)*1024;
    #pragma unroll
    for (int it = 0; it < 4; it++){
      int slot = tid + it*256;
      As4[slot] = sA[slot];
      Ws4[slot] = sW[slot];
    }
    __syncthreads();
    #pragma unroll
    for (int ks = 0; ks < 2; ks++){
      short8 af[4], bf_[4];
      #pragma unroll
      for (int fi = 0; fi < 4; fi++){
        int row = wm + fi*16 + lrow;
        U16S8 u; u.u4 = As4[row*8 + ((ks*4 + lk) ^ (lrow & 7))];
        af[fi] = u.s8;
      }
      #pragma unroll
      for (int fj = 0; fj < 4; fj++){
        int row = wn + fj*16 + lrow;
        U16S8 u; u.u4 = Ws4[row*8 + ((ks*4 + lk) ^ (lrow & 7))];
        bf_[fj] = u.s8;
      }
      #pragma unroll
      for (int fi = 0; fi < 4; fi++)
        #pragma unroll
        for (int fj = 0; fj < 4; fj++)
          acc[fi][fj] = __builtin_amdgcn_mfma_f32_16x16x32_bf16(af[fi], bf_[fj], acc[fi][fj], 0, 0, 0);
    }
    __syncthreads();
  }
  #pragma unroll
  for (int fj = 0; fj < 4; fj++){
    int n = n0 + wn + fj*16 + lrow;
    float bias = lb[n];
    #pragma unroll
    for (int fi = 0; fi < 4; fi++){
      floatx4 av = acc[fi][fj];
      int mb = m0 + wm + fi*16 + lk*4;
      #pragma unroll
      for (int r = 0; r < 4; r++){
        int m = mb + r;
        if (m < B*T) out[(long)m*V + n] = av[r] + bias;
      }
    }
  }
}

// fallback GEMM: A pre-swizzled, W converted inline from f32
__global__ __launch_bounds__(256, 2) void k_gemm_inl(const uint4* __restrict__ Abf4,
                      const float* __restrict__ lw, const float* __restrict__ lb,
                      float* __restrict__ out){
  __shared__ uint4 As4[1024];
  __shared__ uint4 Ws4[1024];
  const int tid = threadIdx.x;
  int orig = blockIdx.x;
  int xcd = orig & 7, ii = orig >> 3;
  int wgid = (xcd < 2 ? xcd*407 : 814 + (xcd-2)*406) + ii;
  int bm = wgid % 13, bn = wgid / 13;
  int m0 = bm*128, n0 = bn*128;
  const int wv = tid >> 6, l = tid & 63;
  const int wm = (wv >> 1)*64, wn = (wv & 1)*64;
  const int lrow = l & 15, lk = l >> 4;

  floatx4 acc[4][4] = {};
  for (int k0c = 0; k0c < 16; k0c++){
    const uint4* sA = Abf4 + (long)(bm*16 + k0c)*1024;
    #pragma unroll
    for (int it = 0; it < 4; it++){
      int slot = tid + it*256;
      As4[slot] = sA[slot];
      int row = slot >> 3, seg = slot & 7;
      const float4* src = (const float4*)(lw + (long)(n0+row)*H + k0c*64 + seg*8);
      float4 v0 = src[0], v1 = src[1];
      uint4 pk;
      pk.x = pkbf(v0.x, v0.y); pk.y = pkbf(v0.z, v0.w);
      pk.z = pkbf(v1.x, v1.y); pk.w = pkbf(v1.z, v1.w);
      Ws4[row*8 + (seg ^ (row & 7))] = pk;
    }
    __syncthreads();
    #pragma unroll
    for (int ks = 0; ks < 2; ks++){
      short8 af[4], bf_[4];
      #pragma unroll
      for (int fi = 0; fi < 4; fi++){
        int row = wm + fi*16 + lrow;
        U16S8 u; u.u4 = As4[row*8 + ((ks*4 + lk) ^ (lrow & 7))];
        af[fi] = u.s8;
      }
      #pragma unroll
      for (int fj = 0; fj < 4; fj++){
        int row = wn + fj*16 + lrow;
        U16S8 u; u.u4 = Ws4[row*8 + ((ks*4 + lk) ^ (lrow & 7))];
        bf_[fj] = u.s8;
      }
      #pragma unroll
      for (int fi = 0; fi < 4; fi++)
        #pragma unroll
        for (int fj = 0; fj < 4; fj++)
          acc[fi][fj] = __builtin_amdgcn_mfma_f32_16x16x32_bf16(af[fi], bf_[fj], acc[fi][fj], 0, 0, 0);
    }
    __syncthreads();
  }
  #pragma unroll
  for (int fj = 0; fj < 4; fj++){
    int n = n0 + wn + fj*16 + lrow;
    float bias = lb[n];
    #pragma unroll
    for (int fi = 0; fi < 4; fi++){
      floatx4 av = acc[fi][fj];
      int mb = m0 + wm + fi*16 + lk*4;
      #pragma unroll
      for (int r = 0; r < 4; r++){
        int m = mb + r;
        if (m < B*T) out[(long)m*V + n] = av[r] + bias;
      }
    }
  }
}

__global__ __launch_bounds__(256) void k_lsm(float* __restrict__ out){
  __shared__ float red[256];
  float4* row = (float4*)(out + (long)blockIdx.x * V);
  const int tid = threadIdx.x;
  float m = -INFINITY;
  for (int n=tid;n<V/4;n+=256){
    float4 v = row[n];
    m = fmaxf(m, fmaxf(fmaxf(v.x,v.y), fmaxf(v.z,v.w)));
  }
  red[tid]=m; __syncthreads();
  for (int s=128;s>0;s>>=1){ if(tid<s) red[tid]=fmaxf(red[tid],red[tid+s]); __syncthreads(); }
  m = red[0]; __syncthreads();
  float s = 0.f;
  for (int n=tid;n<V/4;n+=256){
    float4 v = row[n];
    s += __expf(v.x-m)+__expf(v.y-m)+__expf(v.z-m)+__expf(v.w-m);
  }
  red[tid]=s; __syncthreads();
  for (int st=128;st>0;st>>=1){ if(tid<st) red[tid]+=red[tid+st]; __syncthreads(); }
  float lse = m + __logf(red[0]);
  for (int n=tid;n<V/4;n+=256){
    float4 v = row[n];
    v.x-=lse; v.y-=lse; v.z-=lse; v.w-=lse;
    row[n] = v;
  }
}

extern "C" void kernel_launch(void* const* d_in, const int* in_sizes, int n_in,
                              void* d_out, int out_size, void* d_ws, size_t ws_size,
                              hipStream_t stream){
  const float* enc    = (const float*)d_in[0];
  const float* target = (const float*)d_in[1];
  const float* pw     = (const float*)d_in[2];
  const float* pb     = (const float*)d_in[3];
  const float* wih0   = (const float*)d_in[4];
  const float* whh0   = (const float*)d_in[5];
  const float* bih0   = (const float*)d_in[6];
  const float* bhh0   = (const float*)d_in[7];
  const float* wih1   = (const float*)d_in[8];
  const float* whh1   = (const float*)d_in[9];
  const float* bih1   = (const float*)d_in[10];
  const float* bhh1   = (const float*)d_in[11];
  const float* lw     = (const float*)d_in[12];
  const float* lb     = (const float*)d_in[13];
  float* out = (float*)d_out;

  float* ws   = (float*)d_ws;
  float* xg0  = ws;                              // 6,553,600 f
  float* P    = xg0 + (long)T*G4*B;              // 204,800 f
  float* encp = P + T*E*B;                       // 4,096 f
  unsigned* Abf = (unsigned*)(encp + B*E);       // 851,968 u32 (bf16 A, swizzled)
  unsigned* h0A2 = Abf + 851968;                 // 16,384 each
  unsigned* h0B2 = h0A2 + 16384;
  unsigned* h1A2 = h0B2 + 16384;
  unsigned* h1B2 = h1A2 + 16384;
  float* fh0a = (float*)(h1B2 + 16384);          // fallback f32 state
  float* fh0b = fh0a + H*B;
  float* fh1a = fh0b + H*B;
  float* fh1b = fh1a + H*B;
  float* fc0  = fh1b + H*B;
  float* fc1  = fc0 + H*B;
  unsigned* bar = (unsigned*)(fc1 + H*B);        // 1,024 u32
  unsigned* lwsw = bar + 1024;                   // 16,384,000 u32 (bf16 W, swizzled)
  size_t need = (size_t)((char*)(lwsw + 16384000) - (char*)d_ws);
  bool pre = (ws_size >= need);

  k_encp<<<B, E, 0, stream>>>(enc, pw, pb, encp);
  k_proj<<<T*B, E, 0, stream>>>(target, pw, encp, P);
  k_xg0<<<(T*G4*B)/256, 256, 0, stream>>>(wih0, bih0, bhh0, P, xg0);
  k_zero32<<<851968/256, 256, 0, stream>>>(Abf);
  k_zero32<<<4, 256, 0, stream>>>(bar);
  if (pre) k_cvtw<<<16000, 256, 0, stream>>>(lw, (uint4*)lwsw);

  void* cargs[] = {(void*)&whh0, (void*)&wih1, (void*)&whh1, (void*)&bih1, (void*)&bhh1,
                   (void*)&enc, (void*)&xg0,
                   (void*)&h0A2, (void*)&h0B2, (void*)&h1A2, (void*)&h1B2,
                   (void*)&Abf, (void*)&bar};
  hipError_t cerr = hipLaunchCooperativeKernel((void*)k_cells, dim3(NB), dim3(1024),
                                               cargs, 0, stream);
  if (cerr != hipSuccess){
    k_init<<<(H*B)/256, 256, 0, stream>>>(enc, fh0a, fc0, fh1a, fc1);
    float* h0in=fh0a; float* h0out=fh0b;
    float* h1in=fh1a; float* h1out=fh1b;
    for (int t=0;t<T;t++){
      k_cell0<<<256, 256, 0, stream>>>(whh0, xg0 + (long)t*G4*B, h0in, h0out, fc0);
      k_cell1<<<256, 256, 0, stream>>>(wih1, whh1, bih1, bhh1, h0out, h1in, h1out, fc1,
                                       Abf, t);
      float* tmp;
      tmp=h0in; h0in=h0out; h0out=tmp;
      tmp=h1in; h1in=h1out; h1out=tmp;
    }
  }

  if (pre) k_gemm_pre<<<3250, 256, 0, stream>>>((const uint4*)Abf, (const uint4*)lwsw, lb, out);
  else     k_gemm_inl<<<3250, 256, 0, stream>>>((const uint4*)Abf, lw, lb, out);
  k_lsm<<<B*T, 256, 0, stream>>>(out);
}

// Round 13
// 1548.579 us; speedup vs baseline: 11.2079x; 1.0803x over previous
//
#include <hip/hip_runtime.h>
#include <hip/hip_bf16.h>
#include <math.h>

#define B 32
#define T 50
#define H 1024
#define E 128
#define V 32000
#define G4 4096   // 4*H
#define HE 1152   // H+E
#define MROWS 1664 // 13*128 padded M for GEMM
#define NB 256    // coop grid blocks

typedef __fp16 half2v __attribute__((ext_vector_type(2)));
union U32H2 { unsigned u; half2v h; };
typedef short short8 __attribute__((ext_vector_type(8)));
typedef float floatx4 __attribute__((ext_vector_type(4)));
union U16S8 { uint4 u4; short8 s8; };

__device__ __forceinline__ float sigm(float x){ return 1.0f/(1.0f+expf(-x)); }

__device__ __forceinline__ half2v pk2(float a, float b){
#if __has_builtin(__builtin_amdgcn_cvt_pkrtz)
  return __builtin_amdgcn_cvt_pkrtz(a, b);
#else
  half2v r; r.x = (__fp16)a; r.y = (__fp16)b; return r;
#endif
}

__device__ __forceinline__ float dot2(half2v a, half2v b, float c){
#if __has_builtin(__builtin_amdgcn_fdot2)
  return __builtin_amdgcn_fdot2(a, b, c, false);
#else
  return c + (float)a.x*(float)b.x + (float)a.y*(float)b.y;
#endif
}

// pack two f32 -> one u32 of two bf16 (RNE)
__device__ __forceinline__ unsigned pkbf(float a, float b){
  unsigned ua = __float_as_uint(a), ub = __float_as_uint(b);
  unsigned ra = (ua + 0x7FFFu + ((ua>>16)&1u)) >> 16;
  unsigned rb = (ub + 0x7FFFu + ((ub>>16)&1u)) >> 16;
  return ra | (rb << 16);
}

// ---- two-level tree grid barrier: 8 leaves x 32 blocks + root ----
__device__ __forceinline__ void gbar(unsigned* bar, unsigned ep){
  __syncthreads();
  if (threadIdx.x == 0){
    __builtin_amdgcn_fence(__ATOMIC_RELEASE, "agent");
    unsigned g = blockIdx.x & 7u;
    unsigned old = __hip_atomic_fetch_add(&bar[64 + g*64], 1u,
                     __ATOMIC_RELAXED, __HIP_MEMORY_SCOPE_AGENT);
    if (old == ep*32u - 1u)
      __hip_atomic_fetch_add(&bar[0], 1u, __ATOMIC_RELAXED, __HIP_MEMORY_SCOPE_AGENT);
    while (__hip_atomic_load(&bar[0], __ATOMIC_RELAXED, __HIP_MEMORY_SCOPE_AGENT) < ep*8u)
      __builtin_amdgcn_s_sleep(1);
    __builtin_amdgcn_fence(__ATOMIC_ACQUIRE, "agent");
  }
  __syncthreads();
}

// encp[b][e] = proj_b[e] + sum_j enc[b][j] * proj_w[e][E+j]
__global__ void k_encp(const float* __restrict__ enc, const float* __restrict__ pw,
                       const float* __restrict__ pb, float* __restrict__ encp){
  int b = blockIdx.x, e = threadIdx.x;
  const float* er = enc + b*H;
  const float* wr = pw + e*HE + E;
  float acc = pb[e];
  for (int j=0;j<H;j+=4){
    float4 w4 = *(const float4*)(wr+j);
    float4 e4 = *(const float4*)(er+j);
    acc += w4.x*e4.x + w4.y*e4.y + w4.z*e4.z + w4.w*e4.w;
  }
  encp[b*E+e] = acc;
}

// P[t][e][b] = encp[b][e] + sum_j target[b][t][j] * proj_w[e][j]
__global__ void k_proj(const float* __restrict__ target, const float* __restrict__ pw,
                       const float* __restrict__ encp, float* __restrict__ P){
  int t = blockIdx.x / B, b = blockIdx.x % B, e = threadIdx.x;
  const float* xr = target + (b*T + t)*E;
  const float* wr = pw + e*HE;
  float acc = encp[b*E+e];
  for (int j=0;j<E;j+=4){
    float4 w4 = *(const float4*)(wr+j);
    float4 x4 = *(const float4*)(xr+j);
    acc += w4.x*x4.x + w4.y*x4.y + w4.z*x4.z + w4.w*x4.w;
  }
  P[(t*E + e)*B + b] = acc;
}

// xg0[t][r][b] = b_ih0[r]+b_hh0[r] + sum_e w_ih0[r][e] * P[t][e][b]
__global__ void k_xg0(const float* __restrict__ wih0, const float* __restrict__ bih0,
                      const float* __restrict__ bhh0, const float* __restrict__ P,
                      float* __restrict__ xg){
  int idx = blockIdx.x*256 + threadIdx.x;
  int b = idx & 31; int r = (idx >> 5) & 4095; int t = idx >> 17;
  const float* wr = wih0 + r*E;
  const float* pr = P + t*E*B + b;
  float acc = bih0[r] + bhh0[r];
  #pragma unroll 8
  for (int e=0;e<E;e++) acc += wr[e] * pr[e*B];
  xg[idx] = acc;
}

__global__ void k_zero32(unsigned* __restrict__ p){
  p[blockIdx.x*256 + threadIdx.x] = 0u;
}

// convert lw f32 -> bf16 in the GEMM's swizzled tile layout
__global__ void k_cvtw(const float* __restrict__ lw, uint4* __restrict__ wsw){
  int gid = blockIdx.x*256 + threadIdx.x;   // 4,096,000
  int n = gid >> 7, rem = gid & 127;
  int k0c = rem >> 3, seg = rem & 7;
  const float4* src = (const float4*)(lw + (long)n*H + k0c*64 + seg*8);
  float4 v0 = src[0], v1 = src[1];
  uint4 pk;
  pk.x = pkbf(v0.x, v0.y); pk.y = pkbf(v0.z, v0.w);
  pk.z = pkbf(v1.x, v1.y); pk.w = pkbf(v1.z, v1.w);
  int bn = n >> 7, row = n & 127;
  wsw[((long)(bn*16 + k0c)*128 + row)*8 + (seg ^ (row & 7))] = pk;
}

// pack H1Tmk f32 [m][k] -> Abf swizzled bf16 tiles (m < 1600 only)
__global__ void k_pack(const float* __restrict__ H1Tmk, uint4* __restrict__ Abf){
  int gid = blockIdx.x*256 + threadIdx.x;   // 204,800
  int m = gid >> 7, rem = gid & 127;
  int k0c = rem >> 3, seg = rem & 7;
  const float4* src = (const float4*)(H1Tmk + (long)m*1024 + k0c*64 + seg*8);
  float4 v0 = src[0], v1 = src[1];
  uint4 pk;
  pk.x = pkbf(v0.x, v0.y); pk.y = pkbf(v0.z, v0.w);
  pk.z = pkbf(v1.x, v1.y); pk.w = pkbf(v1.z, v1.w);
  int bm = m >> 7, row = m & 127;
  Abf[((long)(bm*16 + k0c)*128 + row)*8 + (seg ^ (row & 7))] = pk;
}

// ---------------- cooperative persistent cells (v5, verified round 9) ----------------
__global__ __launch_bounds__(1024, 4) void k_cells(
    const float* __restrict__ whh0, const float* __restrict__ wih1, const float* __restrict__ whh1,
    const float* __restrict__ bih1, const float* __restrict__ bhh1,
    const float* __restrict__ enc, const float* __restrict__ xg0,
    unsigned* __restrict__ h0A2, unsigned* __restrict__ h0B2,
    unsigned* __restrict__ h1A2, unsigned* __restrict__ h1B2,
    float* __restrict__ H1Tmk, unsigned* __restrict__ bar){
  const int gB = blockIdx.x;
  const int tid = threadIdx.x;
  const int w = tid >> 6;       // wave 0..15 = k-chunk owner
  const int l = tid & 63;
  const int b = l & 31;
  const int rh = l >> 5;        // row-half: rows rh*8..rh*8+7

  __shared__ half2v w0s[16][512];        // layer0 whh0 rows (32 KB)
  __shared__ half2v w1s[32][512];        // wih1(0-15) + whh1(16-31) (64 KB)
  __shared__ float partial[16][16][32];  // [wave][row][b] (32 KB)
  __shared__ float gates[16][32];
  __shared__ float cst[2][4][32];
  __shared__ float bs1v[16];
  __shared__ __fp16 h1loc[4][1600];      // [hl][b*T+t] (12.8 KB)

  // ---- stage weights f32 -> f16 pairs ----
  for (int i = tid; i < 16*512; i += 1024){
    int r = i >> 9, k2 = i & 511;
    int q = r >> 2, hl = r & 3;
    float2 v = *(const float2*)(whh0 + ((long)q*H + 4*gB + hl)*H + 2*k2);
    w0s[r][k2] = pk2(v.x, v.y);
  }
  for (int i = tid; i < 32*512; i += 1024){
    int r = i >> 9, k2 = i & 511;
    int rr = r & 15;
    int q = rr >> 2, hl = rr & 3;
    const float* srcm = (r < 16) ? wih1 : whh1;
    float2 v = *(const float2*)(srcm + ((long)q*H + 4*gB + hl)*H + 2*k2);
    w1s[r][k2] = pk2(v.x, v.y);
  }
  if (tid < 16){
    int q = tid >> 2, hl = tid & 3;
    bs1v[tid] = bih1[q*H + 4*gB + hl] + bhh1[q*H + 4*gB + hl];
  }
  if (tid < 128){
    int hl = tid >> 5, bb = tid & 31;
    float v = enc[bb*H + 4*gB + hl];
    cst[0][hl][bb] = v; cst[1][hl][bb] = v;
  }
  if (tid < 64){
    int hp = tid >> 5, bb = tid & 31;
    U32H2 uu;
    uu.h = pk2(enc[bb*H + 4*gB + 2*hp], enc[bb*H + 4*gB + 2*hp + 1]);
    h0A2[(2*gB + hp)*32 + bb] = uu.u;
    h1A2[(2*gB + hp)*32 + bb] = uu.u;
  }
  unsigned ep = 1;
  gbar(bar, ep); ep++;

  for (int p = 0; p <= T; p++){
    const unsigned* h0r = (p & 1) ? h0B2 : h0A2;
    unsigned*       h0w = (p & 1) ? h0A2 : h0B2;
    const unsigned* h1r = (p & 1) ? h1A2 : h1B2;
    unsigned*       h1w = (p & 1) ? h1B2 : h1A2;

    // xg prefetch for layer0(p)
    float xgv = 0.f;
    if (p < T && tid < 512){
      int r = tid >> 5, bb = tid & 31;
      int q = r >> 2, hl = r & 3;
      xgv = xg0[((long)p*G4 + (long)q*H + 4*gB + hl)*32 + bb];
    }

    // ---- merged matvec ----
    float a0[8] = {0,0,0,0,0,0,0,0};
    {
      int c = (w + gB + p) & 15;
      const unsigned* sa = h0r + c*1024 + b;
      const unsigned* sb = h1r + c*1024 + b;
      if (p == 0){
        #pragma unroll 4
        for (int j = 0; j < 32; j++){
          U32H2 ua; ua.u = sa[j*32];
          int k2 = c*32 + j;
          #pragma unroll
          for (int r = 0; r < 8; r++)
            a0[r] = dot2(w0s[rh*8 + r][k2], ua.h, a0[r]);
        }
      } else if (p == T){
        float aI[8] = {0,0,0,0,0,0,0,0}, aH[8] = {0,0,0,0,0,0,0,0};
        #pragma unroll 4
        for (int j = 0; j < 32; j++){
          U32H2 ua; ua.u = sa[j*32];
          U32H2 ub; ub.u = sb[j*32];
          int k2 = c*32 + j;
          #pragma unroll
          for (int r = 0; r < 8; r++){
            aI[r] = dot2(w1s[rh*8 + r][k2], ua.h, aI[r]);
            aH[r] = dot2(w1s[16 + rh*8 + r][k2], ub.h, aH[r]);
          }
        }
        #pragma unroll
        for (int r = 0; r < 8; r++) partial[w][rh*8 + r][b] = aI[r] + aH[r];
      } else {
        float aI[8] = {0,0,0,0,0,0,0,0}, aH[8] = {0,0,0,0,0,0,0,0};
        #pragma unroll 2
        for (int j = 0; j < 32; j++){
          U32H2 ua; ua.u = sa[j*32];
          U32H2 ub; ub.u = sb[j*32];
          int k2 = c*32 + j;
          #pragma unroll
          for (int r = 0; r < 8; r++){
            aI[r] = dot2(w1s[rh*8 + r][k2], ua.h, aI[r]);
            aH[r] = dot2(w1s[16 + rh*8 + r][k2], ub.h, aH[r]);
            a0[r] = dot2(w0s[rh*8 + r][k2], ua.h, a0[r]);
          }
        }
        #pragma unroll
        for (int r = 0; r < 8; r++) partial[w][rh*8 + r][b] = aI[r] + aH[r];
      }
    }
    __syncthreads();
    // ---- layer1(p-1) reduce + cell ----
    if (p >= 1 && tid < 512){
      int r = tid >> 5, bb = tid & 31;
      float s = 0.f;
      #pragma unroll
      for (int w2 = 0; w2 < 16; w2++) s += partial[w2][r][bb];
      float v = s + bs1v[r];
      gates[r][bb] = ((r >> 2) == 2) ? tanhf(v) : sigm(v);
    }
    __syncthreads();
    if (p >= 1 && tid < 64){
      int hp = tid >> 5, bb = tid & 31;
      int t1 = p - 1;
      float hn0, hn1;
      {
        int hl = 2*hp;
        float cn = gates[4+hl][bb]*cst[1][hl][bb] + gates[0+hl][bb]*gates[8+hl][bb];
        cst[1][hl][bb] = cn;
        hn0 = gates[12+hl][bb]*tanhf(cn);
        h1loc[hl][bb*T + t1] = (__fp16)hn0;
      }
      {
        int hl = 2*hp + 1;
        float cn = gates[4+hl][bb]*cst[1][hl][bb] + gates[0+hl][bb]*gates[8+hl][bb];
        cst[1][hl][bb] = cn;
        hn1 = gates[12+hl][bb]*tanhf(cn);
        h1loc[hl][bb*T + t1] = (__fp16)hn1;
      }
      U32H2 uu; uu.h = pk2(hn0, hn1);
      h1w[(2*gB + hp)*32 + bb] = uu.u;
    }
    // ---- layer0(p) partial stash ----
    if (p < T){
      #pragma unroll
      for (int r = 0; r < 8; r++) partial[w][rh*8 + r][b] = a0[r];
    }
    __syncthreads();
    if (p < T && tid < 512){
      int r = tid >> 5, bb = tid & 31;
      float s = 0.f;
      #pragma unroll
      for (int w2 = 0; w2 < 16; w2++) s += partial[w2][r][bb];
      float v = s + xgv;
      gates[r][bb] = ((r >> 2) == 2) ? tanhf(v) : sigm(v);
    }
    __syncthreads();
    if (p < T && tid < 64){
      int hp = tid >> 5, bb = tid & 31;
      float hn0, hn1;
      {
        int hl = 2*hp;
        float cn = gates[4+hl][bb]*cst[0][hl][bb] + gates[0+hl][bb]*gates[8+hl][bb];
        cst[0][hl][bb] = cn;
        hn0 = gates[12+hl][bb]*tanhf(cn);
      }
      {
        int hl = 2*hp + 1;
        float cn = gates[4+hl][bb]*cst[0][hl][bb] + gates[0+hl][bb]*gates[8+hl][bb];
        cst[0][hl][bb] = cn;
        hn1 = gates[12+hl][bb]*tanhf(cn);
      }
      U32H2 uu; uu.h = pk2(hn0, hn1);
      h0w[(2*gB + hp)*32 + bb] = uu.u;
    }
    gbar(bar, ep); ep++;
  }

  // H1Tmk flush: row m = b*T+t, 4 contiguous k = 4gB..4gB+3 (16B store)
  for (int m = tid; m < B*T; m += 1024){
    float4 v;
    v.x = (float)h1loc[0][m]; v.y = (float)h1loc[1][m];
    v.z = (float)h1loc[2][m]; v.w = (float)h1loc[3][m];
    *(float4*)&H1Tmk[(long)m*1024 + 4*gB] = v;
  }
}

// ---------------- fallback per-step cells ----------------
__global__ void k_init(const float* __restrict__ enc, float* __restrict__ h0, float* __restrict__ c0,
                       float* __restrict__ h1, float* __restrict__ c1){
  int idx = blockIdx.x*256 + threadIdx.x;
  int b = idx & 31, h = idx >> 5;
  float v = enc[b*H + h];
  h0[idx]=v; c0[idx]=v; h1[idx]=v; c1[idx]=v;
}

__global__ __launch_bounds__(256) void k_cell0(const float* __restrict__ whh, const float* __restrict__ xg_t,
                       const float* __restrict__ h_in, float* __restrict__ h_out,
                       float* __restrict__ c){
  int h = (blockIdx.x*256 + threadIdx.x) >> 6;
  int lane = threadIdx.x & 63;
  int b = lane & 31, kh = lane >> 5;
  const float* w0 = whh + (0*H + h)*H + kh*512;
  const float* w1 = whh + (1*H + h)*H + kh*512;
  const float* w2 = whh + (2*H + h)*H + kh*512;
  const float* w3 = whh + (3*H + h)*H + kh*512;
  const float* hk = h_in + (kh*512)*B + b;
  float a0=0,a1=0,a2=0,a3=0, p0=0,p1=0,p2=0,p3=0;
  #pragma unroll 4
  for (int k=0;k<512;k+=4){
    float4 w40 = *(const float4*)(w0+k);
    float4 w41 = *(const float4*)(w1+k);
    float4 w42 = *(const float4*)(w2+k);
    float4 w43 = *(const float4*)(w3+k);
    float hv0 = hk[(k+0)*B], hv1 = hk[(k+1)*B], hv2 = hk[(k+2)*B], hv3 = hk[(k+3)*B];
    a0 += w40.x*hv0 + w40.y*hv1;  p0 += w40.z*hv2 + w40.w*hv3;
    a1 += w41.x*hv0 + w41.y*hv1;  p1 += w41.z*hv2 + w41.w*hv3;
    a2 += w42.x*hv0 + w42.y*hv1;  p2 += w42.z*hv2 + w42.w*hv3;
    a3 += w43.x*hv0 + w43.y*hv1;  p3 += w43.z*hv2 + w43.w*hv3;
  }
  float g0=a0+p0, g1=a1+p1, g2=a2+p2, g3=a3+p3;
  g0 += __shfl_xor(g0, 32);
  g1 += __shfl_xor(g1, 32);
  g2 += __shfl_xor(g2, 32);
  g3 += __shfl_xor(g3, 32);
  g0 += xg_t[(0*H+h)*B + b];
  g1 += xg_t[(1*H+h)*B + b];
  g2 += xg_t[(2*H+h)*B + b];
  g3 += xg_t[(3*H+h)*B + b];
  float ig = sigm(g0), fg = sigm(g1), gg = tanhf(g2), og = sigm(g3);
  int sidx = h*B + b;
  float cn = fg*c[sidx] + ig*gg;
  float hn = og*tanhf(cn);
  if (kh==0){ c[sidx]=cn; h_out[sidx]=hn; }
}

__global__ __launch_bounds__(256) void k_cell1(const float* __restrict__ wih, const float* __restrict__ whh,
                       const float* __restrict__ bih, const float* __restrict__ bhh,
                       const float* __restrict__ h0n, const float* __restrict__ h_in,
                       float* __restrict__ h_out, float* __restrict__ c,
                       float* __restrict__ H1Tmk, int t){
  int h = (blockIdx.x*256 + threadIdx.x) >> 6;
  int lane = threadIdx.x & 63;
  int b = lane & 31, kh = lane >> 5;
  float a0=0,a1=0,a2=0,a3=0, p0=0,p1=0,p2=0,p3=0;
  {
    const float* w0 = wih + (0*H + h)*H + kh*512;
    const float* w1 = wih + (1*H + h)*H + kh*512;
    const float* w2 = wih + (2*H + h)*H + kh*512;
    const float* w3 = wih + (3*H + h)*H + kh*512;
    const float* hk = h0n + (kh*512)*B + b;
    #pragma unroll 4
    for (int k=0;k<512;k+=4){
      float4 w40 = *(const float4*)(w0+k);
      float4 w41 = *(const float4*)(w1+k);
      float4 w42 = *(const float4*)(w2+k);
      float4 w43 = *(const float4*)(w3+k);
      float hv0 = hk[(k+0)*B], hv1 = hk[(k+1)*B], hv2 = hk[(k+2)*B], hv3 = hk[(k+3)*B];
      a0 += w40.x*hv0 + w40.y*hv1;  p0 += w40.z*hv2 + w40.w*hv3;
      a1 += w41.x*hv0 + w41.y*hv1;  p1 += w41.z*hv2 + w41.w*hv3;
      a2 += w42.x*hv0 + w42.y*hv1;  p2 += w42.z*hv2 + w42.w*hv3;
      a3 += w43.x*hv0 + w43.y*hv1;  p3 += w43.z*hv2 + w43.w*hv3;
    }
  }
  {
    const float* w0 = whh + (0*H + h)*H + kh*512;
    const float* w1 = whh + (1*H + h)*H + kh*512;
    const float* w2 = whh + (2*H + h)*H + kh*512;
    const float* w3 = whh + (3*H + h)*H + kh*512;
    const float* hk = h_in + (kh*512)*B + b;
    #pragma unroll 4
    for (int k=0;k<512;k+=4){
      float4 w40 = *(const float4*)(w0+k);
      float4 w41 = *(const float4*)(w1+k);
      float4 w42 = *(const float4*)(w2+k);
      float4 w43 = *(const float4*)(w3+k);
      float hv0 = hk[(k+0)*B], hv1 = hk[(k+1)*B], hv2 = hk[(k+2)*B], hv3 = hk[(k+3)*B];
      a0 += w40.x*hv0 + w40.y*hv1;  p0 += w40.z*hv2 + w40.w*hv3;
      a1 += w41.x*hv0 + w41.y*hv1;  p1 += w41.z*hv2 + w41.w*hv3;
      a2 += w42.x*hv0 + w42.y*hv1;  p2 += w42.z*hv2 + w42.w*hv3;
      a3 += w43.x*hv0 + w43.y*hv1;  p3 += w43.z*hv2 + w43.w*hv3;
    }
  }
  float g0=a0+p0, g1=a1+p1, g2=a2+p2, g3=a3+p3;
  g0 += __shfl_xor(g0, 32);
  g1 += __shfl_xor(g1, 32);
  g2 += __shfl_xor(g2, 32);
  g3 += __shfl_xor(g3, 32);
  g0 += bih[0*H+h] + bhh[0*H+h];
  g1 += bih[1*H+h] + bhh[1*H+h];
  g2 += bih[2*H+h] + bhh[2*H+h];
  g3 += bih[3*H+h] + bhh[3*H+h];
  float ig = sigm(g0), fg = sigm(g1), gg = tanhf(g2), og = sigm(g3);
  int sidx = h*B + b;
  float cn = fg*c[sidx] + ig*gg;
  float hn = og*tanhf(cn);
  if (kh==0){ c[sidx]=cn; h_out[sidx]=hn; H1Tmk[((long)(b*T + t))*1024 + h] = hn; }
}

// ---------------- MFMA bf16 output GEMM (pre-swizzled operands) ----------------
__global__ __launch_bounds__(256, 2) void k_gemm_pre(const uint4* __restrict__ Abf4,
                      const uint4* __restrict__ Wsw4, const float* __restrict__ lb,
                      float* __restrict__ out){
  __shared__ uint4 As4[1024];
  __shared__ uint4 Ws4[1024];
  const int tid = threadIdx.x;
  int orig = blockIdx.x;
  int xcd = orig & 7, ii = orig >> 3;
  int wgid = (xcd < 2 ? xcd*407 : 814 + (xcd-2)*406) + ii;
  int bm = wgid % 13, bn = wgid / 13;
  int m0 = bm*128, n0 = bn*128;
  const int wv = tid >> 6, l = tid & 63;
  const int wm = (wv >> 1)*64, wn = (wv & 1)*64;
  const int lrow = l & 15, lk = l >> 4;

  floatx4 acc[4][4] = {};
  for (int k0c = 0; k0c < 16; k0c++){
    const uint4* sA = Abf4 + (long)(bm*16 + k0c)*1024;
    const uint4* sW = Wsw4 + (long)(bn*16 + k0c)*1024;
    #pragma unroll
    for (int it = 0; it < 4; it++){
      int slot = tid + it*256;
      As4[slot] = sA[slot];
      Ws4[slot] = sW[slot];
    }
    __syncthreads();
    #pragma unroll
    for (int ks = 0; ks < 2; ks++){
      short8 af[4], bf_[4];
      #pragma unroll
      for (int fi = 0; fi < 4; fi++){
        int row = wm + fi*16 + lrow;
        U16S8 u; u.u4 = As4[row*8 + ((ks*4 + lk) ^ (lrow & 7))];
        af[fi] = u.s8;
      }
      #pragma unroll
      for (int fj = 0; fj < 4; fj++){
        int row = wn + fj*16 + lrow;
        U16S8 u; u.u4 = Ws4[row*8 + ((ks*4 + lk) ^ (lrow & 7))];
        bf_[fj] = u.s8;
      }
      #pragma unroll
      for (int fi = 0; fi < 4; fi++)
        #pragma unroll
        for (int fj = 0; fj < 4; fj++)
          acc[fi][fj] = __builtin_amdgcn_mfma_f32_16x16x32_bf16(af[fi], bf_[fj], acc[fi][fj], 0, 0, 0);
    }
    __syncthreads();
  }
  #pragma unroll
  for (int fj = 0; fj < 4; fj++){
    int n = n0 + wn + fj*16 + lrow;
    float bias = lb[n];
    #pragma unroll
    for (int fi = 0; fi < 4; fi++){
      floatx4 av = acc[fi][fj];
      int mb = m0 + wm + fi*16 + lk*4;
      #pragma unroll
      for (int r = 0; r < 4; r++){
        int m = mb + r;
        if (m < B*T) out[(long)m*V + n] = av[r] + bias;
      }
    }
  }
}

// fallback GEMM: A pre-swizzled, W converted inline from f32
__global__ __launch_bounds__(256, 2) void k_gemm_inl(const uint4* __restrict__ Abf4,
                      const float* __restrict__ lw, const float* __restrict__ lb,
                      float* __restrict__ out){
  __shared__ uint4 As4[1024];
  __shared__ uint4 Ws4[1024];
  const int tid = threadIdx.x;
  int orig = blockIdx.x;
  int xcd = orig & 7, ii = orig >> 3;
  int wgid = (xcd < 2 ? xcd*407 : 814 + (xcd-2)*406) + ii;
  int bm = wgid % 13, bn = wgid / 13;
  int m0 = bm*128, n0 = bn*128;
  const int wv = tid >> 6, l = tid & 63;
  const int wm = (wv >> 1)*64, wn = (wv & 1)*64;
  const int lrow = l & 15, lk = l >> 4;

  floatx4 acc[4][4] = {};
  for (int k0c = 0; k0c < 16; k0c++){
    const uint4* sA = Abf4 + (long)(bm*16 + k0c)*1024;
    #pragma unroll
    for (int it = 0; it < 4; it++){
      int slot = tid + it*256;
      As4[slot] = sA[slot];
      int row = slot >> 3, seg = slot & 7;
      const float4* src = (const float4*)(lw + (long)(n0+row)*H + k0c*64 + seg*8);
      float4 v0 = src[0], v1 = src[1];
      uint4 pk;
      pk.x = pkbf(v0.x, v0.y); pk.y = pkbf(v0.z, v0.w);
      pk.z = pkbf(v1.x, v1.y); pk.w = pkbf(v1.z, v1.w);
      Ws4[row*8 + (seg ^ (row & 7))] = pk;
    }
    __syncthreads();
    #pragma unroll
    for (int ks = 0; ks < 2; ks++){
      short8 af[4], bf_[4];
      #pragma unroll
      for (int fi = 0; fi < 4; fi++){
        int row = wm + fi*16 + lrow;
        U16S8 u; u.u4 = As4[row*8 + ((ks*4 + lk) ^ (lrow & 7))];
        af[fi] = u.s8;
      }
      #pragma unroll
      for (int fj = 0; fj < 4; fj++){
        int row = wn + fj*16 + lrow;
        U16S8 u; u.u4 = Ws4[row*8 + ((ks*4 + lk) ^ (lrow & 7))];
        bf_[fj] = u.s8;
      }
      #pragma unroll
      for (int fi = 0; fi < 4; fi++)
        #pragma unroll
        for (int fj = 0; fj < 4; fj++)
          acc[fi][fj] = __builtin_amdgcn_mfma_f32_16x16x32_bf16(af[fi], bf_[fj], acc[fi][fj], 0, 0, 0);
    }
    __syncthreads();
  }
  #pragma unroll
  for (int fj = 0; fj < 4; fj++){
    int n = n0 + wn + fj*16 + lrow;
    float bias = lb[n];
    #pragma unroll
    for (int fi = 0; fi < 4; fi++){
      floatx4 av = acc[fi][fj];
      int mb = m0 + wm + fi*16 + lk*4;
      #pragma unroll
      for (int r = 0; r < 4; r++){
        int m = mb + r;
        if (m < B*T) out[(long)m*V + n] = av[r] + bias;
      }
    }
  }
}

__global__ __launch_bounds__(256) void k_lsm(float* __restrict__ out){
  __shared__ float red[256];
  float4* row = (float4*)(out + (long)blockIdx.x * V);
  const int tid = threadIdx.x;
  float m = -INFINITY;
  for (int n=tid;n<V/4;n+=256){
    float4 v = row[n];
    m = fmaxf(m, fmaxf(fmaxf(v.x,v.y), fmaxf(v.z,v.w)));
  }
  red[tid]=m; __syncthreads();
  for (int s=128;s>0;s>>=1){ if(tid<s) red[tid]=fmaxf(red[tid],red[tid+s]); __syncthreads(); }
  m = red[0]; __syncthreads();
  float s = 0.f;
  for (int n=tid;n<V/4;n+=256){
    float4 v = row[n];
    s += __expf(v.x-m)+__expf(v.y-m)+__expf(v.z-m)+__expf(v.w-m);
  }
  red[tid]=s; __syncthreads();
  for (int st=128;st>0;st>>=1){ if(tid<st) red[tid]+=red[tid+st]; __syncthreads(); }
  float lse = m + __logf(red[0]);
  for (int n=tid;n<V/4;n+=256){
    float4 v = row[n];
    v.x-=lse; v.y-=lse; v.z-=lse; v.w-=lse;
    row[n] = v;
  }
}

extern "C" void kernel_launch(void* const* d_in, const int* in_sizes, int n_in,
                              void* d_out, int out_size, void* d_ws, size_t ws_size,
                              hipStream_t stream){
  const float* enc    = (const float*)d_in[0];
  const float* target = (const float*)d_in[1];
  const float* pw     = (const float*)d_in[2];
  const float* pb     = (const float*)d_in[3];
  const float* wih0   = (const float*)d_in[4];
  const float* whh0   = (const float*)d_in[5];
  const float* bih0   = (const float*)d_in[6];
  const float* bhh0   = (const float*)d_in[7];
  const float* wih1   = (const float*)d_in[8];
  const float* whh1   = (const float*)d_in[9];
  const float* bih1   = (const float*)d_in[10];
  const float* bhh1   = (const float*)d_in[11];
  const float* lw     = (const float*)d_in[12];
  const float* lb     = (const float*)d_in[13];
  float* out = (float*)d_out;

  float* ws   = (float*)d_ws;
  float* xg0  = ws;                              // 6,553,600 f
  float* P    = xg0 + (long)T*G4*B;              // 204,800 f
  float* encp = P + T*E*B;                       // 4,096 f
  float* H1Tmk = encp + B*E;                     // MROWS*1024 = 1,703,936 f
  unsigned* Abf = (unsigned*)(H1Tmk + (long)MROWS*1024);  // 851,968 u32
  unsigned* h0A2 = Abf + 851968;                 // 16,384 each
  unsigned* h0B2 = h0A2 + 16384;
  unsigned* h1A2 = h0B2 + 16384;
  unsigned* h1B2 = h1A2 + 16384;
  float* fh0a = (float*)(h1B2 + 16384);          // fallback f32 state
  float* fh0b = fh0a + H*B;
  float* fh1a = fh0b + H*B;
  float* fh1b = fh1a + H*B;
  float* fc0  = fh1b + H*B;
  float* fc1  = fc0 + H*B;
  unsigned* bar = (unsigned*)(fc1 + H*B);        // 1,024 u32
  unsigned* lwsw = bar + 1024;                   // 16,384,000 u32
  size_t need = (size_t)((char*)(lwsw + 16384000) - (char*)d_ws);
  bool pre = (ws_size >= need);

  k_encp<<<B, E, 0, stream>>>(enc, pw, pb, encp);
  k_proj<<<T*B, E, 0, stream>>>(target, pw, encp, P);
  k_xg0<<<(T*G4*B)/256, 256, 0, stream>>>(wih0, bih0, bhh0, P, xg0);
  k_zero32<<<4, 256, 0, stream>>>(bar);
  if (pre) k_cvtw<<<16000, 256, 0, stream>>>(lw, (uint4*)lwsw);

  void* cargs[] = {(void*)&whh0, (void*)&wih1, (void*)&whh1, (void*)&bih1, (void*)&bhh1,
                   (void*)&enc, (void*)&xg0,
                   (void*)&h0A2, (void*)&h0B2, (void*)&h1A2, (void*)&h1B2,
                   (void*)&H1Tmk, (void*)&bar};
  hipError_t cerr = hipLaunchCooperativeKernel((void*)k_cells, dim3(NB), dim3(1024),
                                               cargs, 0, stream);
  if (cerr != hipSuccess){
    k_init<<<(H*B)/256, 256, 0, stream>>>(enc, fh0a, fc0, fh1a, fc1);
    float* h0in=fh0a; float* h0out=fh0b;
    float* h1in=fh1a; float* h1out=fh1b;
    for (int t=0;t<T;t++){
      k_cell0<<<256, 256, 0, stream>>>(whh0, xg0 + (long)t*G4*B, h0in, h0out, fc0);
      k_cell1<<<256, 256, 0, stream>>>(wih1, whh1, bih1, bhh1, h0out, h1in, h1out, fc1,
                                       H1Tmk, t);
      float* tmp;
      tmp=h0in; h0in=h0out; h0out=tmp;
      tmp=h1in; h1in=h1out; h1out=tmp;
    }
  }

  k_pack<<<800, 256, 0, stream>>>(H1Tmk, (uint4*)Abf);
  if (pre) k_gemm_pre<<<3250, 256, 0, stream>>>((const uint4*)Abf, (const uint4*)lwsw, lb, out);
  else     k_gemm_inl<<<3250, 256, 0, stream>>>((const uint4*)Abf, lw, lb, out);
  k_lsm<<<B*T, 256, 0, stream>>>(out);
}

// Round 14
// 1440.204 us; speedup vs baseline: 12.0513x; 1.0752x over previous
//
#include <hip/hip_runtime.h>
#include <hip/hip_bf16.h>
#include <math.h>

#define B 32
#define T 50
#define H 1024
#define E 128
#define V 32000
#define G4 4096   // 4*H
#define HE 1152   // H+E
#define MROWS 1664 // 13*128 padded M for GEMM
#define NB 256    // coop grid blocks

typedef __fp16 half2v __attribute__((ext_vector_type(2)));
typedef __fp16 half8 __attribute__((ext_vector_type(8)));
union U32H2 { unsigned u; half2v h; };
union U4H8 { uint4 u4; half8 h8; };
typedef short short8 __attribute__((ext_vector_type(8)));
typedef float floatx4 __attribute__((ext_vector_type(4)));
union U16S8 { uint4 u4; short8 s8; };

__device__ __forceinline__ float sigm(float x){ return 1.0f/(1.0f+expf(-x)); }

__device__ __forceinline__ half2v pk2(float a, float b){
#if __has_builtin(__builtin_amdgcn_cvt_pkrtz)
  return __builtin_amdgcn_cvt_pkrtz(a, b);
#else
  half2v r; r.x = (__fp16)a; r.y = (__fp16)b; return r;
#endif
}

// pack two f32 -> one u32 of two bf16 (RNE)
__device__ __forceinline__ unsigned pkbf(float a, float b){
  unsigned ua = __float_as_uint(a), ub = __float_as_uint(b);
  unsigned ra = (ua + 0x7FFFu + ((ua>>16)&1u)) >> 16;
  unsigned rb = (ub + 0x7FFFu + ((ub>>16)&1u)) >> 16;
  return ra | (rb << 16);
}

// ---- two-level tree grid barrier: 8 leaves x 32 blocks + root ----
__device__ __forceinline__ void gbar(unsigned* bar, unsigned ep){
  __syncthreads();
  if (threadIdx.x == 0){
    __builtin_amdgcn_fence(__ATOMIC_RELEASE, "agent");
    unsigned g = blockIdx.x & 7u;
    unsigned old = __hip_atomic_fetch_add(&bar[64 + g*64], 1u,
                     __ATOMIC_RELAXED, __HIP_MEMORY_SCOPE_AGENT);
    if (old == ep*32u - 1u)
      __hip_atomic_fetch_add(&bar[0], 1u, __ATOMIC_RELAXED, __HIP_MEMORY_SCOPE_AGENT);
    while (__hip_atomic_load(&bar[0], __ATOMIC_RELAXED, __HIP_MEMORY_SCOPE_AGENT) < ep*8u)
      __builtin_amdgcn_s_sleep(1);
    __builtin_amdgcn_fence(__ATOMIC_ACQUIRE, "agent");
  }
  __syncthreads();
}

// encp[b][e] = proj_b[e] + sum_j enc[b][j] * proj_w[e][E+j]
__global__ void k_encp(const float* __restrict__ enc, const float* __restrict__ pw,
                       const float* __restrict__ pb, float* __restrict__ encp){
  int b = blockIdx.x, e = threadIdx.x;
  const float* er = enc + b*H;
  const float* wr = pw + e*HE + E;
  float acc = pb[e];
  for (int j=0;j<H;j+=4){
    float4 w4 = *(const float4*)(wr+j);
    float4 e4 = *(const float4*)(er+j);
    acc += w4.x*e4.x + w4.y*e4.y + w4.z*e4.z + w4.w*e4.w;
  }
  encp[b*E+e] = acc;
}

// P[t][e][b] = encp[b][e] + sum_j target[b][t][j] * proj_w[e][j]
__global__ void k_proj(const float* __restrict__ target, const float* __restrict__ pw,
                       const float* __restrict__ encp, float* __restrict__ P){
  int t = blockIdx.x / B, b = blockIdx.x % B, e = threadIdx.x;
  const float* xr = target + (b*T + t)*E;
  const float* wr = pw + e*HE;
  float acc = encp[b*E+e];
  for (int j=0;j<E;j+=4){
    float4 w4 = *(const float4*)(wr+j);
    float4 x4 = *(const float4*)(xr+j);
    acc += w4.x*x4.x + w4.y*x4.y + w4.z*x4.z + w4.w*x4.w;
  }
  P[(t*E + e)*B + b] = acc;
}

// xg0[t][r][b] = b_ih0[r]+b_hh0[r] + sum_e w_ih0[r][e] * P[t][e][b]
__global__ void k_xg0(const float* __restrict__ wih0, const float* __restrict__ bih0,
                      const float* __restrict__ bhh0, const float* __restrict__ P,
                      float* __restrict__ xg){
  int idx = blockIdx.x*256 + threadIdx.x;
  int b = idx & 31; int r = (idx >> 5) & 4095; int t = idx >> 17;
  const float* wr = wih0 + r*E;
  const float* pr = P + t*E*B + b;
  float acc = bih0[r] + bhh0[r];
  #pragma unroll 8
  for (int e=0;e<E;e++) acc += wr[e] * pr[e*B];
  xg[idx] = acc;
}

__global__ void k_zero32(unsigned* __restrict__ p){
  p[blockIdx.x*256 + threadIdx.x] = 0u;
}

// convert lw f32 -> bf16 in the GEMM's swizzled tile layout
__global__ void k_cvtw(const float* __restrict__ lw, uint4* __restrict__ wsw){
  int gid = blockIdx.x*256 + threadIdx.x;   // 4,096,000
  int n = gid >> 7, rem = gid & 127;
  int k0c = rem >> 3, seg = rem & 7;
  const float4* src = (const float4*)(lw + (long)n*H + k0c*64 + seg*8);
  float4 v0 = src[0], v1 = src[1];
  uint4 pk;
  pk.x = pkbf(v0.x, v0.y); pk.y = pkbf(v0.z, v0.w);
  pk.z = pkbf(v1.x, v1.y); pk.w = pkbf(v1.z, v1.w);
  int bn = n >> 7, row = n & 127;
  wsw[((long)(bn*16 + k0c)*128 + row)*8 + (seg ^ (row & 7))] = pk;
}

// pack H1Tmk f32 [m][k] -> Abf swizzled bf16 tiles
__global__ void k_pack(const float* __restrict__ H1Tmk, uint4* __restrict__ Abf){
  int gid = blockIdx.x*256 + threadIdx.x;   // 204,800
  int m = gid >> 7, rem = gid & 127;
  int k0c = rem >> 3, seg = rem & 7;
  const float4* src = (const float4*)(H1Tmk + (long)m*1024 + k0c*64 + seg*8);
  float4 v0 = src[0], v1 = src[1];
  uint4 pk;
  pk.x = pkbf(v0.x, v0.y); pk.y = pkbf(v0.z, v0.w);
  pk.z = pkbf(v1.x, v1.y); pk.w = pkbf(v1.z, v1.w);
  int bm = m >> 7, row = m & 127;
  Abf[((long)(bm*16 + k0c)*128 + row)*8 + (seg ^ (row & 7))] = pk;
}

// ---------------- cooperative persistent cells (v7: MFMA matvec) ----------------
// State f16 [b][k] (k-contiguous). Weights f16 in LDS, row-major with XOR-swizzled
// 8-elem segments. Wave w owns K-slice c*64 (c rotated); 12 mfma_16x16x32_f16/wave.
// Fragment mapping identical to the validated k_gemm.
__global__ __launch_bounds__(1024, 4) void k_cells(
    const float* __restrict__ whh0, const float* __restrict__ wih1, const float* __restrict__ whh1,
    const float* __restrict__ bih1, const float* __restrict__ bhh1,
    const float* __restrict__ enc, const float* __restrict__ xg0,
    unsigned* __restrict__ h0A2, unsigned* __restrict__ h0B2,
    unsigned* __restrict__ h1A2, unsigned* __restrict__ h1B2,
    float* __restrict__ H1Tmk, unsigned* __restrict__ bar){
  const int gB = blockIdx.x;
  const int tid = threadIdx.x;
  const int w = tid >> 6;       // wave 0..15 = k-chunk owner
  const int l = tid & 63;
  const int lrow = l & 15;      // fragment row/col
  const int lk = l >> 4;        // k-segment 0..3

  __shared__ uint4 w0s4[16*128];        // layer0 whh0 rows, f16 swizzled (32 KB)
  __shared__ uint4 w1s4[32*128];        // wih1(0-15)+whh1(16-31) (64 KB)
  __shared__ float partial[16][16][32]; // [wave][row][b] (32 KB)
  __shared__ float gates[16][32];
  __shared__ float cst[2][4][32];
  __shared__ float bs1v[16];
  __shared__ __fp16 h1loc[4][1600];     // [hl][b*T+t] (12.8 KB)

  // ---- stage weights f32 -> f16, XOR-swizzled segments ----
  for (int i = tid; i < 2048; i += 1024){
    int row = i >> 7, seg = i & 127;
    int q = row >> 2, hl = row & 3;
    const float* src = whh0 + ((long)q*H + 4*gB + hl)*H + seg*8;
    float4 v0 = *(const float4*)src, v1 = *(const float4*)(src+4);
    U32H2 z0,z1,z2,z3;
    z0.h = pk2(v0.x,v0.y); z1.h = pk2(v0.z,v0.w);
    z2.h = pk2(v1.x,v1.y); z3.h = pk2(v1.z,v1.w);
    uint4 pk; pk.x=z0.u; pk.y=z1.u; pk.z=z2.u; pk.w=z3.u;
    int phys = (seg & ~7) | ((seg & 7) ^ (row & 7));
    w0s4[row*128 + phys] = pk;
  }
  for (int i = tid; i < 4096; i += 1024){
    int row = i >> 7, seg = i & 127;
    int rr = row & 15;
    int q = rr >> 2, hl = rr & 3;
    const float* srcm = (row < 16) ? wih1 : whh1;
    const float* src = srcm + ((long)q*H + 4*gB + hl)*H + seg*8;
    float4 v0 = *(const float4*)src, v1 = *(const float4*)(src+4);
    U32H2 z0,z1,z2,z3;
    z0.h = pk2(v0.x,v0.y); z1.h = pk2(v0.z,v0.w);
    z2.h = pk2(v1.x,v1.y); z3.h = pk2(v1.z,v1.w);
    uint4 pk; pk.x=z0.u; pk.y=z1.u; pk.z=z2.u; pk.w=z3.u;
    int phys = (seg & ~7) | ((seg & 7) ^ (rr & 7));
    w1s4[row*128 + phys] = pk;
  }
  if (tid < 16){
    int q = tid >> 2, hl = tid & 3;
    bs1v[tid] = bih1[q*H + 4*gB + hl] + bhh1[q*H + 4*gB + hl];
  }
  if (tid < 128){
    int hl = tid >> 5, bb = tid & 31;
    float v = enc[bb*H + 4*gB + hl];
    cst[0][hl][bb] = v; cst[1][hl][bb] = v;
  }
  if (tid < 32){
    int bb = tid;
    U32H2 z0, z1;
    z0.h = pk2(enc[bb*H + 4*gB + 0], enc[bb*H + 4*gB + 1]);
    z1.h = pk2(enc[bb*H + 4*gB + 2], enc[bb*H + 4*gB + 3]);
    uint2 val; val.x = z0.u; val.y = z1.u;
    *(uint2*)((char*)h0A2 + (long)(bb*1024 + 4*gB)*2) = val;
    *(uint2*)((char*)h1A2 + (long)(bb*1024 + 4*gB)*2) = val;
  }
  unsigned ep = 1;
  gbar(bar, ep); ep++;

  for (int p = 0; p <= T; p++){
    const unsigned* h0r = (p & 1) ? h0B2 : h0A2;
    unsigned*       h0w = (p & 1) ? h0A2 : h0B2;
    const unsigned* h1r = (p & 1) ? h1A2 : h1B2;
    unsigned*       h1w = (p & 1) ? h1B2 : h1A2;

    // xg prefetch for layer0(p)
    float xgv = 0.f;
    if (p < T && tid < 512){
      int r = tid >> 5, bb = tid & 31;
      int q = r >> 2, hl = r & 3;
      xgv = xg0[((long)p*G4 + (long)q*H + 4*gB + hl)*32 + bb];
    }

    // ---- MFMA matvec ----
    floatx4 acc10 = {0,0,0,0}, acc11 = {0,0,0,0};
    floatx4 acc00 = {0,0,0,0}, acc01 = {0,0,0,0};
    {
      int c = (w + gB + p) & 15;
      int kb = c*64;
      const __fp16* h0f = (const __fp16*)h0r;
      const __fp16* h1f = (const __fp16*)h1r;
      const __fp16* s0a = h0f + lrow*1024 + kb + lk*8;
      const __fp16* s0b = h0f + (16+lrow)*1024 + kb + lk*8;
      const __fp16* s1a = h1f + lrow*1024 + kb + lk*8;
      const __fp16* s1b = h1f + (16+lrow)*1024 + kb + lk*8;
      #pragma unroll
      for (int ks = 0; ks < 2; ks++){
        int phys = c*8 + (((ks<<2) + lk) ^ (lrow & 7));
        U4H8 b0a, b0b;
        b0a.u4 = *(const uint4*)(s0a + ks*32);
        b0b.u4 = *(const uint4*)(s0b + ks*32);
        if (p < T){
          U4H8 a0v; a0v.u4 = w0s4[lrow*128 + phys];
          acc00 = __builtin_amdgcn_mfma_f32_16x16x32_f16(a0v.h8, b0a.h8, acc00, 0, 0, 0);
          acc01 = __builtin_amdgcn_mfma_f32_16x16x32_f16(a0v.h8, b0b.h8, acc01, 0, 0, 0);
        }
        if (p >= 1){
          U4H8 a1i; a1i.u4 = w1s4[lrow*128 + phys];
          U4H8 a1h; a1h.u4 = w1s4[(16+lrow)*128 + phys];
          U4H8 b1a, b1b;
          b1a.u4 = *(const uint4*)(s1a + ks*32);
          b1b.u4 = *(const uint4*)(s1b + ks*32);
          acc10 = __builtin_amdgcn_mfma_f32_16x16x32_f16(a1i.h8, b0a.h8, acc10, 0, 0, 0);
          acc10 = __builtin_amdgcn_mfma_f32_16x16x32_f16(a1h.h8, b1a.h8, acc10, 0, 0, 0);
          acc11 = __builtin_amdgcn_mfma_f32_16x16x32_f16(a1i.h8, b0b.h8, acc11, 0, 0, 0);
          acc11 = __builtin_amdgcn_mfma_f32_16x16x32_f16(a1h.h8, b1b.h8, acc11, 0, 0, 0);
        }
      }
    }
    if (p >= 1){
      #pragma unroll
      for (int r = 0; r < 4; r++){
        partial[w][lk*4 + r][lrow]      = acc10[r];
        partial[w][lk*4 + r][16 + lrow] = acc11[r];
      }
    }
    __syncthreads();
    // ---- layer1(p-1) reduce + cell ----
    if (p >= 1 && tid < 512){
      int r = tid >> 5, bb = tid & 31;
      float s = 0.f;
      #pragma unroll
      for (int w2 = 0; w2 < 16; w2++) s += partial[w2][r][bb];
      float v = s + bs1v[r];
      gates[r][bb] = ((r >> 2) == 2) ? tanhf(v) : sigm(v);
    }
    __syncthreads();
    if (p >= 1 && tid < 32){
      int bb = tid, t1 = p - 1;
      float hn[4];
      #pragma unroll
      for (int hl = 0; hl < 4; hl++){
        float cn = gates[4+hl][bb]*cst[1][hl][bb] + gates[0+hl][bb]*gates[8+hl][bb];
        cst[1][hl][bb] = cn;
        hn[hl] = gates[12+hl][bb]*tanhf(cn);
        h1loc[hl][bb*T + t1] = (__fp16)hn[hl];
      }
      U32H2 z0, z1; z0.h = pk2(hn[0], hn[1]); z1.h = pk2(hn[2], hn[3]);
      uint2 val; val.x = z0.u; val.y = z1.u;
      *(uint2*)((char*)h1w + (long)(bb*1024 + 4*gB)*2) = val;
    }
    // ---- layer0(p) partial stash ----
    if (p < T){
      #pragma unroll
      for (int r = 0; r < 4; r++){
        partial[w][lk*4 + r][lrow]      = acc00[r];
        partial[w][lk*4 + r][16 + lrow] = acc01[r];
      }
    }
    __syncthreads();
    if (p < T && tid < 512){
      int r = tid >> 5, bb = tid & 31;
      float s = 0.f;
      #pragma unroll
      for (int w2 = 0; w2 < 16; w2++) s += partial[w2][r][bb];
      float v = s + xgv;
      gates[r][bb] = ((r >> 2) == 2) ? tanhf(v) : sigm(v);
    }
    __syncthreads();
    if (p < T && tid < 32){
      int bb = tid;
      float hn[4];
      #pragma unroll
      for (int hl = 0; hl < 4; hl++){
        float cn = gates[4+hl][bb]*cst[0][hl][bb] + gates[0+hl][bb]*gates[8+hl][bb];
        cst[0][hl][bb] = cn;
        hn[hl] = gates[12+hl][bb]*tanhf(cn);
      }
      U32H2 z0, z1; z0.h = pk2(hn[0], hn[1]); z1.h = pk2(hn[2], hn[3]);
      uint2 val; val.x = z0.u; val.y = z1.u;
      *(uint2*)((char*)h0w + (long)(bb*1024 + 4*gB)*2) = val;
    }
    gbar(bar, ep); ep++;
  }

  // H1Tmk flush: row m = b*T+t, 4 contiguous k = 4gB..4gB+3 (16B store)
  for (int m = tid; m < B*T; m += 1024){
    float4 v;
    v.x = (float)h1loc[0][m]; v.y = (float)h1loc[1][m];
    v.z = (float)h1loc[2][m]; v.w = (float)h1loc[3][m];
    *(float4*)&H1Tmk[(long)m*1024 + 4*gB] = v;
  }
}

// ---------------- fallback per-step cells ----------------
__global__ void k_init(const float* __restrict__ enc, float* __restrict__ h0, float* __restrict__ c0,
                       float* __restrict__ h1, float* __restrict__ c1){
  int idx = blockIdx.x*256 + threadIdx.x;
  int b = idx & 31, h = idx >> 5;
  float v = enc[b*H + h];
  h0[idx]=v; c0[idx]=v; h1[idx]=v; c1[idx]=v;
}

__global__ __launch_bounds__(256) void k_cell0(const float* __restrict__ whh, const float* __restrict__ xg_t,
                       const float* __restrict__ h_in, float* __restrict__ h_out,
                       float* __restrict__ c){
  int h = (blockIdx.x*256 + threadIdx.x) >> 6;
  int lane = threadIdx.x & 63;
  int b = lane & 31, kh = lane >> 5;
  const float* w0 = whh + (0*H + h)*H + kh*512;
  const float* w1 = whh + (1*H + h)*H + kh*512;
  const float* w2 = whh + (2*H + h)*H + kh*512;
  const float* w3 = whh + (3*H + h)*H + kh*512;
  const float* hk = h_in + (kh*512)*B + b;
  float a0=0,a1=0,a2=0,a3=0, p0=0,p1=0,p2=0,p3=0;
  #pragma unroll 4
  for (int k=0;k<512;k+=4){
    float4 w40 = *(const float4*)(w0+k);
    float4 w41 = *(const float4*)(w1+k);
    float4 w42 = *(const float4*)(w2+k);
    float4 w43 = *(const float4*)(w3+k);
    float hv0 = hk[(k+0)*B], hv1 = hk[(k+1)*B], hv2 = hk[(k+2)*B], hv3 = hk[(k+3)*B];
    a0 += w40.x*hv0 + w40.y*hv1;  p0 += w40.z*hv2 + w40.w*hv3;
    a1 += w41.x*hv0 + w41.y*hv1;  p1 += w41.z*hv2 + w41.w*hv3;
    a2 += w42.x*hv0 + w42.y*hv1;  p2 += w42.z*hv2 + w42.w*hv3;
    a3 += w43.x*hv0 + w43.y*hv1;  p3 += w43.z*hv2 + w43.w*hv3;
  }
  float g0=a0+p0, g1=a1+p1, g2=a2+p2, g3=a3+p3;
  g0 += __shfl_xor(g0, 32);
  g1 += __shfl_xor(g1, 32);
  g2 += __shfl_xor(g2, 32);
  g3 += __shfl_xor(g3, 32);
  g0 += xg_t[(0*H+h)*B + b];
  g1 += xg_t[(1*H+h)*B + b];
  g2 += xg_t[(2*H+h)*B + b];
  g3 += xg_t[(3*H+h)*B + b];
  float ig = sigm(g0), fg = sigm(g1), gg = tanhf(g2), og = sigm(g3);
  int sidx = h*B + b;
  float cn = fg*c[sidx] + ig*gg;
  float hn = og*tanhf(cn);
  if (kh==0){ c[sidx]=cn; h_out[sidx]=hn; }
}

__global__ __launch_bounds__(256) void k_cell1(const float* __restrict__ wih, const float* __restrict__ whh,
                       const float* __restrict__ bih, const float* __restrict__ bhh,
                       const float* __restrict__ h0n, const float* __restrict__ h_in,
                       float* __restrict__ h_out, float* __restrict__ c,
                       float* __restrict__ H1Tmk, int t){
  int h = (blockIdx.x*256 + threadIdx.x) >> 6;
  int lane = threadIdx.x & 63;
  int b = lane & 31, kh = lane >> 5;
  float a0=0,a1=0,a2=0,a3=0, p0=0,p1=0,p2=0,p3=0;
  {
    const float* w0 = wih + (0*H + h)*H + kh*512;
    const float* w1 = wih + (1*H + h)*H + kh*512;
    const float* w2 = wih + (2*H + h)*H + kh*512;
    const float* w3 = wih + (3*H + h)*H + kh*512;
    const float* hk = h0n + (kh*512)*B + b;
    #pragma unroll 4
    for (int k=0;k<512;k+=4){
      float4 w40 = *(const float4*)(w0+k);
      float4 w41 = *(const float4*)(w1+k);
      float4 w42 = *(const float4*)(w2+k);
      float4 w43 = *(const float4*)(w3+k);
      float hv0 = hk[(k+0)*B], hv1 = hk[(k+1)*B], hv2 = hk[(k+2)*B], hv3 = hk[(k+3)*B];
      a0 += w40.x*hv0 + w40.y*hv1;  p0 += w40.z*hv2 + w40.w*hv3;
      a1 += w41.x*hv0 + w41.y*hv1;  p1 += w41.z*hv2 + w41.w*hv3;
      a2 += w42.x*hv0 + w42.y*hv1;  p2 += w42.z*hv2 + w42.w*hv3;
      a3 += w43.x*hv0 + w43.y*hv1;  p3 += w43.z*hv2 + w43.w*hv3;
    }
  }
  {
    const float* w0 = whh + (0*H + h)*H + kh*512;
    const float* w1 = whh + (1*H + h)*H + kh*512;
    const float* w2 = whh + (2*H + h)*H + kh*512;
    const float* w3 = whh + (3*H + h)*H + kh*512;
    const float* hk = h_in + (kh*512)*B + b;
    #pragma unroll 4
    for (int k=0;k<512;k+=4){
      float4 w40 = *(const float4*)(w0+k);
      float4 w41 = *(const float4*)(w1+k);
      float4 w42 = *(const float4*)(w2+k);
      float4 w43 = *(const float4*)(w3+k);
      float hv0 = hk[(k+0)*B], hv1 = hk[(k+1)*B], hv2 = hk[(k+2)*B], hv3 = hk[(k+3)*B];
      a0 += w40.x*hv0 + w40.y*hv1;  p0 += w40.z*hv2 + w40.w*hv3;
      a1 += w41.x*hv0 + w41.y*hv1;  p1 += w41.z*hv2 + w41.w*hv3;
      a2 += w42.x*hv0 + w42.y*hv1;  p2 += w42.z*hv2 + w42.w*hv3;
      a3 += w43.x*hv0 + w43.y*hv1;  p3 += w43.z*hv2 + w43.w*hv3;
    }
  }
  float g0=a0+p0, g1=a1+p1, g2=a2+p2, g3=a3+p3;
  g0 += __shfl_xor(g0, 32);
  g1 += __shfl_xor(g1, 32);
  g2 += __shfl_xor(g2, 32);
  g3 += __shfl_xor(g3, 32);
  g0 += bih[0*H+h] + bhh[0*H+h];
  g1 += bih[1*H+h] + bhh[1*H+h];
  g2 += bih[2*H+h] + bhh[2*H+h];
  g3 += bih[3*H+h] + bhh[3*H+h];
  float ig = sigm(g0), fg = sigm(g1), gg = tanhf(g2), og = sigm(g3);
  int sidx = h*B + b;
  float cn = fg*c[sidx] + ig*gg;
  float hn = og*tanhf(cn);
  if (kh==0){ c[sidx]=cn; h_out[sidx]=hn; H1Tmk[((long)(b*T + t))*1024 + h] = hn; }
}

// ---------------- MFMA bf16 output GEMM (pre-swizzled operands) ----------------
__global__ __launch_bounds__(256, 2) void k_gemm_pre(const uint4* __restrict__ Abf4,
                      const uint4* __restrict__ Wsw4, const float* __restrict__ lb,
                      float* __restrict__ out){
  __shared__ uint4 As4[1024];
  __shared__ uint4 Ws4[1024];
  const int tid = threadIdx.x;
  int orig = blockIdx.x;
  int xcd = orig & 7, ii = orig >> 3;
  int wgid = (xcd < 2 ? xcd*407 : 814 + (xcd-2)*406) + ii;
  int bm = wgid % 13, bn = wgid / 13;
  int m0 = bm*128, n0 = bn*128;
  const int wv = tid >> 6, l = tid & 63;
  const int wm = (wv >> 1)*64, wn = (wv & 1)*64;
  const int lrow = l & 15, lk = l >> 4;

  floatx4 acc[4][4] = {};
  for (int k0c = 0; k0c < 16; k0c++){
    const uint4* sA = Abf4 + (long)(bm*16 + k0c)*1024;
    const uint4* sW = Wsw4 + (long)(bn*16 + k0c)*1024;
    #pragma unroll
    for (int it = 0; it < 4; it++){
      int slot = tid + it*256;
      As4[slot] = sA[slot];
      Ws4[slot] = sW[slot];
    }
    __syncthreads();
    #pragma unroll
    for (int ks = 0; ks < 2; ks++){
      short8 af[4], bf_[4];
      #pragma unroll
      for (int fi = 0; fi < 4; fi++){
        int row = wm + fi*16 + lrow;
        U16S8 u; u.u4 = As4[row*8 + ((ks*4 + lk) ^ (lrow & 7))];
        af[fi] = u.s8;
      }
      #pragma unroll
      for (int fj = 0; fj < 4; fj++){
        int row = wn + fj*16 + lrow;
        U16S8 u; u.u4 = Ws4[row*8 + ((ks*4 + lk) ^ (lrow & 7))];
        bf_[fj] = u.s8;
      }
      #pragma unroll
      for (int fi = 0; fi < 4; fi++)
        #pragma unroll
        for (int fj = 0; fj < 4; fj++)
          acc[fi][fj] = __builtin_amdgcn_mfma_f32_16x16x32_bf16(af[fi], bf_[fj], acc[fi][fj], 0, 0, 0);
    }
    __syncthreads();
  }
  #pragma unroll
  for (int fj = 0; fj < 4; fj++){
    int n = n0 + wn + fj*16 + lrow;
    float bias = lb[n];
    #pragma unroll
    for (int fi = 0; fi < 4; fi++){
      floatx4 av = acc[fi][fj];
      int mb = m0 + wm + fi*16 + lk*4;
      #pragma unroll
      for (int r = 0; r < 4; r++){
        int m = mb + r;
        if (m < B*T) out[(long)m*V + n] = av[r] + bias;
      }
    }
  }
}

// fallback GEMM: A pre-swizzled, W converted inline from f32
__global__ __launch_bounds__(256, 2) void k_gemm_inl(const uint4* __restrict__ Abf4,
                      const float* __restrict__ lw, const float* __restrict__ lb,
                      float* __restrict__ out){
  __shared__ uint4 As4[1024];
  __shared__ uint4 Ws4[1024];
  const int tid = threadIdx.x;
  int orig = blockIdx.x;
  int xcd = orig & 7, ii = orig >> 3;
  int wgid = (xcd < 2 ? xcd*407 : 814 + (xcd-2)*406) + ii;
  int bm = wgid % 13, bn = wgid / 13;
  int m0 = bm*128, n0 = bn*128;
  const int wv = tid >> 6, l = tid & 63;
  const int wm = (wv >> 1)*64, wn = (wv & 1)*64;
  const int lrow = l & 15, lk = l >> 4;

  floatx4 acc[4][4] = {};
  for (int k0c = 0; k0c < 16; k0c++){
    const uint4* sA = Abf4 + (long)(bm*16 + k0c)*1024;
    #pragma unroll
    for (int it = 0; it < 4; it++){
      int slot = tid + it*256;
      As4[slot] = sA[slot];
      int row = slot >> 3, seg = slot & 7;
      const float4* src = (const float4*)(lw + (long)(n0+row)*H + k0c*64 + seg*8);
      float4 v0 = src[0], v1 = src[1];
      uint4 pk;
      pk.x = pkbf(v0.x, v0.y); pk.y = pkbf(v0.z, v0.w);
      pk.z = pkbf(v1.x, v1.y); pk.w = pkbf(v1.z, v1.w);
      Ws4[row*8 + (seg ^ (row & 7))] = pk;
    }
    __syncthreads();
    #pragma unroll
    for (int ks = 0; ks < 2; ks++){
      short8 af[4], bf_[4];
      #pragma unroll
      for (int fi = 0; fi < 4; fi++){
        int row = wm + fi*16 + lrow;
        U16S8 u; u.u4 = As4[row*8 + ((ks*4 + lk) ^ (lrow & 7))];
        af[fi] = u.s8;
      }
      #pragma unroll
      for (int fj = 0; fj < 4; fj++){
        int row = wn + fj*16 + lrow;
        U16S8 u; u.u4 = Ws4[row*8 + ((ks*4 + lk) ^ (lrow & 7))];
        bf_[fj] = u.s8;
      }
      #pragma unroll
      for (int fi = 0; fi < 4; fi++)
        #pragma unroll
        for (int fj = 0; fj < 4; fj++)
          acc[fi][fj] = __builtin_amdgcn_mfma_f32_16x16x32_bf16(af[fi], bf_[fj], acc[fi][fj], 0, 0, 0);
    }
    __syncthreads();
  }
  #pragma unroll
  for (int fj = 0; fj < 4; fj++){
    int n = n0 + wn + fj*16 + lrow;
    float bias = lb[n];
    #pragma unroll
    for (int fi = 0; fi < 4; fi++){
      floatx4 av = acc[fi][fj];
      int mb = m0 + wm + fi*16 + lk*4;
      #pragma unroll
      for (int r = 0; r < 4; r++){
        int m = mb + r;
        if (m < B*T) out[(long)m*V + n] = av[r] + bias;
      }
    }
  }
}

__global__ __launch_bounds__(256) void k_lsm(float* __restrict__ out){
  __shared__ float red[256];
  float4* row = (float4*)(out + (long)blockIdx.x * V);
  const int tid = threadIdx.x;
  float m = -INFINITY;
  for (int n=tid;n<V/4;n+=256){
    float4 v = row[n];
    m = fmaxf(m, fmaxf(fmaxf(v.x,v.y), fmaxf(v.z,v.w)));
  }
  red[tid]=m; __syncthreads();
  for (int s=128;s>0;s>>=1){ if(tid<s) red[tid]=fmaxf(red[tid],red[tid+s]); __syncthreads(); }
  m = red[0]; __syncthreads();
  float s = 0.f;
  for (int n=tid;n<V/4;n+=256){
    float4 v = row[n];
    s += __expf(v.x-m)+__expf(v.y-m)+__expf(v.z-m)+__expf(v.w-m);
  }
  red[tid]=s; __syncthreads();
  for (int st=128;st>0;st>>=1){ if(tid<st) red[tid]+=red[tid+st]; __syncthreads(); }
  float lse = m + __logf(red[0]);
  for (int n=tid;n<V/4;n+=256){
    float4 v = row[n];
    v.x-=lse; v.y-=lse; v.z-=lse; v.w-=lse;
    row[n] = v;
  }
}

extern "C" void kernel_launch(void* const* d_in, const int* in_sizes, int n_in,
                              void* d_out, int out_size, void* d_ws, size_t ws_size,
                              hipStream_t stream){
  const float* enc    = (const float*)d_in[0];
  const float* target = (const float*)d_in[1];
  const float* pw     = (const float*)d_in[2];
  const float* pb     = (const float*)d_in[3];
  const float* wih0   = (const float*)d_in[4];
  const float* whh0   = (const float*)d_in[5];
  const float* bih0   = (const float*)d_in[6];
  const float* bhh0   = (const float*)d_in[7];
  const float* wih1   = (const float*)d_in[8];
  const float* whh1   = (const float*)d_in[9];
  const float* bih1   = (const float*)d_in[10];
  const float* bhh1   = (const float*)d_in[11];
  const float* lw     = (const float*)d_in[12];
  const float* lb     = (const float*)d_in[13];
  float* out = (float*)d_out;

  float* ws   = (float*)d_ws;
  float* xg0  = ws;                              // 6,553,600 f
  float* P    = xg0 + (long)T*G4*B;              // 204,800 f
  float* encp = P + T*E*B;                       // 4,096 f
  float* H1Tmk = encp + B*E;                     // MROWS*1024 = 1,703,936 f
  unsigned* Abf = (unsigned*)(H1Tmk + (long)MROWS*1024);  // 851,968 u32
  unsigned* h0A2 = Abf + 851968;                 // 16,384 each (64KB f16 state)
  unsigned* h0B2 = h0A2 + 16384;
  unsigned* h1A2 = h0B2 + 16384;
  unsigned* h1B2 = h1A2 + 16384;
  float* fh0a = (float*)(h1B2 + 16384);          // fallback f32 state
  float* fh0b = fh0a + H*B;
  float* fh1a = fh0b + H*B;
  float* fh1b = fh1a + H*B;
  float* fc0  = fh1b + H*B;
  float* fc1  = fc0 + H*B;
  unsigned* bar = (unsigned*)(fc1 + H*B);        // 1,024 u32
  unsigned* lwsw = bar + 1024;                   // 16,384,000 u32
  size_t need = (size_t)((char*)(lwsw + 16384000) - (char*)d_ws);
  bool pre = (ws_size >= need);

  k_encp<<<B, E, 0, stream>>>(enc, pw, pb, encp);
  k_proj<<<T*B, E, 0, stream>>>(target, pw, encp, P);
  k_xg0<<<(T*G4*B)/256, 256, 0, stream>>>(wih0, bih0, bhh0, P, xg0);
  k_zero32<<<4, 256, 0, stream>>>(bar);
  if (pre) k_cvtw<<<16000, 256, 0, stream>>>(lw, (uint4*)lwsw);

  void* cargs[] = {(void*)&whh0, (void*)&wih1, (void*)&whh1, (void*)&bih1, (void*)&bhh1,
                   (void*)&enc, (void*)&xg0,
                   (void*)&h0A2, (void*)&h0B2, (void*)&h1A2, (void*)&h1B2,
                   (void*)&H1Tmk, (void*)&bar};
  hipError_t cerr = hipLaunchCooperativeKernel((void*)k_cells, dim3(NB), dim3(1024),
                                               cargs, 0, stream);
  if (cerr != hipSuccess){
    k_init<<<(H*B)/256, 256, 0, stream>>>(enc, fh0a, fc0, fh1a, fc1);
    float* h0in=fh0a; float* h0out=fh0b;
    float* h1in=fh1a; float* h1out=fh1b;
    for (int t=0;t<T;t++){
      k_cell0<<<256, 256, 0, stream>>>(whh0, xg0 + (long)t*G4*B, h0in, h0out, fc0);
      k_cell1<<<256, 256, 0, stream>>>(wih1, whh1, bih1, bhh1, h0out, h1in, h1out, fc1,
                                       H1Tmk, t);
      float* tmp;
      tmp=h0in; h0in=h0out; h0out=tmp;
      tmp=h1in; h1in=h1out; h1out=tmp;
    }
  }

  k_pack<<<800, 256, 0, stream>>>(H1Tmk, (uint4*)Abf);
  if (pre) k_gemm_pre<<<3250, 256, 0, stream>>>((const uint4*)Abf, (const uint4*)lwsw, lb, out);
  else     k_gemm_inl<<<3250, 256, 0, stream>>>((const uint4*)Abf, lw, lb, out);
  k_lsm<<<B*T, 256, 0, stream>>>(out);
}